// Round 2
// baseline (1493.189 us; speedup 1.0000x reference)
//
#include <hip/hip_runtime.h>
#include <hip/hip_bf16.h>

#define DEV static __device__ __forceinline__

// ---------------- stat layout (floats, inside ws) ----------------
#define ST_S_BN0   0
#define ST_Q_BN0   64
#define ST_S_SC    128
#define ST_Q_SC    384
#define ST_S_IN1   640
#define ST_Q_IN1   896
#define ST_S_IN2   1152
#define ST_Q_IN2   1408
#define ST_S_BN1   1664
#define ST_Q_BN1   1728
#define ST_S_BN2   1792
#define ST_Q_BN2   2048
#define ST_ACC_END 2304
#define ST_SC_BN0  2304
#define ST_SH_BN0  2368
#define ST_SC_SC   2432
#define ST_SH_SC   2688
#define ST_SC_IN1  2944
#define ST_SH_IN1  3200
#define ST_SC_IN2  3456
#define ST_SH_IN2  3712
#define ST_SC_BN1  3968
#define ST_SH_BN1  4032
#define ST_SC_BN2  4096
#define ST_SH_BN2  4352

DEV float rsum16(float v){
#pragma unroll
  for (int off = 8; off >= 1; off >>= 1) v += __shfl_xor(v, off, 16);
  return v;
}
DEV float rmax16(float v){
#pragma unroll
  for (int off = 8; off >= 1; off >>= 1) v = fmaxf(v, __shfl_xor(v, off, 16));
  return v;
}

// =================================================================
// K1: fused cv0 (64ch) + shortcut (256ch) GEMM over x.
// out layouts: y0t (b, n, 64) bf16 ; sct (b, n, 256) bf16. + bn0/bnsc stats.
// grid = 5(oc) * 32(ntile) * 16(b); 256 thr; tile 64o x 256n, K=128.
// =================================================================
__global__ __launch_bounds__(256) void k_gemm320(
    const float* __restrict__ x, const float* __restrict__ cv0w, const float* __restrict__ cv0b,
    const float* __restrict__ scw, const float* __restrict__ scb,
    __hip_bfloat16* __restrict__ y0t, __hip_bfloat16* __restrict__ sct,
    float* __restrict__ stat)
{
  const int tid = threadIdx.x;
  int bx = blockIdx.x;
  const int oc = bx % 5; bx /= 5;
  const int nt = bx & 31;
  const int b  = bx >> 5;
  const int n0 = nt << 8;
  const float* W    = (oc == 0) ? cv0w : scw + (size_t)(oc - 1) * 64 * 128;
  const float* bias = (oc == 0) ? cv0b : scb + (oc - 1) * 64;

  __shared__ float Xs[32][256];
  __shared__ float Ws[64][32];

  const int tx = tid & 31;   // n micro (8 n at stride 32)
  const int ty = tid >> 5;   // o micro (8 consecutive o)

  float acc[8][8];
#pragma unroll
  for (int i = 0; i < 8; i++)
#pragma unroll
    for (int j = 0; j < 8; j++) acc[i][j] = 0.0f;

  for (int k0 = 0; k0 < 128; k0 += 32){
#pragma unroll
    for (int r = 0; r < 8; r++){
      int fi  = tid + (r << 8);
      int row = fi >> 6, c4 = fi & 63;
      *(float4*)&Xs[row][c4 << 2] =
        *(const float4*)&x[(((size_t)b * 128 + k0 + row) << 13) + n0 + (c4 << 2)];
    }
#pragma unroll
    for (int r = 0; r < 2; r++){
      int fi  = tid + (r << 8);
      int row = fi >> 3, c4 = fi & 7;
      *(float4*)&Ws[row][c4 << 2] = *(const float4*)&W[row * 128 + k0 + (c4 << 2)];
    }
    __syncthreads();
#pragma unroll
    for (int kk = 0; kk < 32; kk++){
      float a[8], xv[8];
#pragma unroll
      for (int i = 0; i < 8; i++) a[i] = Ws[(ty << 3) + i][kk];
#pragma unroll
      for (int j = 0; j < 8; j++) xv[j] = Xs[kk][tx + (j << 5)];
#pragma unroll
      for (int i = 0; i < 8; i++)
#pragma unroll
        for (int j = 0; j < 8; j++) acc[i][j] = fmaf(a[i], xv[j], acc[i][j]);
    }
    __syncthreads();
  }

  float bv[8];
#pragma unroll
  for (int i = 0; i < 8; i++) bv[i] = bias[(ty << 3) + i];
#pragma unroll
  for (int i = 0; i < 8; i++)
#pragma unroll
    for (int j = 0; j < 8; j++) acc[i][j] += bv[i];

  // write bf16 (channel-contiguous)
#pragma unroll
  for (int j = 0; j < 8; j++){
    int n = n0 + tx + (j << 5);
    union { uint4 u; __hip_bfloat16 h[8]; } pk;
#pragma unroll
    for (int i = 0; i < 8; i++) pk.h[i] = __float2bfloat16(acc[i][j]);
    if (oc == 0)
      *(uint4*)&y0t[((((size_t)b << 13) + n) << 6) + (ty << 3)] = pk.u;
    else
      *(uint4*)&sct[((((size_t)b << 13) + n) << 8) + ((oc - 1) << 6) + (ty << 3)] = pk.u;
  }

  // per-channel stats (sum, sumsq) -> atomics
#pragma unroll
  for (int i = 0; i < 8; i++){
    float ss = 0.0f, qq = 0.0f;
#pragma unroll
    for (int j = 0; j < 8; j++){ float v = acc[i][j]; ss += v; qq += v * v; }
#pragma unroll
    for (int off = 16; off >= 1; off >>= 1){
      ss += __shfl_xor(ss, off, 32);
      qq += __shfl_xor(qq, off, 32);
    }
    if (tx == 0){
      int ch = (oc << 6) + (ty << 3) + i;   // 0..319
      float* sd = (ch < 64) ? stat + ST_S_BN0 + ch : stat + ST_S_SC + (ch - 64);
      float* qd = (ch < 64) ? stat + ST_Q_BN0 + ch : stat + ST_Q_SC + (ch - 64);
      atomicAdd(sd, ss);
      atomicAdd(qd, qq);
    }
  }
}

// =================================================================
// finalize: scale = g*rsqrt(var+eps), shift = b - mean*scale
// =================================================================
__global__ void k_finalize(const float* __restrict__ s, const float* __restrict__ q,
                           const float* __restrict__ g, const float* __restrict__ bb,
                           float inv_cnt, int nch, int gmod,
                           float* __restrict__ scale, float* __restrict__ shift)
{
  int i = threadIdx.x;
  if (i < nch){
    float m  = s[i] * inv_cnt;
    float v  = q[i] * inv_cnt - m * m;
    float sc = g[i % gmod] * rsqrtf(v + 1e-5f);
    scale[i] = sc;
    shift[i] = bb[i % gmod] - m * sc;
  }
}

// =================================================================
// K3: IN1 stats on z1 = fc1 @ (pts/nr). block=(b, 16-s tile), thread=(sl,k)
// =================================================================
__global__ __launch_bounds__(256) void k_in1_stats(
    const float* __restrict__ pos, const float* __restrict__ sup, const int* __restrict__ nbr,
    const float* __restrict__ fc1, const float* __restrict__ nrp, float* __restrict__ stat)
{
  const int tid = threadIdx.x;
  const int b  = blockIdx.x >> 7;
  const int st = blockIdx.x & 127;
  const int sl = tid >> 4, k = tid & 15;
  const int s  = (st << 4) + sl;
  const int n  = nbr[((((size_t)b << 11) + s) << 4) + k];
  const float inr = 1.0f / nrp[0];
  float p0 = (pos[((size_t)b * 3 + 0) * 8192 + n] - sup[((size_t)b * 3 + 0) * 2048 + s]) * inr;
  float p1 = (pos[((size_t)b * 3 + 1) * 8192 + n] - sup[((size_t)b * 3 + 1) * 2048 + s]) * inr;
  float p2 = (pos[((size_t)b * 3 + 2) * 8192 + n] - sup[((size_t)b * 3 + 2) * 2048 + s]) * inr;
#pragma unroll
  for (int q = 0; q < 16; q++){
    float z = fc1[q * 3] * p0 + fc1[q * 3 + 1] * p1 + fc1[q * 3 + 2] * p2;
    float a = z, c = z * z;
#pragma unroll
    for (int off = 32; off >= 1; off >>= 1){
      a += __shfl_xor(a, off, 64);
      c += __shfl_xor(c, off, 64);
    }
    if ((tid & 63) == 0){
      atomicAdd(&stat[ST_S_IN1 + (b << 4) + q], a);
      atomicAdd(&stat[ST_Q_IN1 + (b << 4) + q], c);
    }
  }
}

// =================================================================
// K4: IN2 stats on z2 = fc2 @ [mat1; mp1]
// =================================================================
__global__ __launch_bounds__(256) void k_in2_stats(
    const float* __restrict__ pos, const float* __restrict__ sup, const int* __restrict__ nbr,
    const float* __restrict__ fc1, const float* __restrict__ fc2,
    const float* __restrict__ alp, const float* __restrict__ bet, const float* __restrict__ nrp,
    float* __restrict__ stat)
{
  __shared__ float fc2s[512];
  __shared__ float sc1s[16], sh1s[16];
  const int tid = threadIdx.x;
  const int b  = blockIdx.x >> 7;
  const int st = blockIdx.x & 127;
  fc2s[tid]       = fc2[tid];
  fc2s[tid + 256] = fc2[tid + 256];
  if (tid < 16){
    sc1s[tid] = stat[ST_SC_IN1 + (b << 4) + tid];
    sh1s[tid] = stat[ST_SH_IN1 + (b << 4) + tid];
  }
  __syncthreads();
  const int sl = tid >> 4, k = tid & 15;
  const int s  = (st << 4) + sl;
  const int n  = nbr[((((size_t)b << 11) + s) << 4) + k];
  float t0 = pos[((size_t)b * 3 + 0) * 8192 + n] - sup[((size_t)b * 3 + 0) * 2048 + s];
  float t1 = pos[((size_t)b * 3 + 1) * 8192 + n] - sup[((size_t)b * 3 + 1) * 2048 + s];
  float t2 = pos[((size_t)b * 3 + 2) * 8192 + n] - sup[((size_t)b * 3 + 2) * 2048 + s];
  float dist = sqrtf(t0 * t0 + t1 * t1 + t2 * t2);
  float dw = 1.0f / (1.0f + expf(alp[0] * dist - bet[0]));
  float ssum = rsum16(dw);
  ssum += (ssum == 0.0f ? 1.0f : 0.0f) + 1e-6f;
  dw = dw / ssum * 16.0f;
  const float inr = 1.0f / nrp[0];
  float p0 = t0 * inr, p1 = t1 * inr, p2 = t2 * inr;
  float m1[16], mp1[16];
#pragma unroll
  for (int q = 0; q < 16; q++){
    float z = fc1[q * 3] * p0 + fc1[q * 3 + 1] * p1 + fc1[q * 3 + 2] * p2;
    m1[q] = fmaxf(z * sc1s[q] + sh1s[q], 0.0f);
  }
#pragma unroll
  for (int q = 0; q < 16; q++) mp1[q] = rmax16(m1[q] * dw);
#pragma unroll
  for (int q = 0; q < 16; q++){
    float z = 0.0f;
#pragma unroll
    for (int j = 0; j < 16; j++) z = fmaf(fc2s[q * 32 + j], m1[j], z);
#pragma unroll
    for (int j = 0; j < 16; j++) z = fmaf(fc2s[q * 32 + 16 + j], mp1[j], z);
    float a = z, c = z * z;
#pragma unroll
    for (int off = 32; off >= 1; off >>= 1){
      a += __shfl_xor(a, off, 64);
      c += __shfl_xor(c, off, 64);
    }
    if ((tid & 63) == 0){
      atomicAdd(&stat[ST_S_IN2 + (b << 4) + q], a);
      atomicAdd(&stat[ST_Q_IN2 + (b << 4) + q], c);
    }
  }
}

// =================================================================
// K5: FKA main: full chain -> mat3 (LDS); gather feat (bn0+relu applied);
// agg[c,q] = sum_k feat*mat3 -> write agg (b,s,1024) bf16.
// =================================================================
__global__ __launch_bounds__(256) void k_fka(
    const float* __restrict__ pos, const float* __restrict__ sup, const int* __restrict__ nbr,
    const float* __restrict__ fc1, const float* __restrict__ fc2, const float* __restrict__ fc3,
    const float* __restrict__ alp, const float* __restrict__ bet, const float* __restrict__ nrp,
    const __hip_bfloat16* __restrict__ y0t, const float* __restrict__ stat,
    __hip_bfloat16* __restrict__ agg)
{
  __shared__ float fc2s[512], fc3s[512];
  __shared__ float sc1s[16], sh1s[16], sc2s[16], sh2s[16];
  __shared__ float sc0s[64], sh0s[64];
  __shared__ float mat3_s[16][16][16];  // [sl][q][k]
  __shared__ float feat_s[16][64];      // [k][c]
  __shared__ int   idx_s[16][16];

  const int tid = threadIdx.x;
  const int b  = blockIdx.x >> 7;
  const int st = blockIdx.x & 127;
  fc2s[tid]       = fc2[tid];
  fc2s[tid + 256] = fc2[tid + 256];
  fc3s[tid]       = fc3[tid];
  fc3s[tid + 256] = fc3[tid + 256];
  if (tid < 16){
    sc1s[tid] = stat[ST_SC_IN1 + (b << 4) + tid];
    sh1s[tid] = stat[ST_SH_IN1 + (b << 4) + tid];
    sc2s[tid] = stat[ST_SC_IN2 + (b << 4) + tid];
    sh2s[tid] = stat[ST_SH_IN2 + (b << 4) + tid];
  }
  if (tid < 64){
    sc0s[tid] = stat[ST_SC_BN0 + tid];
    sh0s[tid] = stat[ST_SH_BN0 + tid];
  }
  const int sl = tid >> 4, k = tid & 15;
  const int s  = (st << 4) + sl;
  const int n  = nbr[((((size_t)b << 11) + s) << 4) + k];
  idx_s[sl][k] = n;
  __syncthreads();

  // ---- Phase A: per-(s,k) chain to mat3 ----
  float t0 = pos[((size_t)b * 3 + 0) * 8192 + n] - sup[((size_t)b * 3 + 0) * 2048 + s];
  float t1 = pos[((size_t)b * 3 + 1) * 8192 + n] - sup[((size_t)b * 3 + 1) * 2048 + s];
  float t2 = pos[((size_t)b * 3 + 2) * 8192 + n] - sup[((size_t)b * 3 + 2) * 2048 + s];
  float dist = sqrtf(t0 * t0 + t1 * t1 + t2 * t2);
  float dw = 1.0f / (1.0f + expf(alp[0] * dist - bet[0]));
  float ssum = rsum16(dw);
  ssum += (ssum == 0.0f ? 1.0f : 0.0f) + 1e-6f;
  dw = dw / ssum * 16.0f;
  const float inr = 1.0f / nrp[0];
  float p0 = t0 * inr, p1 = t1 * inr, p2 = t2 * inr;
  float m1[16], mp1[16];
#pragma unroll
  for (int q = 0; q < 16; q++){
    float z = fc1[q * 3] * p0 + fc1[q * 3 + 1] * p1 + fc1[q * 3 + 2] * p2;
    m1[q] = fmaxf(z * sc1s[q] + sh1s[q], 0.0f);
  }
#pragma unroll
  for (int q = 0; q < 16; q++) mp1[q] = rmax16(m1[q] * dw);
  float m2[16], mp2[16];
#pragma unroll
  for (int q = 0; q < 16; q++){
    float z = 0.0f;
#pragma unroll
    for (int j = 0; j < 16; j++) z = fmaf(fc2s[q * 32 + j], m1[j], z);
#pragma unroll
    for (int j = 0; j < 16; j++) z = fmaf(fc2s[q * 32 + 16 + j], mp1[j], z);
    m2[q] = fmaxf(z * sc2s[q] + sh2s[q], 0.0f);
  }
#pragma unroll
  for (int q = 0; q < 16; q++) mp2[q] = rmax16(m2[q] * dw);
#pragma unroll
  for (int q = 0; q < 16; q++){
    float z = 0.0f;
#pragma unroll
    for (int j = 0; j < 16; j++) z = fmaf(fc3s[q * 32 + j], m2[j], z);
#pragma unroll
    for (int j = 0; j < 16; j++) z = fmaf(fc3s[q * 32 + 16 + j], mp2[j], z);
    mat3_s[sl][q][k] = fmaxf(z, 0.0f) * dw;
  }
  __syncthreads();

  // ---- Phase B: feat gather + agg, per s in tile ----
  const int c  = tid >> 2;   // 0..63
  const int q4 = tid & 3;    // 4 consecutive q each
  const int kg = tid >> 6;   // gather: k base
  const int cc = tid & 63;   // gather: channel
  for (int sl2 = 0; sl2 < 16; sl2++){
#pragma unroll
    for (int it = 0; it < 4; it++){
      int kk = kg + (it << 2);
      int nn = idx_s[sl2][kk];
      float v = __bfloat162float(y0t[((((size_t)b << 13) + nn) << 6) + cc]);
      feat_s[kk][cc] = fmaxf(v * sc0s[cc] + sh0s[cc], 0.0f);
    }
    __syncthreads();
    float fv[16];
#pragma unroll
    for (int kk = 0; kk < 16; kk++) fv[kk] = feat_s[kk][c];
    union { uint2 u; __hip_bfloat16 h[4]; } pk;
#pragma unroll
    for (int jj = 0; jj < 4; jj++){
      int q = (q4 << 2) + jj;
      float a2 = 0.0f;
#pragma unroll
      for (int kk = 0; kk < 16; kk++) a2 = fmaf(fv[kk], mat3_s[sl2][q][kk], a2);
      pk.h[jj] = __float2bfloat16(a2);
    }
    *(uint2*)&agg[((((size_t)b << 11) + (st << 4) + sl2) << 10) + (c << 4) + (q4 << 2)] = pk.u;
    __syncthreads();
  }
}

// =================================================================
// K6: hfka[b][s][o] = sum_j cv_w[o][j] * agg[b][s][j]  (M=64,K=1024,N=2048)
// + bn1 stats.  grid = 16b * 16 stiles; tile 64o x 128s.
// =================================================================
__global__ __launch_bounds__(256) void k_cvgemm(
    const __hip_bfloat16* __restrict__ agg, const float* __restrict__ cvw,
    float* __restrict__ hfka, float* __restrict__ stat)
{
  __shared__ float As[128][65];
  __shared__ float Wsh[64][65];
  const int tid = threadIdx.x;
  const int b     = blockIdx.x >> 4;
  const int stile = blockIdx.x & 15;
  const int s0 = stile << 7;
  const int tx = tid & 31;  // 4 s at stride 32
  const int ty = tid >> 5;  // 8 consecutive o
  float acc[8][4];
#pragma unroll
  for (int i = 0; i < 8; i++)
#pragma unroll
    for (int j = 0; j < 4; j++) acc[i][j] = 0.0f;

  for (int k0 = 0; k0 < 1024; k0 += 64){
#pragma unroll
    for (int r = 0; r < 4; r++){
      int fi = tid + (r << 8);
      int row = fi >> 3, c8 = fi & 7;
      union { uint4 u; __hip_bfloat16 h[8]; } ld;
      ld.u = *(const uint4*)&agg[((((size_t)b << 11) + s0 + row) << 10) + k0 + (c8 << 3)];
#pragma unroll
      for (int m = 0; m < 8; m++) As[row][(c8 << 3) + m] = __bfloat162float(ld.h[m]);
    }
#pragma unroll
    for (int r = 0; r < 4; r++){
      int fi = tid + (r << 8);
      int row = fi >> 4, c4 = fi & 15;
      float4 w4 = *(const float4*)&cvw[row * 1024 + k0 + (c4 << 2)];
      Wsh[row][(c4 << 2) + 0] = w4.x;
      Wsh[row][(c4 << 2) + 1] = w4.y;
      Wsh[row][(c4 << 2) + 2] = w4.z;
      Wsh[row][(c4 << 2) + 3] = w4.w;
    }
    __syncthreads();
#pragma unroll
    for (int kk = 0; kk < 64; kk++){
      float a[8], xv[4];
#pragma unroll
      for (int i = 0; i < 8; i++) a[i] = Wsh[(ty << 3) + i][kk];
#pragma unroll
      for (int j = 0; j < 4; j++) xv[j] = As[tx + (j << 5)][kk];
#pragma unroll
      for (int i = 0; i < 8; i++)
#pragma unroll
        for (int j = 0; j < 4; j++) acc[i][j] = fmaf(a[i], xv[j], acc[i][j]);
    }
    __syncthreads();
  }
#pragma unroll
  for (int j = 0; j < 4; j++){
    int s = s0 + tx + (j << 5);
    float4 v0 = make_float4(acc[0][j], acc[1][j], acc[2][j], acc[3][j]);
    float4 v1 = make_float4(acc[4][j], acc[5][j], acc[6][j], acc[7][j]);
    *(float4*)&hfka[((((size_t)b << 11) + s) << 6) + (ty << 3)]     = v0;
    *(float4*)&hfka[((((size_t)b << 11) + s) << 6) + (ty << 3) + 4] = v1;
  }
#pragma unroll
  for (int i = 0; i < 8; i++){
    float ss = 0.0f, qq = 0.0f;
#pragma unroll
    for (int j = 0; j < 4; j++){ float v = acc[i][j]; ss += v; qq += v * v; }
#pragma unroll
    for (int off = 16; off >= 1; off >>= 1){
      ss += __shfl_xor(ss, off, 32);
      qq += __shfl_xor(qq, off, 32);
    }
    if (tx == 0){
      int ch = (ty << 3) + i;
      atomicAdd(&stat[ST_S_BN1 + ch], ss);
      atomicAdd(&stat[ST_Q_BN1 + ch], qq);
    }
  }
}

// =================================================================
// K7: h2[b][s][o] = cv2_w @ relu(bn1(hfka)) + bias, + bn2 stats.
// M=256 (2 chunks of 128) x N=64s, K=64. grid = 16b*32st*2oc.
// =================================================================
__global__ __launch_bounds__(256) void k_cv2(
    const float* __restrict__ hfka, const float* __restrict__ w, const float* __restrict__ bias,
    const float* __restrict__ stat_ro, float* __restrict__ h2, float* __restrict__ stat)
{
  __shared__ float As[64][65];
  __shared__ float Wsh[128][65];
  __shared__ float s1s[64], h1s[64];
  const int tid = threadIdx.x;
  int bx = blockIdx.x;
  const int oc = bx & 1; bx >>= 1;
  const int stile = bx & 31;
  const int b = bx >> 5;
  const int s0 = stile << 6;
  if (tid < 64){
    s1s[tid] = stat_ro[ST_SC_BN1 + tid];
    h1s[tid] = stat_ro[ST_SH_BN1 + tid];
  }
#pragma unroll
  for (int r = 0; r < 8; r++){
    int fi = tid + (r << 8);
    int row = fi >> 4, c4 = fi & 15;
    float4 w4 = *(const float4*)&w[(((size_t)oc << 7) + row) * 64 + (c4 << 2)];
    Wsh[row][(c4 << 2) + 0] = w4.x;
    Wsh[row][(c4 << 2) + 1] = w4.y;
    Wsh[row][(c4 << 2) + 2] = w4.z;
    Wsh[row][(c4 << 2) + 3] = w4.w;
  }
  __syncthreads();
#pragma unroll
  for (int r = 0; r < 4; r++){
    int fi = tid + (r << 8);
    int row = fi >> 4, c4 = fi & 15;
    float4 v = *(const float4*)&hfka[((((size_t)b << 11) + s0 + row) << 6) + (c4 << 2)];
    float vv[4] = {v.x, v.y, v.z, v.w};
#pragma unroll
    for (int m = 0; m < 4; m++){
      int cch = (c4 << 2) + m;
      As[row][cch] = fmaxf(vv[m] * s1s[cch] + h1s[cch], 0.0f);
    }
  }
  __syncthreads();
  const int tx = tid & 15;  // 4 s at stride 16
  const int ty = tid >> 4;  // 8 consecutive o
  float acc[8][4];
#pragma unroll
  for (int i = 0; i < 8; i++)
#pragma unroll
    for (int j = 0; j < 4; j++) acc[i][j] = 0.0f;
#pragma unroll
  for (int kk = 0; kk < 64; kk++){
    float a[8], xv[4];
#pragma unroll
    for (int i = 0; i < 8; i++) a[i] = Wsh[(ty << 3) + i][kk];
#pragma unroll
    for (int j = 0; j < 4; j++) xv[j] = As[tx + (j << 4)][kk];
#pragma unroll
    for (int i = 0; i < 8; i++)
#pragma unroll
      for (int j = 0; j < 4; j++) acc[i][j] = fmaf(a[i], xv[j], acc[i][j]);
  }
  float bv[8];
#pragma unroll
  for (int i = 0; i < 8; i++) bv[i] = bias[(oc << 7) + (ty << 3) + i];
#pragma unroll
  for (int i = 0; i < 8; i++)
#pragma unroll
    for (int j = 0; j < 4; j++) acc[i][j] += bv[i];
#pragma unroll
  for (int j = 0; j < 4; j++){
    int s = s0 + tx + (j << 4);
    float4 v0 = make_float4(acc[0][j], acc[1][j], acc[2][j], acc[3][j]);
    float4 v1 = make_float4(acc[4][j], acc[5][j], acc[6][j], acc[7][j]);
    *(float4*)&h2[((((size_t)b << 11) + s) << 8) + (oc << 7) + (ty << 3)]     = v0;
    *(float4*)&h2[((((size_t)b << 11) + s) << 8) + (oc << 7) + (ty << 3) + 4] = v1;
  }
#pragma unroll
  for (int i = 0; i < 8; i++){
    float ss = 0.0f, qq = 0.0f;
#pragma unroll
    for (int j = 0; j < 4; j++){ float v = acc[i][j]; ss += v; qq += v * v; }
#pragma unroll
    for (int off = 8; off >= 1; off >>= 1){
      ss += __shfl_xor(ss, off, 16);
      qq += __shfl_xor(qq, off, 16);
    }
    if (tx == 0){
      int ch = (oc << 7) + (ty << 3) + i;
      atomicAdd(&stat[ST_S_BN2 + ch], ss);
      atomicAdd(&stat[ST_Q_BN2 + ch], qq);
    }
  }
}

// =================================================================
// K8: final: out[b][o][s] = relu(bn2(h2) + max_k bnsc(sct gathered))
// =================================================================
__global__ __launch_bounds__(256) void k_final(
    const __hip_bfloat16* __restrict__ sct, const float* __restrict__ h2,
    const int* __restrict__ nbr, const float* __restrict__ stat, float* __restrict__ out)
{
  __shared__ int   idx_s[256];
  __shared__ float tile_s[256][17];
  const int tid = threadIdx.x;
  const int b  = blockIdx.x >> 7;
  const int st = blockIdx.x & 127;
  idx_s[tid] = nbr[((((size_t)b << 11) + (st << 4)) << 4) + tid];
  const float ssc = stat[ST_SC_SC + tid], hsc = stat[ST_SH_SC + tid];
  const float s2  = stat[ST_SC_BN2 + tid], h2s = stat[ST_SH_BN2 + tid];
  __syncthreads();
  for (int sl = 0; sl < 16; sl++){
    float m = -3.4e38f;
#pragma unroll
    for (int k = 0; k < 16; k++){
      int nn = idx_s[(sl << 4) + k];
      float v = __bfloat162float(sct[((((size_t)b << 13) + nn) << 8) + tid]);
      m = fmaxf(m, v * ssc + hsc);
    }
    int s = (st << 4) + sl;
    float hv = h2[((((size_t)b << 11) + s) << 8) + tid];
    tile_s[tid][sl] = fmaxf(hv * s2 + h2s + m, 0.0f);
  }
  __syncthreads();
#pragma unroll
  for (int r = 0; r < 16; r++){
    int fi = tid + (r << 8);
    int o2 = fi >> 4, sl2 = fi & 15;
    out[((((size_t)b << 8) + o2) << 11) + (st << 4) + sl2] = tile_s[o2][sl2];
  }
}

// =================================================================
extern "C" void kernel_launch(void* const* d_in, const int* in_sizes, int n_in,
                              void* d_out, int out_size, void* d_ws, size_t ws_size,
                              hipStream_t stream)
{
  (void)in_sizes; (void)n_in; (void)out_size; (void)ws_size;
  const float* x     = (const float*)d_in[0];
  const float* pos   = (const float*)d_in[1];
  const float* sup   = (const float*)d_in[2];
  const int*   nbr   = (const int*)d_in[3];
  const float* cv0w  = (const float*)d_in[5];
  const float* cv0b  = (const float*)d_in[6];
  const float* bn0g  = (const float*)d_in[7];
  const float* bn0b  = (const float*)d_in[8];
  const float* fc1   = (const float*)d_in[9];
  const float* fc2   = (const float*)d_in[10];
  const float* fc3   = (const float*)d_in[11];
  const float* in1g  = (const float*)d_in[12];
  const float* in1b  = (const float*)d_in[13];
  const float* in2g  = (const float*)d_in[14];
  const float* in2b  = (const float*)d_in[15];
  const float* alp   = (const float*)d_in[16];
  const float* bet   = (const float*)d_in[17];
  const float* nrp   = (const float*)d_in[18];
  const float* cvw   = (const float*)d_in[19];
  const float* bn1g  = (const float*)d_in[20];
  const float* bn1b  = (const float*)d_in[21];
  const float* cv2w  = (const float*)d_in[22];
  const float* cv2b  = (const float*)d_in[23];
  const float* bn2g  = (const float*)d_in[24];
  const float* bn2b  = (const float*)d_in[25];
  const float* scw   = (const float*)d_in[26];
  const float* scb   = (const float*)d_in[27];
  const float* bnscg = (const float*)d_in[28];
  const float* bnscb = (const float*)d_in[29];

  char* w = (char*)d_ws;
  __hip_bfloat16* sct  = (__hip_bfloat16*)(w);                         //  67108864 B
  __hip_bfloat16* y0t  = (__hip_bfloat16*)(w + 67108864);              //  16777216 B
  __hip_bfloat16* aggp = (__hip_bfloat16*)(w + 83886080);              //  67108864 B
  float*          hfka = (float*)(w + 150994944);                      //   8388608 B
  float*          h2   = (float*)(w + 159383552);                      //  33554432 B
  float*          stat = (float*)(w + 192937984UL);                    //     18 KB

  hipMemsetAsync(stat, 0, ST_ACC_END * sizeof(float), stream);

  k_gemm320<<<2560, 256, 0, stream>>>(x, cv0w, cv0b, scw, scb, y0t, sct, stat);
  k_finalize<<<1, 256, 0, stream>>>(stat + ST_S_BN0, stat + ST_Q_BN0, bn0g, bn0b,
                                    1.0f / 131072.0f, 64, 64, stat + ST_SC_BN0, stat + ST_SH_BN0);
  k_finalize<<<1, 256, 0, stream>>>(stat + ST_S_SC, stat + ST_Q_SC, bnscg, bnscb,
                                    1.0f / 131072.0f, 256, 256, stat + ST_SC_SC, stat + ST_SH_SC);
  k_in1_stats<<<2048, 256, 0, stream>>>(pos, sup, nbr, fc1, nrp, stat);
  k_finalize<<<1, 256, 0, stream>>>(stat + ST_S_IN1, stat + ST_Q_IN1, in1g, in1b,
                                    1.0f / 32768.0f, 256, 16, stat + ST_SC_IN1, stat + ST_SH_IN1);
  k_in2_stats<<<2048, 256, 0, stream>>>(pos, sup, nbr, fc1, fc2, alp, bet, nrp, stat);
  k_finalize<<<1, 256, 0, stream>>>(stat + ST_S_IN2, stat + ST_Q_IN2, in2g, in2b,
                                    1.0f / 32768.0f, 256, 16, stat + ST_SC_IN2, stat + ST_SH_IN2);
  k_fka<<<2048, 256, 0, stream>>>(pos, sup, nbr, fc1, fc2, fc3, alp, bet, nrp, y0t, stat, aggp);
  k_cvgemm<<<256, 256, 0, stream>>>(aggp, cvw, hfka, stat);
  k_finalize<<<1, 256, 0, stream>>>(stat + ST_S_BN1, stat + ST_Q_BN1, bn1g, bn1b,
                                    1.0f / 32768.0f, 64, 64, stat + ST_SC_BN1, stat + ST_SH_BN1);
  k_cv2<<<1024, 256, 0, stream>>>(hfka, cv2w, cv2b, stat, h2, stat);
  k_finalize<<<1, 256, 0, stream>>>(stat + ST_S_BN2, stat + ST_Q_BN2, bn2g, bn2b,
                                    1.0f / 32768.0f, 256, 256, stat + ST_SC_BN2, stat + ST_SH_BN2);
  k_final<<<2048, 256, 0, stream>>>(sct, h2, nbr, stat, (float*)d_out);
}

// Round 3
// 1417.938 us; speedup vs baseline: 1.0531x; 1.0531x over previous
//
#include <hip/hip_runtime.h>
#include <hip/hip_bf16.h>

#define DEV static __device__ __forceinline__

typedef __attribute__((ext_vector_type(8))) short bf16x8;
typedef __attribute__((ext_vector_type(4))) float f32x4;

// ---------------- stat layout (floats, inside ws) ----------------
#define ST_S_BN0   0
#define ST_Q_BN0   64
#define ST_S_SC    128
#define ST_Q_SC    384
#define ST_S_IN1   640
#define ST_Q_IN1   896
#define ST_S_IN2   1152
#define ST_Q_IN2   1408
#define ST_S_BN1   1664
#define ST_Q_BN1   1728
#define ST_S_BN2   1792
#define ST_Q_BN2   2048
#define ST_ACC_END 2304
#define ST_SC_BN0  2304
#define ST_SH_BN0  2368
#define ST_SC_SC   2432
#define ST_SH_SC   2688
#define ST_SC_IN1  2944
#define ST_SH_IN1  3200
#define ST_SC_IN2  3456
#define ST_SH_IN2  3712
#define ST_SC_BN1  3968
#define ST_SH_BN1  4032
#define ST_SC_BN2  4096
#define ST_SH_BN2  4352

DEV float rsum16(float v){
#pragma unroll
  for (int off = 8; off >= 1; off >>= 1) v += __shfl_xor(v, off, 16);
  return v;
}
DEV float rmax16(float v){
#pragma unroll
  for (int off = 8; off >= 1; off >>= 1) v = fmaxf(v, __shfl_xor(v, off, 16));
  return v;
}

// =================================================================
// P0: weight conversion f32 -> bf16.
// =================================================================
__global__ __launch_bounds__(256) void k_prep_w(
    const float* __restrict__ cv0w, const float* __restrict__ scw,
    const float* __restrict__ cvw,  const float* __restrict__ cv2w,
    __hip_bfloat16* __restrict__ wb, __hip_bfloat16* __restrict__ cvb,
    __hip_bfloat16* __restrict__ cv2b)
{
  int i = blockIdx.x * 256 + threadIdx.x;   // 0 .. 122879
  if (i < 40960){
    float v = (i < 8192) ? cv0w[i] : scw[i - 8192];
    wb[i] = __float2bfloat16(v);
  } else if (i < 106496){
    cvb[i - 40960] = __float2bfloat16(cvw[i - 40960]);
  } else {
    cv2b[i - 106496] = __float2bfloat16(cv2w[i - 106496]);
  }
}

// =================================================================
// P1: transpose x (b,128,8192) f32 -> xb (b,8192,128) bf16
// =================================================================
__global__ __launch_bounds__(256) void k_xpose(
    const float* __restrict__ x, __hip_bfloat16* __restrict__ xb)
{
  __shared__ float t[128][65];
  const int tid = threadIdx.x;
  const int b = blockIdx.x >> 7, nt = blockIdx.x & 127;
  const int n0 = nt << 6;
#pragma unroll
  for (int p = 0; p < 8; p++){
    int row = (p << 4) + (tid >> 4);
    float4 v = *(const float4*)&x[(((size_t)b * 128 + row) << 13) + n0 + ((tid & 15) << 2)];
    t[row][(tid & 15) * 4 + 0] = v.x;
    t[row][(tid & 15) * 4 + 1] = v.y;
    t[row][(tid & 15) * 4 + 2] = v.z;
    t[row][(tid & 15) * 4 + 3] = v.w;
  }
  __syncthreads();
  const int k8 = tid & 15;
#pragma unroll
  for (int p = 0; p < 4; p++){
    int n = (p << 4) + (tid >> 4);
    union { uint4 u; __hip_bfloat16 e[8]; } pk;
#pragma unroll
    for (int j = 0; j < 8; j++) pk.e[j] = __float2bfloat16(t[k8 * 8 + j][n]);
    *(uint4*)&xb[((size_t)(b << 13) + n0 + n) * 128 + k8 * 8] = pk.u;
  }
}

// =================================================================
// K1: MFMA cv0+shortcut GEMM, no LDS.
// =================================================================
__global__ __launch_bounds__(256) void k1_mfma(
    const __hip_bfloat16* __restrict__ xb, const __hip_bfloat16* __restrict__ wb,
    const float* __restrict__ cv0b, const float* __restrict__ scb,
    __hip_bfloat16* __restrict__ y0t, __hip_bfloat16* __restrict__ sct,
    float* __restrict__ stat)
{
  const int tid = threadIdx.x;
  const int b = blockIdx.x >> 7, nt = blockIdx.x & 127;
  const int n0 = nt << 6;
  const int wv = tid >> 6, l = tid & 63;
  const int lr = l & 15, lg = l >> 4;

  f32x4 acc[5][4];
#pragma unroll
  for (int i = 0; i < 5; i++)
#pragma unroll
    for (int j = 0; j < 4; j++) acc[i][j] = (f32x4){0.f, 0.f, 0.f, 0.f};

  const __hip_bfloat16* xrow = xb + ((size_t)(b << 13) + n0 + lr) * 128 + lg * 8;
  const __hip_bfloat16* wrow = wb + (size_t)(wv * 80 + lr) * 128 + lg * 8;

#pragma unroll
  for (int ks = 0; ks < 4; ks++){
    bf16x8 B[4], A[5];
#pragma unroll
    for (int nf = 0; nf < 4; nf++) B[nf] = *(const bf16x8*)(xrow + nf * 2048 + ks * 32);
#pragma unroll
    for (int mf = 0; mf < 5; mf++) A[mf] = *(const bf16x8*)(wrow + mf * 2048 + ks * 32);
#pragma unroll
    for (int mf = 0; mf < 5; mf++)
#pragma unroll
      for (int nf = 0; nf < 4; nf++)
        acc[mf][nf] = __builtin_amdgcn_mfma_f32_16x16x32_bf16(A[mf], B[nf], acc[mf][nf], 0, 0, 0);
  }

#pragma unroll
  for (int mf = 0; mf < 5; mf++){
    const int m0 = wv * 80 + mf * 16 + lg * 4;
    float bv[4];
#pragma unroll
    for (int r = 0; r < 4; r++){
      int m = m0 + r;
      bv[r] = (m < 64) ? cv0b[m] : scb[m - 64];
    }
#pragma unroll
    for (int nf = 0; nf < 4; nf++)
#pragma unroll
      for (int r = 0; r < 4; r++) acc[mf][nf][r] += bv[r];

#pragma unroll
    for (int nf = 0; nf < 4; nf++){
      int n = n0 + nf * 16 + lr;
      union { uint2 u; __hip_bfloat16 e[4]; } pk;
#pragma unroll
      for (int r = 0; r < 4; r++) pk.e[r] = __float2bfloat16(acc[mf][nf][r]);
      if (m0 < 64)
        *(uint2*)&y0t[((size_t)(b << 13) + n) * 64 + m0] = pk.u;
      else
        *(uint2*)&sct[((size_t)(b << 13) + n) * 256 + (m0 - 64)] = pk.u;
    }
#pragma unroll
    for (int r = 0; r < 4; r++){
      float ss = 0.f, qq = 0.f;
#pragma unroll
      for (int nf = 0; nf < 4; nf++){ float v = acc[mf][nf][r]; ss += v; qq += v * v; }
#pragma unroll
      for (int off = 8; off >= 1; off >>= 1){
        ss += __shfl_xor(ss, off, 16);
        qq += __shfl_xor(qq, off, 16);
      }
      if (lr == 0){
        int ch = m0 + r;
        float* sd = (ch < 64) ? stat + ST_S_BN0 + ch : stat + ST_S_SC + (ch - 64);
        float* qd = (ch < 64) ? stat + ST_Q_BN0 + ch : stat + ST_Q_SC + (ch - 64);
        atomicAdd(sd, ss);
        atomicAdd(qd, qq);
      }
    }
  }
}

// =================================================================
__global__ void k_finalize(const float* __restrict__ s, const float* __restrict__ q,
                           const float* __restrict__ g, const float* __restrict__ bb,
                           float inv_cnt, int nch, int gmod,
                           float* __restrict__ scale, float* __restrict__ shift)
{
  int i = threadIdx.x;
  if (i < nch){
    float m  = s[i] * inv_cnt;
    float v  = q[i] * inv_cnt - m * m;
    float sc = g[i % gmod] * rsqrtf(v + 1e-5f);
    scale[i] = sc;
    shift[i] = bb[i % gmod] - m * sc;
  }
}

// =================================================================
__global__ __launch_bounds__(256) void k_in1_stats(
    const float* __restrict__ pos, const float* __restrict__ sup, const int* __restrict__ nbr,
    const float* __restrict__ fc1, const float* __restrict__ nrp, float* __restrict__ stat)
{
  const int tid = threadIdx.x;
  const int b  = blockIdx.x >> 7;
  const int st = blockIdx.x & 127;
  const int sl = tid >> 4, k = tid & 15;
  const int s  = (st << 4) + sl;
  const int n  = nbr[((((size_t)b << 11) + s) << 4) + k];
  const float inr = 1.0f / nrp[0];
  float p0 = (pos[((size_t)b * 3 + 0) * 8192 + n] - sup[((size_t)b * 3 + 0) * 2048 + s]) * inr;
  float p1 = (pos[((size_t)b * 3 + 1) * 8192 + n] - sup[((size_t)b * 3 + 1) * 2048 + s]) * inr;
  float p2 = (pos[((size_t)b * 3 + 2) * 8192 + n] - sup[((size_t)b * 3 + 2) * 2048 + s]) * inr;
#pragma unroll
  for (int q = 0; q < 16; q++){
    float z = fc1[q * 3] * p0 + fc1[q * 3 + 1] * p1 + fc1[q * 3 + 2] * p2;
    float a = z, c = z * z;
#pragma unroll
    for (int off = 32; off >= 1; off >>= 1){
      a += __shfl_xor(a, off, 64);
      c += __shfl_xor(c, off, 64);
    }
    if ((tid & 63) == 0){
      atomicAdd(&stat[ST_S_IN1 + (b << 4) + q], a);
      atomicAdd(&stat[ST_Q_IN1 + (b << 4) + q], c);
    }
  }
}

// =================================================================
__global__ __launch_bounds__(256) void k_in2_stats(
    const float* __restrict__ pos, const float* __restrict__ sup, const int* __restrict__ nbr,
    const float* __restrict__ fc1, const float* __restrict__ fc2,
    const float* __restrict__ alp, const float* __restrict__ bet, const float* __restrict__ nrp,
    float* __restrict__ stat)
{
  __shared__ float fc2s[512];
  __shared__ float sc1s[16], sh1s[16];
  const int tid = threadIdx.x;
  const int b  = blockIdx.x >> 7;
  const int st = blockIdx.x & 127;
  fc2s[tid]       = fc2[tid];
  fc2s[tid + 256] = fc2[tid + 256];
  if (tid < 16){
    sc1s[tid] = stat[ST_SC_IN1 + (b << 4) + tid];
    sh1s[tid] = stat[ST_SH_IN1 + (b << 4) + tid];
  }
  __syncthreads();
  const int sl = tid >> 4, k = tid & 15;
  const int s  = (st << 4) + sl;
  const int n  = nbr[((((size_t)b << 11) + s) << 4) + k];
  float t0 = pos[((size_t)b * 3 + 0) * 8192 + n] - sup[((size_t)b * 3 + 0) * 2048 + s];
  float t1 = pos[((size_t)b * 3 + 1) * 8192 + n] - sup[((size_t)b * 3 + 1) * 2048 + s];
  float t2 = pos[((size_t)b * 3 + 2) * 8192 + n] - sup[((size_t)b * 3 + 2) * 2048 + s];
  float dist = sqrtf(t0 * t0 + t1 * t1 + t2 * t2);
  float dw = 1.0f / (1.0f + expf(alp[0] * dist - bet[0]));
  float ssum = rsum16(dw);
  ssum += (ssum == 0.0f ? 1.0f : 0.0f) + 1e-6f;
  dw = dw / ssum * 16.0f;
  const float inr = 1.0f / nrp[0];
  float p0 = t0 * inr, p1 = t1 * inr, p2 = t2 * inr;
  float m1[16], mp1[16];
#pragma unroll
  for (int q = 0; q < 16; q++){
    float z = fc1[q * 3] * p0 + fc1[q * 3 + 1] * p1 + fc1[q * 3 + 2] * p2;
    m1[q] = fmaxf(z * sc1s[q] + sh1s[q], 0.0f);
  }
#pragma unroll
  for (int q = 0; q < 16; q++) mp1[q] = rmax16(m1[q] * dw);
#pragma unroll
  for (int q = 0; q < 16; q++){
    float z = 0.0f;
#pragma unroll
    for (int j = 0; j < 16; j++) z = fmaf(fc2s[q * 32 + j], m1[j], z);
#pragma unroll
    for (int j = 0; j < 16; j++) z = fmaf(fc2s[q * 32 + 16 + j], mp1[j], z);
    float a = z, c = z * z;
#pragma unroll
    for (int off = 32; off >= 1; off >>= 1){
      a += __shfl_xor(a, off, 64);
      c += __shfl_xor(c, off, 64);
    }
    if ((tid & 63) == 0){
      atomicAdd(&stat[ST_S_IN2 + (b << 4) + q], a);
      atomicAdd(&stat[ST_Q_IN2 + (b << 4) + q], c);
    }
  }
}

// =================================================================
// K5: FKA main
// =================================================================
__global__ __launch_bounds__(256) void k_fka(
    const float* __restrict__ pos, const float* __restrict__ sup, const int* __restrict__ nbr,
    const float* __restrict__ fc1, const float* __restrict__ fc2, const float* __restrict__ fc3,
    const float* __restrict__ alp, const float* __restrict__ bet, const float* __restrict__ nrp,
    const __hip_bfloat16* __restrict__ y0t, const float* __restrict__ stat,
    __hip_bfloat16* __restrict__ agg)
{
  __shared__ float fc2s[512], fc3s[512];
  __shared__ float sc1s[16], sh1s[16], sc2s[16], sh2s[16];
  __shared__ float sc0s[64], sh0s[64];
  __shared__ float mat3_s[16][16][17];
  __shared__ float feat2_s[2][16][65];
  __shared__ int   idx_s[16][16];

  const int tid = threadIdx.x;
  const int b  = blockIdx.x >> 7;
  const int st = blockIdx.x & 127;
  fc2s[tid]       = fc2[tid];
  fc2s[tid + 256] = fc2[tid + 256];
  fc3s[tid]       = fc3[tid];
  fc3s[tid + 256] = fc3[tid + 256];
  if (tid < 16){
    sc1s[tid] = stat[ST_SC_IN1 + (b << 4) + tid];
    sh1s[tid] = stat[ST_SH_IN1 + (b << 4) + tid];
    sc2s[tid] = stat[ST_SC_IN2 + (b << 4) + tid];
    sh2s[tid] = stat[ST_SH_IN2 + (b << 4) + tid];
  }
  if (tid < 64){
    sc0s[tid] = stat[ST_SC_BN0 + tid];
    sh0s[tid] = stat[ST_SH_BN0 + tid];
  }
  const int sl = tid >> 4, k = tid & 15;
  const int s  = (st << 4) + sl;
  const int n  = nbr[((((size_t)b << 11) + s) << 4) + k];
  idx_s[sl][k] = n;
  __syncthreads();

  float t0 = pos[((size_t)b * 3 + 0) * 8192 + n] - sup[((size_t)b * 3 + 0) * 2048 + s];
  float t1 = pos[((size_t)b * 3 + 1) * 8192 + n] - sup[((size_t)b * 3 + 1) * 2048 + s];
  float t2 = pos[((size_t)b * 3 + 2) * 8192 + n] - sup[((size_t)b * 3 + 2) * 2048 + s];
  float dist = sqrtf(t0 * t0 + t1 * t1 + t2 * t2);
  float dw = 1.0f / (1.0f + expf(alp[0] * dist - bet[0]));
  float ssum = rsum16(dw);
  ssum += (ssum == 0.0f ? 1.0f : 0.0f) + 1e-6f;
  dw = dw / ssum * 16.0f;
  const float inr = 1.0f / nrp[0];
  float p0 = t0 * inr, p1 = t1 * inr, p2 = t2 * inr;
  float m1[16], mp1[16];
#pragma unroll
  for (int q = 0; q < 16; q++){
    float z = fc1[q * 3] * p0 + fc1[q * 3 + 1] * p1 + fc1[q * 3 + 2] * p2;
    m1[q] = fmaxf(z * sc1s[q] + sh1s[q], 0.0f);
  }
#pragma unroll
  for (int q = 0; q < 16; q++) mp1[q] = rmax16(m1[q] * dw);
  float m2[16], mp2[16];
#pragma unroll
  for (int q = 0; q < 16; q++){
    float z = 0.0f;
#pragma unroll
    for (int j = 0; j < 16; j++) z = fmaf(fc2s[q * 32 + j], m1[j], z);
#pragma unroll
    for (int j = 0; j < 16; j++) z = fmaf(fc2s[q * 32 + 16 + j], mp1[j], z);
    m2[q] = fmaxf(z * sc2s[q] + sh2s[q], 0.0f);
  }
#pragma unroll
  for (int q = 0; q < 16; q++) mp2[q] = rmax16(m2[q] * dw);
#pragma unroll
  for (int q = 0; q < 16; q++){
    float z = 0.0f;
#pragma unroll
    for (int j = 0; j < 16; j++) z = fmaf(fc3s[q * 32 + j], m2[j], z);
#pragma unroll
    for (int j = 0; j < 16; j++) z = fmaf(fc3s[q * 32 + 16 + j], mp2[j], z);
    mat3_s[sl][q][k] = fmaxf(z, 0.0f) * dw;
  }
  __syncthreads();

  const int h   = tid >> 7;
  const int r7  = tid & 127;
  const int gk  = r7 >> 3;
  const int gc8 = r7 & 7;
  const int cc  = r7 >> 1;
  const int qh  = r7 & 1;

  for (int it = 0; it < 8; it++){
    const int sl2 = it * 2 + h;
    {
      int nn = idx_s[sl2][gk];
      union { uint4 u; __hip_bfloat16 e[8]; } ld;
      ld.u = *(const uint4*)&y0t[((size_t)(b << 13) + nn) * 64 + gc8 * 8];
#pragma unroll
      for (int j = 0; j < 8; j++){
        int ch = gc8 * 8 + j;
        feat2_s[h][gk][ch] = fmaxf(__bfloat162float(ld.e[j]) * sc0s[ch] + sh0s[ch], 0.0f);
      }
    }
    __syncthreads();
    {
      float fv[16];
#pragma unroll
      for (int kk = 0; kk < 16; kk++) fv[kk] = feat2_s[h][kk][cc];
      union { uint4 u; __hip_bfloat16 e[8]; } pk;
#pragma unroll
      for (int q2 = 0; q2 < 8; q2++){
        int q = qh * 8 + q2;
        float a2 = 0.0f;
#pragma unroll
        for (int kk = 0; kk < 16; kk++) a2 = fmaf(fv[kk], mat3_s[sl2][q][kk], a2);
        pk.e[q2] = __float2bfloat16(a2);
      }
      int ss = (st << 4) + sl2;
      *(uint4*)&agg[((size_t)(b << 11) + ss) * 1024 + cc * 16 + qh * 8] = pk.u;
    }
    __syncthreads();
  }
}

// =================================================================
// K6: MFMA cv GEMM
// =================================================================
__global__ __launch_bounds__(256) void k6_mfma(
    const __hip_bfloat16* __restrict__ agg, const __hip_bfloat16* __restrict__ cvb,
    float* __restrict__ hfka, float* __restrict__ stat)
{
  const int tid = threadIdx.x;
  const int b = blockIdx.x >> 5, stile = blockIdx.x & 31;
  const int wv = tid >> 6, l = tid & 63;
  const int lr = l & 15, lg = l >> 4;
  const int sw = (stile << 6) + (wv << 4);

  f32x4 acc[4];
#pragma unroll
  for (int i = 0; i < 4; i++) acc[i] = (f32x4){0.f, 0.f, 0.f, 0.f};

  const __hip_bfloat16* brow = agg + ((size_t)(b << 11) + sw + lr) * 1024 + lg * 8;
  const __hip_bfloat16* arow = cvb + (size_t)lr * 1024 + lg * 8;

#pragma unroll 4
  for (int ks = 0; ks < 32; ks++){
    bf16x8 B = *(const bf16x8*)(brow + ks * 32);
    bf16x8 A[4];
#pragma unroll
    for (int mf = 0; mf < 4; mf++) A[mf] = *(const bf16x8*)(arow + mf * 16384 + ks * 32);
#pragma unroll
    for (int mf = 0; mf < 4; mf++)
      acc[mf] = __builtin_amdgcn_mfma_f32_16x16x32_bf16(A[mf], B, acc[mf], 0, 0, 0);
  }

  const int s = sw + lr;
#pragma unroll
  for (int mf = 0; mf < 4; mf++){
    const int m0 = mf * 16 + lg * 4;
    float4 v = make_float4(acc[mf][0], acc[mf][1], acc[mf][2], acc[mf][3]);
    *(float4*)&hfka[((size_t)(b << 11) + s) * 64 + m0] = v;
#pragma unroll
    for (int r = 0; r < 4; r++){
      float ss = acc[mf][r], qq = ss * ss;
#pragma unroll
      for (int off = 8; off >= 1; off >>= 1){
        ss += __shfl_xor(ss, off, 16);
        qq += __shfl_xor(qq, off, 16);
      }
      if (lr == 0){
        atomicAdd(&stat[ST_S_BN1 + m0 + r], ss);
        atomicAdd(&stat[ST_Q_BN1 + m0 + r], qq);
      }
    }
  }
}

// =================================================================
// K7: MFMA cv2
// =================================================================
__global__ __launch_bounds__(256) void k7_mfma(
    const float* __restrict__ hfka, const __hip_bfloat16* __restrict__ cv2b,
    const float* __restrict__ bias, const float* __restrict__ stat_ro,
    __hip_bfloat16* __restrict__ h2, float* __restrict__ stat)
{
  const int tid = threadIdx.x;
  const int b = blockIdx.x >> 5, stile = blockIdx.x & 31;
  const int s0 = stile << 6;
  const int wv = tid >> 6, l = tid & 63;
  const int lr = l & 15, lg = l >> 4;

  float s1r[2][8], h1r[2][8];
#pragma unroll
  for (int ks = 0; ks < 2; ks++)
#pragma unroll
    for (int j = 0; j < 8; j++){
      int ch = ks * 32 + lg * 8 + j;
      s1r[ks][j] = stat_ro[ST_SC_BN1 + ch];
      h1r[ks][j] = stat_ro[ST_SH_BN1 + ch];
    }

  bf16x8 B[2][4];
#pragma unroll
  for (int ks = 0; ks < 2; ks++)
#pragma unroll
    for (int nf = 0; nf < 4; nf++){
      int s = s0 + nf * 16 + lr;
      const float* hp = hfka + ((size_t)(b << 11) + s) * 64 + ks * 32 + lg * 8;
      float4 v0 = *(const float4*)hp;
      float4 v1 = *(const float4*)(hp + 4);
      float vv[8] = {v0.x, v0.y, v0.z, v0.w, v1.x, v1.y, v1.z, v1.w};
      union { bf16x8 f; __hip_bfloat16 e[8]; } pk;
#pragma unroll
      for (int j = 0; j < 8; j++)
        pk.e[j] = __float2bfloat16(fmaxf(vv[j] * s1r[ks][j] + h1r[ks][j], 0.0f));
      B[ks][nf] = pk.f;
    }

  f32x4 acc[4][4];
#pragma unroll
  for (int i = 0; i < 4; i++)
#pragma unroll
    for (int j = 0; j < 4; j++) acc[i][j] = (f32x4){0.f, 0.f, 0.f, 0.f};

  const __hip_bfloat16* arow = cv2b + (size_t)(wv * 64 + lr) * 64 + lg * 8;
#pragma unroll
  for (int ks = 0; ks < 2; ks++){
    bf16x8 A[4];
#pragma unroll
    for (int mf = 0; mf < 4; mf++) A[mf] = *(const bf16x8*)(arow + mf * 1024 + ks * 32);
#pragma unroll
    for (int mf = 0; mf < 4; mf++)
#pragma unroll
      for (int nf = 0; nf < 4; nf++)
        acc[mf][nf] = __builtin_amdgcn_mfma_f32_16x16x32_bf16(A[mf], B[ks][nf], acc[mf][nf], 0, 0, 0);
  }

#pragma unroll
  for (int mf = 0; mf < 4; mf++){
    const int m0 = wv * 64 + mf * 16 + lg * 4;
    float bv[4];
#pragma unroll
    for (int r = 0; r < 4; r++) bv[r] = bias[m0 + r];
#pragma unroll
    for (int nf = 0; nf < 4; nf++){
      int s = s0 + nf * 16 + lr;
      union { uint2 u; __hip_bfloat16 e[4]; } pk;
#pragma unroll
      for (int r = 0; r < 4; r++){
        acc[mf][nf][r] += bv[r];
        pk.e[r] = __float2bfloat16(acc[mf][nf][r]);
      }
      *(uint2*)&h2[((size_t)(b << 11) + s) * 256 + m0] = pk.u;
    }
#pragma unroll
    for (int r = 0; r < 4; r++){
      float ss = 0.f, qq = 0.f;
#pragma unroll
      for (int nf = 0; nf < 4; nf++){ float v = acc[mf][nf][r]; ss += v; qq += v * v; }
#pragma unroll
      for (int off = 8; off >= 1; off >>= 1){
        ss += __shfl_xor(ss, off, 16);
        qq += __shfl_xor(qq, off, 16);
      }
      if (lr == 0){
        atomicAdd(&stat[ST_S_BN2 + m0 + r], ss);
        atomicAdd(&stat[ST_Q_BN2 + m0 + r], qq);
      }
    }
  }
}

// =================================================================
// K8: final
// =================================================================
__global__ __launch_bounds__(256) void k_final(
    const __hip_bfloat16* __restrict__ sct, const __hip_bfloat16* __restrict__ h2,
    const int* __restrict__ nbr, const float* __restrict__ stat, float* __restrict__ out)
{
  __shared__ int   idx_s[256];
  __shared__ float tile_s[16][257];
  const int tid = threadIdx.x;
  const int b  = blockIdx.x >> 7;
  const int st = blockIdx.x & 127;
  const int s0 = st << 4;
  idx_s[tid] = nbr[((size_t)(b << 11) + s0) * 16 + tid];
  const int sl = tid >> 4, cg = tid & 15, ch0 = cg << 4;

  float ssc[16], hsc[16], s2v[16], h2v[16];
#pragma unroll
  for (int j = 0; j < 16; j++){
    ssc[j] = stat[ST_SC_SC  + ch0 + j];
    hsc[j] = stat[ST_SH_SC  + ch0 + j];
    s2v[j] = stat[ST_SC_BN2 + ch0 + j];
    h2v[j] = stat[ST_SH_BN2 + ch0 + j];
  }
  __syncthreads();

  float mx[16];
#pragma unroll
  for (int j = 0; j < 16; j++) mx[j] = -3.4e38f;
  for (int k = 0; k < 16; k++){
    int nn = idx_s[sl * 16 + k];
    const uint4* p = (const uint4*)&sct[((size_t)(b << 13) + nn) * 256 + ch0];
    union { uint4 u; __hip_bfloat16 e[8]; } a0, a1;
    a0.u = p[0]; a1.u = p[1];
#pragma unroll
    for (int j = 0; j < 8; j++){
      mx[j]     = fmaxf(mx[j],     __bfloat162float(a0.e[j]) * ssc[j]     + hsc[j]);
      mx[j + 8] = fmaxf(mx[j + 8], __bfloat162float(a1.e[j]) * ssc[j + 8] + hsc[j + 8]);
    }
  }
  {
    const uint4* p = (const uint4*)&h2[((size_t)(b << 11) + s0 + sl) * 256 + ch0];
    union { uint4 u; __hip_bfloat16 e[8]; } a0, a1;
    a0.u = p[0]; a1.u = p[1];
#pragma unroll
    for (int j = 0; j < 8; j++){
      tile_s[sl][ch0 + j]     = fmaxf(__bfloat162float(a0.e[j]) * s2v[j]     + h2v[j]     + mx[j], 0.0f);
      tile_s[sl][ch0 + 8 + j] = fmaxf(__bfloat162float(a1.e[j]) * s2v[j + 8] + h2v[j + 8] + mx[j + 8], 0.0f);
    }
  }
  __syncthreads();
  const int o = tid;
#pragma unroll
  for (int p4 = 0; p4 < 4; p4++){
    float4 v = make_float4(tile_s[p4 * 4 + 0][o], tile_s[p4 * 4 + 1][o],
                           tile_s[p4 * 4 + 2][o], tile_s[p4 * 4 + 3][o]);
    *(float4*)&out[((size_t)(b << 8) + o) * 2048 + s0 + p4 * 4] = v;
  }
}

// =================================================================
extern "C" void kernel_launch(void* const* d_in, const int* in_sizes, int n_in,
                              void* d_out, int out_size, void* d_ws, size_t ws_size,
                              hipStream_t stream)
{
  (void)in_sizes; (void)n_in; (void)out_size; (void)ws_size;
  const float* x     = (const float*)d_in[0];
  const float* pos   = (const float*)d_in[1];
  const float* sup   = (const float*)d_in[2];
  const int*   nbr   = (const int*)d_in[3];
  const float* cv0w  = (const float*)d_in[5];
  const float* cv0b  = (const float*)d_in[6];
  const float* bn0g  = (const float*)d_in[7];
  const float* bn0b  = (const float*)d_in[8];
  const float* fc1   = (const float*)d_in[9];
  const float* fc2   = (const float*)d_in[10];
  const float* fc3   = (const float*)d_in[11];
  const float* in1g  = (const float*)d_in[12];
  const float* in1b  = (const float*)d_in[13];
  const float* in2g  = (const float*)d_in[14];
  const float* in2b  = (const float*)d_in[15];
  const float* alp   = (const float*)d_in[16];
  const float* bet   = (const float*)d_in[17];
  const float* nrp   = (const float*)d_in[18];
  const float* cvw   = (const float*)d_in[19];
  const float* bn1g  = (const float*)d_in[20];
  const float* bn1b  = (const float*)d_in[21];
  const float* cv2w  = (const float*)d_in[22];
  const float* cv2bi = (const float*)d_in[23];
  const float* bn2g  = (const float*)d_in[24];
  const float* bn2b  = (const float*)d_in[25];
  const float* scw   = (const float*)d_in[26];
  const float* scb   = (const float*)d_in[27];
  const float* bnscg = (const float*)d_in[28];
  const float* bnscb = (const float*)d_in[29];

  char* w = (char*)d_ws;
  __hip_bfloat16* sct  = (__hip_bfloat16*)(w);                  //  67108864 B
  __hip_bfloat16* y0t  = (__hip_bfloat16*)(w + 67108864);       //  16777216 B
  __hip_bfloat16* aggp = (__hip_bfloat16*)(w + 83886080);       //  67108864 B
  __hip_bfloat16* xb   = (__hip_bfloat16*)(w + 83886080);       //  33554432 B (dead after k1)
  float*          hfka = (float*)(w + 150994944);               //   8388608 B
  __hip_bfloat16* h2   = (__hip_bfloat16*)(w + 159383552);      //  16777216 B
  __hip_bfloat16* wb   = (__hip_bfloat16*)(w + 176160768);      //     81920 B
  __hip_bfloat16* cvb  = (__hip_bfloat16*)(w + 176242688);      //    131072 B
  __hip_bfloat16* cv2b = (__hip_bfloat16*)(w + 176373760);      //     32768 B
  float*          stat = (float*)(w + 192937984UL);             //     18 KB

  hipMemsetAsync(stat, 0, ST_ACC_END * sizeof(float), stream);

  k_prep_w<<<480, 256, 0, stream>>>(cv0w, scw, cvw, cv2w, wb, cvb, cv2b);
  k_xpose<<<2048, 256, 0, stream>>>(x, xb);
  k1_mfma<<<2048, 256, 0, stream>>>(xb, wb, cv0b, scb, y0t, sct, stat);
  k_finalize<<<1, 256, 0, stream>>>(stat + ST_S_BN0, stat + ST_Q_BN0, bn0g, bn0b,
                                    1.0f / 131072.0f, 64, 64, stat + ST_SC_BN0, stat + ST_SH_BN0);
  k_finalize<<<1, 256, 0, stream>>>(stat + ST_S_SC, stat + ST_Q_SC, bnscg, bnscb,
                                    1.0f / 131072.0f, 256, 256, stat + ST_SC_SC, stat + ST_SH_SC);
  k_in1_stats<<<2048, 256, 0, stream>>>(pos, sup, nbr, fc1, nrp, stat);
  k_finalize<<<1, 256, 0, stream>>>(stat + ST_S_IN1, stat + ST_Q_IN1, in1g, in1b,
                                    1.0f / 32768.0f, 256, 16, stat + ST_SC_IN1, stat + ST_SH_IN1);
  k_in2_stats<<<2048, 256, 0, stream>>>(pos, sup, nbr, fc1, fc2, alp, bet, nrp, stat);
  k_finalize<<<1, 256, 0, stream>>>(stat + ST_S_IN2, stat + ST_Q_IN2, in2g, in2b,
                                    1.0f / 32768.0f, 256, 16, stat + ST_SC_IN2, stat + ST_SH_IN2);
  k_fka<<<2048, 256, 0, stream>>>(pos, sup, nbr, fc1, fc2, fc3, alp, bet, nrp, y0t, stat, aggp);
  k6_mfma<<<512, 256, 0, stream>>>(aggp, cvb, hfka, stat);
  k_finalize<<<1, 256, 0, stream>>>(stat + ST_S_BN1, stat + ST_Q_BN1, bn1g, bn1b,
                                    1.0f / 32768.0f, 64, 64, stat + ST_SC_BN1, stat + ST_SH_BN1);
  k7_mfma<<<512, 256, 0, stream>>>(hfka, cv2b, cv2bi, stat, h2, stat);
  k_finalize<<<1, 256, 0, stream>>>(stat + ST_S_BN2, stat + ST_Q_BN2, bn2g, bn2b,
                                    1.0f / 32768.0f, 256, 256, stat + ST_SC_BN2, stat + ST_SH_BN2);
  k_final<<<2048, 256, 0, stream>>>(sct, h2, nbr, stat, (float*)d_out);
}

// Round 4
// 1004.379 us; speedup vs baseline: 1.4867x; 1.4118x over previous
//
#include <hip/hip_runtime.h>
#include <hip/hip_bf16.h>

#define DEV static __device__ __forceinline__

typedef __attribute__((ext_vector_type(8))) short bf16x8;
typedef __attribute__((ext_vector_type(4))) float f32x4;

// ---------------- stat layout (floats, inside ws) ----------------
// only scale/shift live here now (partials are in big ws regions)
#define ST_SC_BN0  0
#define ST_SH_BN0  64
#define ST_SC_SC   128
#define ST_SH_SC   384
#define ST_SC_IN1  640
#define ST_SH_IN1  896
#define ST_SC_IN2  1152
#define ST_SH_IN2  1408
#define ST_SC_BN1  1664
#define ST_SH_BN1  1728
#define ST_SC_BN2  1792
#define ST_SH_BN2  2048

DEV float rsum16(float v){
#pragma unroll
  for (int off = 8; off >= 1; off >>= 1) v += __shfl_xor(v, off, 16);
  return v;
}
DEV float rmax16(float v){
#pragma unroll
  for (int off = 8; off >= 1; off >>= 1) v = fmaxf(v, __shfl_xor(v, off, 16));
  return v;
}

// =================================================================
// P0: weight conversion f32 -> bf16.
// =================================================================
__global__ __launch_bounds__(256) void k_prep_w(
    const float* __restrict__ cv0w, const float* __restrict__ scw,
    const float* __restrict__ cvw,  const float* __restrict__ cv2w,
    __hip_bfloat16* __restrict__ wb, __hip_bfloat16* __restrict__ cvb,
    __hip_bfloat16* __restrict__ cv2b)
{
  int i = blockIdx.x * 256 + threadIdx.x;   // 0 .. 122879
  if (i < 40960){
    float v = (i < 8192) ? cv0w[i] : scw[i - 8192];
    wb[i] = __float2bfloat16(v);
  } else if (i < 106496){
    cvb[i - 40960] = __float2bfloat16(cvw[i - 40960]);
  } else {
    cv2b[i - 106496] = __float2bfloat16(cv2w[i - 106496]);
  }
}

// =================================================================
// P1: transpose x (b,128,8192) f32 -> xb (b,8192,128) bf16
// =================================================================
__global__ __launch_bounds__(256) void k_xpose(
    const float* __restrict__ x, __hip_bfloat16* __restrict__ xb)
{
  __shared__ float t[128][65];
  const int tid = threadIdx.x;
  const int b = blockIdx.x >> 7, nt = blockIdx.x & 127;
  const int n0 = nt << 6;
#pragma unroll
  for (int p = 0; p < 8; p++){
    int row = (p << 4) + (tid >> 4);
    float4 v = *(const float4*)&x[(((size_t)b * 128 + row) << 13) + n0 + ((tid & 15) << 2)];
    t[row][(tid & 15) * 4 + 0] = v.x;
    t[row][(tid & 15) * 4 + 1] = v.y;
    t[row][(tid & 15) * 4 + 2] = v.z;
    t[row][(tid & 15) * 4 + 3] = v.w;
  }
  __syncthreads();
  const int k8 = tid & 15;
#pragma unroll
  for (int p = 0; p < 4; p++){
    int n = (p << 4) + (tid >> 4);
    union { uint4 u; __hip_bfloat16 e[8]; } pk;
#pragma unroll
    for (int j = 0; j < 8; j++) pk.e[j] = __float2bfloat16(t[k8 * 8 + j][n]);
    *(uint4*)&xb[((size_t)(b << 13) + n0 + n) * 128 + k8 * 8] = pk.u;
  }
}

// =================================================================
// K1: MFMA cv0+shortcut GEMM, no LDS. Partials (no atomics):
// p1[blk][640]: [ch]=sum, [320+ch]=sumsq, ch in 0..319.
// =================================================================
__global__ __launch_bounds__(256) void k1_mfma(
    const __hip_bfloat16* __restrict__ xb, const __hip_bfloat16* __restrict__ wb,
    const float* __restrict__ cv0b, const float* __restrict__ scb,
    __hip_bfloat16* __restrict__ y0t, __hip_bfloat16* __restrict__ sct,
    float* __restrict__ p1)
{
  const int tid = threadIdx.x;
  const int b = blockIdx.x >> 7, nt = blockIdx.x & 127;
  const int n0 = nt << 6;
  const int wv = tid >> 6, l = tid & 63;
  const int lr = l & 15, lg = l >> 4;
  float* p1row = p1 + (size_t)blockIdx.x * 640;

  f32x4 acc[5][4];
#pragma unroll
  for (int i = 0; i < 5; i++)
#pragma unroll
    for (int j = 0; j < 4; j++) acc[i][j] = (f32x4){0.f, 0.f, 0.f, 0.f};

  const __hip_bfloat16* xrow = xb + ((size_t)(b << 13) + n0 + lr) * 128 + lg * 8;
  const __hip_bfloat16* wrow = wb + (size_t)(wv * 80 + lr) * 128 + lg * 8;

#pragma unroll
  for (int ks = 0; ks < 4; ks++){
    bf16x8 B[4], A[5];
#pragma unroll
    for (int nf = 0; nf < 4; nf++) B[nf] = *(const bf16x8*)(xrow + nf * 2048 + ks * 32);
#pragma unroll
    for (int mf = 0; mf < 5; mf++) A[mf] = *(const bf16x8*)(wrow + mf * 2048 + ks * 32);
#pragma unroll
    for (int mf = 0; mf < 5; mf++)
#pragma unroll
      for (int nf = 0; nf < 4; nf++)
        acc[mf][nf] = __builtin_amdgcn_mfma_f32_16x16x32_bf16(A[mf], B[nf], acc[mf][nf], 0, 0, 0);
  }

#pragma unroll
  for (int mf = 0; mf < 5; mf++){
    const int m0 = wv * 80 + mf * 16 + lg * 4;
    float bv[4];
#pragma unroll
    for (int r = 0; r < 4; r++){
      int m = m0 + r;
      bv[r] = (m < 64) ? cv0b[m] : scb[m - 64];
    }
#pragma unroll
    for (int nf = 0; nf < 4; nf++)
#pragma unroll
      for (int r = 0; r < 4; r++) acc[mf][nf][r] += bv[r];

#pragma unroll
    for (int nf = 0; nf < 4; nf++){
      int n = n0 + nf * 16 + lr;
      union { uint2 u; __hip_bfloat16 e[4]; } pk;
#pragma unroll
      for (int r = 0; r < 4; r++) pk.e[r] = __float2bfloat16(acc[mf][nf][r]);
      if (m0 < 64)
        *(uint2*)&y0t[((size_t)(b << 13) + n) * 64 + m0] = pk.u;
      else
        *(uint2*)&sct[((size_t)(b << 13) + n) * 256 + (m0 - 64)] = pk.u;
    }
#pragma unroll
    for (int r = 0; r < 4; r++){
      float ss = 0.f, qq = 0.f;
#pragma unroll
      for (int nf = 0; nf < 4; nf++){ float v = acc[mf][nf][r]; ss += v; qq += v * v; }
#pragma unroll
      for (int off = 8; off >= 1; off >>= 1){
        ss += __shfl_xor(ss, off, 16);
        qq += __shfl_xor(qq, off, 16);
      }
      if (lr == 0){
        int ch = m0 + r;
        p1row[ch]       = ss;
        p1row[320 + ch] = qq;
      }
    }
  }
}

// =================================================================
// flat reducer + finalize: sums part[row][sum_off+ch], part[row][sq_off+ch]
// over nblk rows; ch = blockIdx*16 + lane&15; 64 threads.
// =================================================================
__global__ __launch_bounds__(64) void k_red_fin(
    const float* __restrict__ part, int nblk, int rowstride,
    int sum_off, int sq_off,
    const float* __restrict__ g, const float* __restrict__ bb,
    float inv_cnt, int gmod,
    float* __restrict__ scale, float* __restrict__ shift)
{
  const int lane = threadIdx.x;
  const int ch = (blockIdx.x << 4) + (lane & 15);
  const int bl = lane >> 4;
  float s = 0.f, q = 0.f;
  for (int k = bl; k < nblk; k += 4){
    const float* row = part + (size_t)k * rowstride;
    s += row[sum_off + ch];
    q += row[sq_off + ch];
  }
  s += __shfl_xor(s, 16, 64); s += __shfl_xor(s, 32, 64);
  q += __shfl_xor(q, 16, 64); q += __shfl_xor(q, 32, 64);
  if (bl == 0){
    float m  = s * inv_cnt;
    float v  = q * inv_cnt - m * m;
    float sc = g[ch % gmod] * rsqrtf(v + 1e-5f);
    scale[ch] = sc;
    shift[ch] = bb[ch % gmod] - m * sc;
  }
}

// =================================================================
// per-batch reducer (IN1/IN2): part rows [32]: [q]=sum, [16+q]=sq.
// grid = 16 (b); rows for b are [b*rows_per_b, ...). 64 threads.
// =================================================================
__global__ __launch_bounds__(64) void k_red_fin_b(
    const float* __restrict__ part, int rows_per_b,
    const float* __restrict__ g, const float* __restrict__ bb, float inv_cnt,
    float* __restrict__ scale, float* __restrict__ shift)
{
  const int lane = threadIdx.x;
  const int b = blockIdx.x;
  const int q = lane & 15, bl = lane >> 4;
  const float* base = part + (size_t)b * rows_per_b * 32;
  float s = 0.f, sq = 0.f;
  for (int k = bl; k < rows_per_b; k += 4){
    s  += base[k * 32 + q];
    sq += base[k * 32 + 16 + q];
  }
  s  += __shfl_xor(s, 16, 64);  s  += __shfl_xor(s, 32, 64);
  sq += __shfl_xor(sq, 16, 64); sq += __shfl_xor(sq, 32, 64);
  if (bl == 0){
    float m  = s * inv_cnt;
    float v  = sq * inv_cnt - m * m;
    float sc = g[q] * rsqrtf(v + 1e-5f);
    scale[b * 16 + q] = sc;
    shift[b * 16 + q] = bb[q] - m * sc;
  }
}

// =================================================================
// K3: IN1 stats -> pin1[blk*4+wv][32] (no atomics)
// =================================================================
__global__ __launch_bounds__(256) void k_in1_stats(
    const float* __restrict__ pos, const float* __restrict__ sup, const int* __restrict__ nbr,
    const float* __restrict__ fc1, const float* __restrict__ nrp, float* __restrict__ pin1)
{
  const int tid = threadIdx.x;
  const int b  = blockIdx.x >> 7;
  const int st = blockIdx.x & 127;
  const int sl = tid >> 4, k = tid & 15;
  const int s  = (st << 4) + sl;
  const int n  = nbr[((((size_t)b << 11) + s) << 4) + k];
  float* pr = pin1 + ((size_t)blockIdx.x * 4 + (tid >> 6)) * 32;
  const float inr = 1.0f / nrp[0];
  float p0 = (pos[((size_t)b * 3 + 0) * 8192 + n] - sup[((size_t)b * 3 + 0) * 2048 + s]) * inr;
  float p1 = (pos[((size_t)b * 3 + 1) * 8192 + n] - sup[((size_t)b * 3 + 1) * 2048 + s]) * inr;
  float p2 = (pos[((size_t)b * 3 + 2) * 8192 + n] - sup[((size_t)b * 3 + 2) * 2048 + s]) * inr;
#pragma unroll
  for (int q = 0; q < 16; q++){
    float z = fc1[q * 3] * p0 + fc1[q * 3 + 1] * p1 + fc1[q * 3 + 2] * p2;
    float a = z, c = z * z;
#pragma unroll
    for (int off = 32; off >= 1; off >>= 1){
      a += __shfl_xor(a, off, 64);
      c += __shfl_xor(c, off, 64);
    }
    if ((tid & 63) == q){
      pr[q]      = a;
      pr[16 + q] = c;
    }
  }
}

// =================================================================
// K4: IN2 stats -> pin2[blk*4+wv][32] (no atomics)
// =================================================================
__global__ __launch_bounds__(256) void k_in2_stats(
    const float* __restrict__ pos, const float* __restrict__ sup, const int* __restrict__ nbr,
    const float* __restrict__ fc1, const float* __restrict__ fc2,
    const float* __restrict__ alp, const float* __restrict__ bet, const float* __restrict__ nrp,
    const float* __restrict__ stat, float* __restrict__ pin2)
{
  __shared__ float fc2s[512];
  __shared__ float sc1s[16], sh1s[16];
  const int tid = threadIdx.x;
  const int b  = blockIdx.x >> 7;
  const int st = blockIdx.x & 127;
  fc2s[tid]       = fc2[tid];
  fc2s[tid + 256] = fc2[tid + 256];
  if (tid < 16){
    sc1s[tid] = stat[ST_SC_IN1 + (b << 4) + tid];
    sh1s[tid] = stat[ST_SH_IN1 + (b << 4) + tid];
  }
  __syncthreads();
  const int sl = tid >> 4, k = tid & 15;
  const int s  = (st << 4) + sl;
  const int n  = nbr[((((size_t)b << 11) + s) << 4) + k];
  float* pr = pin2 + ((size_t)blockIdx.x * 4 + (tid >> 6)) * 32;
  float t0 = pos[((size_t)b * 3 + 0) * 8192 + n] - sup[((size_t)b * 3 + 0) * 2048 + s];
  float t1 = pos[((size_t)b * 3 + 1) * 8192 + n] - sup[((size_t)b * 3 + 1) * 2048 + s];
  float t2 = pos[((size_t)b * 3 + 2) * 8192 + n] - sup[((size_t)b * 3 + 2) * 2048 + s];
  float dist = sqrtf(t0 * t0 + t1 * t1 + t2 * t2);
  float dw = 1.0f / (1.0f + expf(alp[0] * dist - bet[0]));
  float ssum = rsum16(dw);
  ssum += (ssum == 0.0f ? 1.0f : 0.0f) + 1e-6f;
  dw = dw / ssum * 16.0f;
  const float inr = 1.0f / nrp[0];
  float p0 = t0 * inr, p1 = t1 * inr, p2 = t2 * inr;
  float m1[16], mp1[16];
#pragma unroll
  for (int q = 0; q < 16; q++){
    float z = fc1[q * 3] * p0 + fc1[q * 3 + 1] * p1 + fc1[q * 3 + 2] * p2;
    m1[q] = fmaxf(z * sc1s[q] + sh1s[q], 0.0f);
  }
#pragma unroll
  for (int q = 0; q < 16; q++) mp1[q] = rmax16(m1[q] * dw);
#pragma unroll
  for (int q = 0; q < 16; q++){
    float z = 0.0f;
#pragma unroll
    for (int j = 0; j < 16; j++) z = fmaf(fc2s[q * 32 + j], m1[j], z);
#pragma unroll
    for (int j = 0; j < 16; j++) z = fmaf(fc2s[q * 32 + 16 + j], mp1[j], z);
    float a = z, c = z * z;
#pragma unroll
    for (int off = 32; off >= 1; off >>= 1){
      a += __shfl_xor(a, off, 64);
      c += __shfl_xor(c, off, 64);
    }
    if ((tid & 63) == q){
      pr[q]      = a;
      pr[16 + q] = c;
    }
  }
}

// =================================================================
// K5: FKA main
// =================================================================
__global__ __launch_bounds__(256) void k_fka(
    const float* __restrict__ pos, const float* __restrict__ sup, const int* __restrict__ nbr,
    const float* __restrict__ fc1, const float* __restrict__ fc2, const float* __restrict__ fc3,
    const float* __restrict__ alp, const float* __restrict__ bet, const float* __restrict__ nrp,
    const __hip_bfloat16* __restrict__ y0t, const float* __restrict__ stat,
    __hip_bfloat16* __restrict__ agg)
{
  __shared__ float fc2s[512], fc3s[512];
  __shared__ float sc1s[16], sh1s[16], sc2s[16], sh2s[16];
  __shared__ float sc0s[64], sh0s[64];
  __shared__ float mat3_s[16][16][17];
  __shared__ float feat2_s[2][16][65];
  __shared__ int   idx_s[16][16];

  const int tid = threadIdx.x;
  const int b  = blockIdx.x >> 7;
  const int st = blockIdx.x & 127;
  fc2s[tid]       = fc2[tid];
  fc2s[tid + 256] = fc2[tid + 256];
  fc3s[tid]       = fc3[tid];
  fc3s[tid + 256] = fc3[tid + 256];
  if (tid < 16){
    sc1s[tid] = stat[ST_SC_IN1 + (b << 4) + tid];
    sh1s[tid] = stat[ST_SH_IN1 + (b << 4) + tid];
    sc2s[tid] = stat[ST_SC_IN2 + (b << 4) + tid];
    sh2s[tid] = stat[ST_SH_IN2 + (b << 4) + tid];
  }
  if (tid < 64){
    sc0s[tid] = stat[ST_SC_BN0 + tid];
    sh0s[tid] = stat[ST_SH_BN0 + tid];
  }
  const int sl = tid >> 4, k = tid & 15;
  const int s  = (st << 4) + sl;
  const int n  = nbr[((((size_t)b << 11) + s) << 4) + k];
  idx_s[sl][k] = n;
  __syncthreads();

  float t0 = pos[((size_t)b * 3 + 0) * 8192 + n] - sup[((size_t)b * 3 + 0) * 2048 + s];
  float t1 = pos[((size_t)b * 3 + 1) * 8192 + n] - sup[((size_t)b * 3 + 1) * 2048 + s];
  float t2 = pos[((size_t)b * 3 + 2) * 8192 + n] - sup[((size_t)b * 3 + 2) * 2048 + s];
  float dist = sqrtf(t0 * t0 + t1 * t1 + t2 * t2);
  float dw = 1.0f / (1.0f + expf(alp[0] * dist - bet[0]));
  float ssum = rsum16(dw);
  ssum += (ssum == 0.0f ? 1.0f : 0.0f) + 1e-6f;
  dw = dw / ssum * 16.0f;
  const float inr = 1.0f / nrp[0];
  float p0 = t0 * inr, p1 = t1 * inr, p2 = t2 * inr;
  float m1[16], mp1[16];
#pragma unroll
  for (int q = 0; q < 16; q++){
    float z = fc1[q * 3] * p0 + fc1[q * 3 + 1] * p1 + fc1[q * 3 + 2] * p2;
    m1[q] = fmaxf(z * sc1s[q] + sh1s[q], 0.0f);
  }
#pragma unroll
  for (int q = 0; q < 16; q++) mp1[q] = rmax16(m1[q] * dw);
  float m2[16], mp2[16];
#pragma unroll
  for (int q = 0; q < 16; q++){
    float z = 0.0f;
#pragma unroll
    for (int j = 0; j < 16; j++) z = fmaf(fc2s[q * 32 + j], m1[j], z);
#pragma unroll
    for (int j = 0; j < 16; j++) z = fmaf(fc2s[q * 32 + 16 + j], mp1[j], z);
    m2[q] = fmaxf(z * sc2s[q] + sh2s[q], 0.0f);
  }
#pragma unroll
  for (int q = 0; q < 16; q++) mp2[q] = rmax16(m2[q] * dw);
#pragma unroll
  for (int q = 0; q < 16; q++){
    float z = 0.0f;
#pragma unroll
    for (int j = 0; j < 16; j++) z = fmaf(fc3s[q * 32 + j], m2[j], z);
#pragma unroll
    for (int j = 0; j < 16; j++) z = fmaf(fc3s[q * 32 + 16 + j], mp2[j], z);
    mat3_s[sl][q][k] = fmaxf(z, 0.0f) * dw;
  }
  __syncthreads();

  const int h   = tid >> 7;
  const int r7  = tid & 127;
  const int gk  = r7 >> 3;
  const int gc8 = r7 & 7;
  const int cc  = r7 >> 1;
  const int qh  = r7 & 1;

  for (int it = 0; it < 8; it++){
    const int sl2 = it * 2 + h;
    {
      int nn = idx_s[sl2][gk];
      union { uint4 u; __hip_bfloat16 e[8]; } ld;
      ld.u = *(const uint4*)&y0t[((size_t)(b << 13) + nn) * 64 + gc8 * 8];
#pragma unroll
      for (int j = 0; j < 8; j++){
        int ch = gc8 * 8 + j;
        feat2_s[h][gk][ch] = fmaxf(__bfloat162float(ld.e[j]) * sc0s[ch] + sh0s[ch], 0.0f);
      }
    }
    __syncthreads();
    {
      float fv[16];
#pragma unroll
      for (int kk = 0; kk < 16; kk++) fv[kk] = feat2_s[h][kk][cc];
      union { uint4 u; __hip_bfloat16 e[8]; } pk;
#pragma unroll
      for (int q2 = 0; q2 < 8; q2++){
        int q = qh * 8 + q2;
        float a2 = 0.0f;
#pragma unroll
        for (int kk = 0; kk < 16; kk++) a2 = fmaf(fv[kk], mat3_s[sl2][q][kk], a2);
        pk.e[q2] = __float2bfloat16(a2);
      }
      int ss = (st << 4) + sl2;
      *(uint4*)&agg[((size_t)(b << 11) + ss) * 1024 + cc * 16 + qh * 8] = pk.u;
    }
    __syncthreads();
  }
}

// =================================================================
// K6: MFMA cv GEMM. Partials: p6[blk*4+wv][128]: [ch]=sum,[64+ch]=sq
// =================================================================
__global__ __launch_bounds__(256) void k6_mfma(
    const __hip_bfloat16* __restrict__ agg, const __hip_bfloat16* __restrict__ cvb,
    float* __restrict__ hfka, float* __restrict__ p6)
{
  const int tid = threadIdx.x;
  const int b = blockIdx.x >> 5, stile = blockIdx.x & 31;
  const int wv = tid >> 6, l = tid & 63;
  const int lr = l & 15, lg = l >> 4;
  const int sw = (stile << 6) + (wv << 4);
  float* p6row = p6 + ((size_t)blockIdx.x * 4 + wv) * 128;

  f32x4 acc[4];
#pragma unroll
  for (int i = 0; i < 4; i++) acc[i] = (f32x4){0.f, 0.f, 0.f, 0.f};

  const __hip_bfloat16* brow = agg + ((size_t)(b << 11) + sw + lr) * 1024 + lg * 8;
  const __hip_bfloat16* arow = cvb + (size_t)lr * 1024 + lg * 8;

#pragma unroll 4
  for (int ks = 0; ks < 32; ks++){
    bf16x8 B = *(const bf16x8*)(brow + ks * 32);
    bf16x8 A[4];
#pragma unroll
    for (int mf = 0; mf < 4; mf++) A[mf] = *(const bf16x8*)(arow + mf * 16384 + ks * 32);
#pragma unroll
    for (int mf = 0; mf < 4; mf++)
      acc[mf] = __builtin_amdgcn_mfma_f32_16x16x32_bf16(A[mf], B, acc[mf], 0, 0, 0);
  }

  const int s = sw + lr;
#pragma unroll
  for (int mf = 0; mf < 4; mf++){
    const int m0 = mf * 16 + lg * 4;
    float4 v = make_float4(acc[mf][0], acc[mf][1], acc[mf][2], acc[mf][3]);
    *(float4*)&hfka[((size_t)(b << 11) + s) * 64 + m0] = v;
#pragma unroll
    for (int r = 0; r < 4; r++){
      float ss = acc[mf][r], qq = ss * ss;
#pragma unroll
      for (int off = 8; off >= 1; off >>= 1){
        ss += __shfl_xor(ss, off, 16);
        qq += __shfl_xor(qq, off, 16);
      }
      if (lr == 0){
        p6row[m0 + r]      = ss;
        p6row[64 + m0 + r] = qq;
      }
    }
  }
}

// =================================================================
// K7: MFMA cv2. Partials: p7[blk][512]: [ch]=sum, [256+ch]=sq
// =================================================================
__global__ __launch_bounds__(256) void k7_mfma(
    const float* __restrict__ hfka, const __hip_bfloat16* __restrict__ cv2b,
    const float* __restrict__ bias, const float* __restrict__ stat_ro,
    __hip_bfloat16* __restrict__ h2, float* __restrict__ p7)
{
  const int tid = threadIdx.x;
  const int b = blockIdx.x >> 5, stile = blockIdx.x & 31;
  const int s0 = stile << 6;
  const int wv = tid >> 6, l = tid & 63;
  const int lr = l & 15, lg = l >> 4;
  float* p7row = p7 + (size_t)blockIdx.x * 512;

  float s1r[2][8], h1r[2][8];
#pragma unroll
  for (int ks = 0; ks < 2; ks++)
#pragma unroll
    for (int j = 0; j < 8; j++){
      int ch = ks * 32 + lg * 8 + j;
      s1r[ks][j] = stat_ro[ST_SC_BN1 + ch];
      h1r[ks][j] = stat_ro[ST_SH_BN1 + ch];
    }

  bf16x8 B[2][4];
#pragma unroll
  for (int ks = 0; ks < 2; ks++)
#pragma unroll
    for (int nf = 0; nf < 4; nf++){
      int s = s0 + nf * 16 + lr;
      const float* hp = hfka + ((size_t)(b << 11) + s) * 64 + ks * 32 + lg * 8;
      float4 v0 = *(const float4*)hp;
      float4 v1 = *(const float4*)(hp + 4);
      float vv[8] = {v0.x, v0.y, v0.z, v0.w, v1.x, v1.y, v1.z, v1.w};
      union { bf16x8 f; __hip_bfloat16 e[8]; } pk;
#pragma unroll
      for (int j = 0; j < 8; j++)
        pk.e[j] = __float2bfloat16(fmaxf(vv[j] * s1r[ks][j] + h1r[ks][j], 0.0f));
      B[ks][nf] = pk.f;
    }

  f32x4 acc[4][4];
#pragma unroll
  for (int i = 0; i < 4; i++)
#pragma unroll
    for (int j = 0; j < 4; j++) acc[i][j] = (f32x4){0.f, 0.f, 0.f, 0.f};

  const __hip_bfloat16* arow = cv2b + (size_t)(wv * 64 + lr) * 64 + lg * 8;
#pragma unroll
  for (int ks = 0; ks < 2; ks++){
    bf16x8 A[4];
#pragma unroll
    for (int mf = 0; mf < 4; mf++) A[mf] = *(const bf16x8*)(arow + mf * 1024 + ks * 32);
#pragma unroll
    for (int mf = 0; mf < 4; mf++)
#pragma unroll
      for (int nf = 0; nf < 4; nf++)
        acc[mf][nf] = __builtin_amdgcn_mfma_f32_16x16x32_bf16(A[mf], B[ks][nf], acc[mf][nf], 0, 0, 0);
  }

#pragma unroll
  for (int mf = 0; mf < 4; mf++){
    const int m0 = wv * 64 + mf * 16 + lg * 4;
    float bv[4];
#pragma unroll
    for (int r = 0; r < 4; r++) bv[r] = bias[m0 + r];
#pragma unroll
    for (int nf = 0; nf < 4; nf++){
      int s = s0 + nf * 16 + lr;
      union { uint2 u; __hip_bfloat16 e[4]; } pk;
#pragma unroll
      for (int r = 0; r < 4; r++){
        acc[mf][nf][r] += bv[r];
        pk.e[r] = __float2bfloat16(acc[mf][nf][r]);
      }
      *(uint2*)&h2[((size_t)(b << 11) + s) * 256 + m0] = pk.u;
    }
#pragma unroll
    for (int r = 0; r < 4; r++){
      float ss = 0.f, qq = 0.f;
#pragma unroll
      for (int nf = 0; nf < 4; nf++){ float v = acc[mf][nf][r]; ss += v; qq += v * v; }
#pragma unroll
      for (int off = 8; off >= 1; off >>= 1){
        ss += __shfl_xor(ss, off, 16);
        qq += __shfl_xor(qq, off, 16);
      }
      if (lr == 0){
        p7row[m0 + r]       = ss;
        p7row[256 + m0 + r] = qq;
      }
    }
  }
}

// =================================================================
// K8: final
// =================================================================
__global__ __launch_bounds__(256) void k_final(
    const __hip_bfloat16* __restrict__ sct, const __hip_bfloat16* __restrict__ h2,
    const int* __restrict__ nbr, const float* __restrict__ stat, float* __restrict__ out)
{
  __shared__ int   idx_s[256];
  __shared__ float tile_s[16][257];
  const int tid = threadIdx.x;
  const int b  = blockIdx.x >> 7;
  const int st = blockIdx.x & 127;
  const int s0 = st << 4;
  idx_s[tid] = nbr[((size_t)(b << 11) + s0) * 16 + tid];
  const int sl = tid >> 4, cg = tid & 15, ch0 = cg << 4;

  float ssc[16], hsc[16], s2v[16], h2v[16];
#pragma unroll
  for (int j = 0; j < 16; j++){
    ssc[j] = stat[ST_SC_SC  + ch0 + j];
    hsc[j] = stat[ST_SH_SC  + ch0 + j];
    s2v[j] = stat[ST_SC_BN2 + ch0 + j];
    h2v[j] = stat[ST_SH_BN2 + ch0 + j];
  }
  __syncthreads();

  float mx[16];
#pragma unroll
  for (int j = 0; j < 16; j++) mx[j] = -3.4e38f;
  for (int k = 0; k < 16; k++){
    int nn = idx_s[sl * 16 + k];
    const uint4* p = (const uint4*)&sct[((size_t)(b << 13) + nn) * 256 + ch0];
    union { uint4 u; __hip_bfloat16 e[8]; } a0, a1;
    a0.u = p[0]; a1.u = p[1];
#pragma unroll
    for (int j = 0; j < 8; j++){
      mx[j]     = fmaxf(mx[j],     __bfloat162float(a0.e[j]) * ssc[j]     + hsc[j]);
      mx[j + 8] = fmaxf(mx[j + 8], __bfloat162float(a1.e[j]) * ssc[j + 8] + hsc[j + 8]);
    }
  }
  {
    const uint4* p = (const uint4*)&h2[((size_t)(b << 11) + s0 + sl) * 256 + ch0];
    union { uint4 u; __hip_bfloat16 e[8]; } a0, a1;
    a0.u = p[0]; a1.u = p[1];
#pragma unroll
    for (int j = 0; j < 8; j++){
      tile_s[sl][ch0 + j]     = fmaxf(__bfloat162float(a0.e[j]) * s2v[j]     + h2v[j]     + mx[j], 0.0f);
      tile_s[sl][ch0 + 8 + j] = fmaxf(__bfloat162float(a1.e[j]) * s2v[j + 8] + h2v[j + 8] + mx[j + 8], 0.0f);
    }
  }
  __syncthreads();
  const int o = tid;
#pragma unroll
  for (int p4 = 0; p4 < 4; p4++){
    float4 v = make_float4(tile_s[p4 * 4 + 0][o], tile_s[p4 * 4 + 1][o],
                           tile_s[p4 * 4 + 2][o], tile_s[p4 * 4 + 3][o]);
    *(float4*)&out[((size_t)(b << 8) + o) * 2048 + s0 + p4 * 4] = v;
  }
}

// =================================================================
extern "C" void kernel_launch(void* const* d_in, const int* in_sizes, int n_in,
                              void* d_out, int out_size, void* d_ws, size_t ws_size,
                              hipStream_t stream)
{
  (void)in_sizes; (void)n_in; (void)out_size; (void)ws_size;
  const float* x     = (const float*)d_in[0];
  const float* pos   = (const float*)d_in[1];
  const float* sup   = (const float*)d_in[2];
  const int*   nbr   = (const int*)d_in[3];
  const float* cv0w  = (const float*)d_in[5];
  const float* cv0b  = (const float*)d_in[6];
  const float* bn0g  = (const float*)d_in[7];
  const float* bn0b  = (const float*)d_in[8];
  const float* fc1   = (const float*)d_in[9];
  const float* fc2   = (const float*)d_in[10];
  const float* fc3   = (const float*)d_in[11];
  const float* in1g  = (const float*)d_in[12];
  const float* in1b  = (const float*)d_in[13];
  const float* in2g  = (const float*)d_in[14];
  const float* in2b  = (const float*)d_in[15];
  const float* alp   = (const float*)d_in[16];
  const float* bet   = (const float*)d_in[17];
  const float* nrp   = (const float*)d_in[18];
  const float* cvw   = (const float*)d_in[19];
  const float* bn1g  = (const float*)d_in[20];
  const float* bn1b  = (const float*)d_in[21];
  const float* cv2w  = (const float*)d_in[22];
  const float* cv2bi = (const float*)d_in[23];
  const float* bn2g  = (const float*)d_in[24];
  const float* bn2b  = (const float*)d_in[25];
  const float* scw   = (const float*)d_in[26];
  const float* scb   = (const float*)d_in[27];
  const float* bnscg = (const float*)d_in[28];
  const float* bnscb = (const float*)d_in[29];

  char* w = (char*)d_ws;
  __hip_bfloat16* sct  = (__hip_bfloat16*)(w);                  //  0        (64 MB)
  __hip_bfloat16* y0t  = (__hip_bfloat16*)(w + 67108864);       //  16 MB
  __hip_bfloat16* aggp = (__hip_bfloat16*)(w + 83886080);       //  64 MB (k_fka..k6)
  __hip_bfloat16* xb   = (__hip_bfloat16*)(w + 83886080);       //  32 MB (xpose..k1)
  float*          pin1 = (float*)(w + 83886080);                //   1 MB (in1..red, after k1)
  float*          pin2 = (float*)(w + 84934656);                //   1 MB (in2..red)
  float*          p7   = (float*)(w + 83886080);                //   1 MB (k7..red, after k6)
  float*          hfka = (float*)(w + 150994944);               //   8 MB (k6..k7)
  float*          p1   = (float*)(w + 150994944);               // 5.2 MB (k1..red, before k6)
  __hip_bfloat16* h2   = (__hip_bfloat16*)(w + 159383552);      //  16 MB (k7..final)
  float*          p6   = (float*)(w + 159383552);               //   1 MB (k6..red, before k7)
  __hip_bfloat16* wb   = (__hip_bfloat16*)(w + 176160768);
  __hip_bfloat16* cvb  = (__hip_bfloat16*)(w + 176242688);
  __hip_bfloat16* cv2b = (__hip_bfloat16*)(w + 176373760);
  float*          stat = (float*)(w + 192937984UL);

  k_prep_w<<<480, 256, 0, stream>>>(cv0w, scw, cvw, cv2w, wb, cvb, cv2b);
  k_xpose<<<2048, 256, 0, stream>>>(x, xb);
  k1_mfma<<<2048, 256, 0, stream>>>(xb, wb, cv0b, scb, y0t, sct, p1);
  k_red_fin<<<4, 64, 0, stream>>>(p1, 2048, 640, 0, 320, bn0g, bn0b,
                                  1.0f / 131072.0f, 64, stat + ST_SC_BN0, stat + ST_SH_BN0);
  k_red_fin<<<16, 64, 0, stream>>>(p1, 2048, 640, 64, 384, bnscg, bnscb,
                                   1.0f / 131072.0f, 256, stat + ST_SC_SC, stat + ST_SH_SC);
  k_in1_stats<<<2048, 256, 0, stream>>>(pos, sup, nbr, fc1, nrp, pin1);
  k_red_fin_b<<<16, 64, 0, stream>>>(pin1, 512, in1g, in1b, 1.0f / 32768.0f,
                                     stat + ST_SC_IN1, stat + ST_SH_IN1);
  k_in2_stats<<<2048, 256, 0, stream>>>(pos, sup, nbr, fc1, fc2, alp, bet, nrp, stat, pin2);
  k_red_fin_b<<<16, 64, 0, stream>>>(pin2, 512, in2g, in2b, 1.0f / 32768.0f,
                                     stat + ST_SC_IN2, stat + ST_SH_IN2);
  k_fka<<<2048, 256, 0, stream>>>(pos, sup, nbr, fc1, fc2, fc3, alp, bet, nrp, y0t, stat, aggp);
  k6_mfma<<<512, 256, 0, stream>>>(aggp, cvb, hfka, p6);
  k_red_fin<<<4, 64, 0, stream>>>(p6, 2048, 128, 0, 64, bn1g, bn1b,
                                  1.0f / 32768.0f, 64, stat + ST_SC_BN1, stat + ST_SH_BN1);
  k7_mfma<<<512, 256, 0, stream>>>(hfka, cv2b, cv2bi, stat, h2, p7);
  k_red_fin<<<16, 64, 0, stream>>>(p7, 512, 512, 0, 256, bn2g, bn2b,
                                   1.0f / 32768.0f, 256, stat + ST_SC_BN2, stat + ST_SH_BN2);
  k_final<<<2048, 256, 0, stream>>>(sct, h2, nbr, stat, (float*)d_out);
}

// Round 6
// 508.530 us; speedup vs baseline: 2.9363x; 1.9751x over previous
//
#include <hip/hip_runtime.h>
#include <hip/hip_bf16.h>

#define DEV static __device__ __forceinline__

typedef __attribute__((ext_vector_type(8))) short bf16x8;
typedef __attribute__((ext_vector_type(4))) float f32x4;

// ---------------- stat layout (floats, inside ws) ----------------
#define ST_SC_BN0  0
#define ST_SH_BN0  64
#define ST_SC_SC   128
#define ST_SH_SC   384
#define ST_SC_IN1  640
#define ST_SH_IN1  896
#define ST_SC_IN2  1152
#define ST_SH_IN2  1408
#define ST_SC_BN1  1664
#define ST_SH_BN1  1728
#define ST_SC_BN2  1792
#define ST_SH_BN2  2048

DEV float rsum16(float v){
#pragma unroll
  for (int off = 8; off >= 1; off >>= 1) v += __shfl_xor(v, off, 16);
  return v;
}
DEV float rmax16(float v){
#pragma unroll
  for (int off = 8; off >= 1; off >>= 1) v = fmaxf(v, __shfl_xor(v, off, 16));
  return v;
}

// =================================================================
// P0: weight conversion f32 -> bf16.
// =================================================================
__global__ __launch_bounds__(256) void k_prep_w(
    const float* __restrict__ cv0w, const float* __restrict__ scw,
    const float* __restrict__ cvw,  const float* __restrict__ cv2w,
    __hip_bfloat16* __restrict__ wb, __hip_bfloat16* __restrict__ cvb,
    __hip_bfloat16* __restrict__ cv2b)
{
  int i = blockIdx.x * 256 + threadIdx.x;   // 0 .. 122879
  if (i < 40960){
    float v = (i < 8192) ? cv0w[i] : scw[i - 8192];
    wb[i] = __float2bfloat16(v);
  } else if (i < 106496){
    cvb[i - 40960] = __float2bfloat16(cvw[i - 40960]);
  } else {
    cv2b[i - 106496] = __float2bfloat16(cv2w[i - 106496]);
  }
}

// =================================================================
// P1: transpose x (b,128,8192) f32 -> xb (b,8192,128) bf16
// =================================================================
__global__ __launch_bounds__(256) void k_xpose(
    const float* __restrict__ x, __hip_bfloat16* __restrict__ xb)
{
  __shared__ float t[128][65];
  const int tid = threadIdx.x;
  const int b = blockIdx.x >> 7, nt = blockIdx.x & 127;
  const int n0 = nt << 6;
#pragma unroll
  for (int p = 0; p < 8; p++){
    int row = (p << 4) + (tid >> 4);
    float4 v = *(const float4*)&x[(((size_t)b * 128 + row) << 13) + n0 + ((tid & 15) << 2)];
    t[row][(tid & 15) * 4 + 0] = v.x;
    t[row][(tid & 15) * 4 + 1] = v.y;
    t[row][(tid & 15) * 4 + 2] = v.z;
    t[row][(tid & 15) * 4 + 3] = v.w;
  }
  __syncthreads();
  const int k8 = tid & 15;
#pragma unroll
  for (int p = 0; p < 4; p++){
    int n = (p << 4) + (tid >> 4);
    union { uint4 u; __hip_bfloat16 e[8]; } pk;
#pragma unroll
    for (int j = 0; j < 8; j++) pk.e[j] = __float2bfloat16(t[k8 * 8 + j][n]);
    *(uint4*)&xb[((size_t)(b << 13) + n0 + n) * 128 + k8 * 8] = pk.u;
  }
}

// =================================================================
// K1: MFMA cv0+shortcut GEMM, no LDS.
// p1[blk][640]: [ch]=sum, [320+ch]=sumsq, ch in 0..319.
// =================================================================
__global__ __launch_bounds__(256) void k1_mfma(
    const __hip_bfloat16* __restrict__ xb, const __hip_bfloat16* __restrict__ wb,
    const float* __restrict__ cv0b, const float* __restrict__ scb,
    __hip_bfloat16* __restrict__ y0t, __hip_bfloat16* __restrict__ sct,
    float* __restrict__ p1)
{
  const int tid = threadIdx.x;
  const int b = blockIdx.x >> 7, nt = blockIdx.x & 127;
  const int n0 = nt << 6;
  const int wv = tid >> 6, l = tid & 63;
  const int lr = l & 15, lg = l >> 4;
  float* p1row = p1 + (size_t)blockIdx.x * 640;

  f32x4 acc[5][4];
#pragma unroll
  for (int i = 0; i < 5; i++)
#pragma unroll
    for (int j = 0; j < 4; j++) acc[i][j] = (f32x4){0.f, 0.f, 0.f, 0.f};

  const __hip_bfloat16* xrow = xb + ((size_t)(b << 13) + n0 + lr) * 128 + lg * 8;
  const __hip_bfloat16* wrow = wb + (size_t)(wv * 80 + lr) * 128 + lg * 8;

#pragma unroll
  for (int ks = 0; ks < 4; ks++){
    bf16x8 B[4], A[5];
#pragma unroll
    for (int nf = 0; nf < 4; nf++) B[nf] = *(const bf16x8*)(xrow + nf * 2048 + ks * 32);
#pragma unroll
    for (int mf = 0; mf < 5; mf++) A[mf] = *(const bf16x8*)(wrow + mf * 2048 + ks * 32);
#pragma unroll
    for (int mf = 0; mf < 5; mf++)
#pragma unroll
      for (int nf = 0; nf < 4; nf++)
        acc[mf][nf] = __builtin_amdgcn_mfma_f32_16x16x32_bf16(A[mf], B[nf], acc[mf][nf], 0, 0, 0);
  }

#pragma unroll
  for (int mf = 0; mf < 5; mf++){
    const int m0 = wv * 80 + mf * 16 + lg * 4;
    float bv[4];
#pragma unroll
    for (int r = 0; r < 4; r++){
      int m = m0 + r;
      bv[r] = (m < 64) ? cv0b[m] : scb[m - 64];
    }
#pragma unroll
    for (int nf = 0; nf < 4; nf++)
#pragma unroll
      for (int r = 0; r < 4; r++) acc[mf][nf][r] += bv[r];

#pragma unroll
    for (int nf = 0; nf < 4; nf++){
      int n = n0 + nf * 16 + lr;
      union { uint2 u; __hip_bfloat16 e[4]; } pk;
#pragma unroll
      for (int r = 0; r < 4; r++) pk.e[r] = __float2bfloat16(acc[mf][nf][r]);
      if (m0 < 64)
        *(uint2*)&y0t[((size_t)(b << 13) + n) * 64 + m0] = pk.u;
      else
        *(uint2*)&sct[((size_t)(b << 13) + n) * 256 + (m0 - 64)] = pk.u;
    }
#pragma unroll
    for (int r = 0; r < 4; r++){
      float ss = 0.f, qq = 0.f;
#pragma unroll
      for (int nf = 0; nf < 4; nf++){ float v = acc[mf][nf][r]; ss += v; qq += v * v; }
#pragma unroll
      for (int off = 8; off >= 1; off >>= 1){
        ss += __shfl_xor(ss, off, 16);
        qq += __shfl_xor(qq, off, 16);
      }
      if (lr == 0){
        int ch = m0 + r;
        p1row[ch]       = ss;
        p1row[320 + ch] = qq;
      }
    }
  }
}

// =================================================================
// Fast reducers: 256 thr = 64 row-stripes x 4 ch-quads, f32x4 loads,
// LDS tree reduce. ~8-32 iterations per thread.
// =================================================================
__global__ __launch_bounds__(256) void k_redP1(
    const float* __restrict__ part, int nrows,
    const float* __restrict__ g0, const float* __restrict__ b0,
    const float* __restrict__ gs, const float* __restrict__ bs,
    float inv_cnt, float* __restrict__ stat)
{
  __shared__ f32x4 sh_s[256], sh_q[256];
  const int tid = threadIdx.x;
  const int ch0 = blockIdx.x << 4;
  const int c4 = (tid & 3) << 2;
  const int stripe = tid >> 2;
  f32x4 s = {0.f,0.f,0.f,0.f}, q = {0.f,0.f,0.f,0.f};
  for (int r = stripe; r < nrows; r += 64){
    const float* row = part + (size_t)r * 640;
    s += *(const f32x4*)&row[ch0 + c4];
    q += *(const f32x4*)&row[320 + ch0 + c4];
  }
  sh_s[tid] = s; sh_q[tid] = q;
  __syncthreads();
  for (int off = 128; off >= 4; off >>= 1){
    if (tid < off){ sh_s[tid] += sh_s[tid + off]; sh_q[tid] += sh_q[tid + off]; }
    __syncthreads();
  }
  if (tid < 4){
    f32x4 S = sh_s[tid], Q = sh_q[tid];
#pragma unroll
    for (int j = 0; j < 4; j++){
      int ch = ch0 + (tid << 2) + j;
      float m  = S[j] * inv_cnt;
      float v  = Q[j] * inv_cnt - m * m;
      if (ch < 64){
        float sc = g0[ch] * rsqrtf(v + 1e-5f);
        stat[ST_SC_BN0 + ch] = sc;
        stat[ST_SH_BN0 + ch] = b0[ch] - m * sc;
      } else {
        int c = ch - 64;
        float sc = gs[c] * rsqrtf(v + 1e-5f);
        stat[ST_SC_SC + c] = sc;
        stat[ST_SH_SC + c] = bs[c] - m * sc;
      }
    }
  }
}

__global__ __launch_bounds__(256) void k_redA(
    const float* __restrict__ part, int nrows, int rowstride,
    int sum_off, int sq_off,
    const float* __restrict__ g, const float* __restrict__ bb,
    float inv_cnt, int gmod,
    float* __restrict__ scale, float* __restrict__ shift)
{
  __shared__ f32x4 sh_s[256], sh_q[256];
  const int tid = threadIdx.x;
  const int ch0 = blockIdx.x << 4;
  const int c4 = (tid & 3) << 2;
  const int stripe = tid >> 2;
  f32x4 s = {0.f,0.f,0.f,0.f}, q = {0.f,0.f,0.f,0.f};
  for (int r = stripe; r < nrows; r += 64){
    const float* row = part + (size_t)r * rowstride;
    s += *(const f32x4*)&row[sum_off + ch0 + c4];
    q += *(const f32x4*)&row[sq_off + ch0 + c4];
  }
  sh_s[tid] = s; sh_q[tid] = q;
  __syncthreads();
  for (int off = 128; off >= 4; off >>= 1){
    if (tid < off){ sh_s[tid] += sh_s[tid + off]; sh_q[tid] += sh_q[tid + off]; }
    __syncthreads();
  }
  if (tid < 4){
    f32x4 S = sh_s[tid], Q = sh_q[tid];
#pragma unroll
    for (int j = 0; j < 4; j++){
      int ch = ch0 + (tid << 2) + j;
      float m  = S[j] * inv_cnt;
      float v  = Q[j] * inv_cnt - m * m;
      float sc = g[ch % gmod] * rsqrtf(v + 1e-5f);
      scale[ch] = sc;
      shift[ch] = bb[ch % gmod] - m * sc;
    }
  }
}

__global__ __launch_bounds__(256) void k_redB(
    const float* __restrict__ part, int rows_per_b,
    const float* __restrict__ g, const float* __restrict__ bb, float inv_cnt,
    float* __restrict__ scale, float* __restrict__ shift)
{
  __shared__ f32x4 sh_s[256], sh_q[256];
  const int tid = threadIdx.x;
  const int b = blockIdx.x;
  const int c4 = (tid & 3) << 2;
  const int stripe = tid >> 2;
  const float* base = part + (size_t)b * rows_per_b * 32;
  f32x4 s = {0.f,0.f,0.f,0.f}, q = {0.f,0.f,0.f,0.f};
  for (int r = stripe; r < rows_per_b; r += 64){
    s += *(const f32x4*)&base[r * 32 + c4];
    q += *(const f32x4*)&base[r * 32 + 16 + c4];
  }
  sh_s[tid] = s; sh_q[tid] = q;
  __syncthreads();
  for (int off = 128; off >= 4; off >>= 1){
    if (tid < off){ sh_s[tid] += sh_s[tid + off]; sh_q[tid] += sh_q[tid + off]; }
    __syncthreads();
  }
  if (tid < 4){
    f32x4 S = sh_s[tid], Q = sh_q[tid];
#pragma unroll
    for (int j = 0; j < 4; j++){
      int c = (tid << 2) + j;
      float m  = S[j] * inv_cnt;
      float v  = Q[j] * inv_cnt - m * m;
      float sc = g[c] * rsqrtf(v + 1e-5f);
      scale[b * 16 + c] = sc;
      shift[b * 16 + c] = bb[c] - m * sc;
    }
  }
}

// =================================================================
// K3: IN1 stats -> pin1[blk*4+wv][32]
// =================================================================
__global__ __launch_bounds__(256) void k_in1_stats(
    const float* __restrict__ pos, const float* __restrict__ sup, const int* __restrict__ nbr,
    const float* __restrict__ fc1, const float* __restrict__ nrp, float* __restrict__ pin1)
{
  const int tid = threadIdx.x;
  const int b  = blockIdx.x >> 7;
  const int st = blockIdx.x & 127;
  const int sl = tid >> 4, k = tid & 15;
  const int s  = (st << 4) + sl;
  const int n  = nbr[((((size_t)b << 11) + s) << 4) + k];
  float* pr = pin1 + ((size_t)blockIdx.x * 4 + (tid >> 6)) * 32;
  const float inr = 1.0f / nrp[0];
  float p0 = (pos[((size_t)b * 3 + 0) * 8192 + n] - sup[((size_t)b * 3 + 0) * 2048 + s]) * inr;
  float p1 = (pos[((size_t)b * 3 + 1) * 8192 + n] - sup[((size_t)b * 3 + 1) * 2048 + s]) * inr;
  float p2 = (pos[((size_t)b * 3 + 2) * 8192 + n] - sup[((size_t)b * 3 + 2) * 2048 + s]) * inr;
#pragma unroll
  for (int q = 0; q < 16; q++){
    float z = fc1[q * 3] * p0 + fc1[q * 3 + 1] * p1 + fc1[q * 3 + 2] * p2;
    float a = z, c = z * z;
#pragma unroll
    for (int off = 32; off >= 1; off >>= 1){
      a += __shfl_xor(a, off, 64);
      c += __shfl_xor(c, off, 64);
    }
    if ((tid & 63) == q){
      pr[q]      = a;
      pr[16 + q] = c;
    }
  }
}

// =================================================================
// K4: IN2 stats -> pin2[blk*4+wv][32]
// =================================================================
__global__ __launch_bounds__(256) void k_in2_stats(
    const float* __restrict__ pos, const float* __restrict__ sup, const int* __restrict__ nbr,
    const float* __restrict__ fc1, const float* __restrict__ fc2,
    const float* __restrict__ alp, const float* __restrict__ bet, const float* __restrict__ nrp,
    const float* __restrict__ stat, float* __restrict__ pin2)
{
  __shared__ float fc2s[512];
  __shared__ float sc1s[16], sh1s[16];
  const int tid = threadIdx.x;
  const int b  = blockIdx.x >> 7;
  const int st = blockIdx.x & 127;
  fc2s[tid]       = fc2[tid];
  fc2s[tid + 256] = fc2[tid + 256];
  if (tid < 16){
    sc1s[tid] = stat[ST_SC_IN1 + (b << 4) + tid];
    sh1s[tid] = stat[ST_SH_IN1 + (b << 4) + tid];
  }
  __syncthreads();
  const int sl = tid >> 4, k = tid & 15;
  const int s  = (st << 4) + sl;
  const int n  = nbr[((((size_t)b << 11) + s) << 4) + k];
  float* pr = pin2 + ((size_t)blockIdx.x * 4 + (tid >> 6)) * 32;
  float t0 = pos[((size_t)b * 3 + 0) * 8192 + n] - sup[((size_t)b * 3 + 0) * 2048 + s];
  float t1 = pos[((size_t)b * 3 + 1) * 8192 + n] - sup[((size_t)b * 3 + 1) * 2048 + s];
  float t2 = pos[((size_t)b * 3 + 2) * 8192 + n] - sup[((size_t)b * 3 + 2) * 2048 + s];
  float dist = sqrtf(t0 * t0 + t1 * t1 + t2 * t2);
  float dw = 1.0f / (1.0f + expf(alp[0] * dist - bet[0]));
  float ssum = rsum16(dw);
  ssum += (ssum == 0.0f ? 1.0f : 0.0f) + 1e-6f;
  dw = dw / ssum * 16.0f;
  const float inr = 1.0f / nrp[0];
  float p0 = t0 * inr, p1 = t1 * inr, p2 = t2 * inr;
  float m1[16], mp1[16];
#pragma unroll
  for (int q = 0; q < 16; q++){
    float z = fc1[q * 3] * p0 + fc1[q * 3 + 1] * p1 + fc1[q * 3 + 2] * p2;
    m1[q] = fmaxf(z * sc1s[q] + sh1s[q], 0.0f);
  }
#pragma unroll
  for (int q = 0; q < 16; q++) mp1[q] = rmax16(m1[q] * dw);
#pragma unroll
  for (int q = 0; q < 16; q++){
    float z = 0.0f;
#pragma unroll
    for (int j = 0; j < 16; j++) z = fmaf(fc2s[q * 32 + j], m1[j], z);
#pragma unroll
    for (int j = 0; j < 16; j++) z = fmaf(fc2s[q * 32 + 16 + j], mp1[j], z);
    float a = z, c = z * z;
#pragma unroll
    for (int off = 32; off >= 1; off >>= 1){
      a += __shfl_xor(a, off, 64);
      c += __shfl_xor(c, off, 64);
    }
    if ((tid & 63) == q){
      pr[q]      = a;
      pr[16 + q] = c;
    }
  }
}

// =================================================================
// K5: FKA main
// =================================================================
__global__ __launch_bounds__(256) void k_fka(
    const float* __restrict__ pos, const float* __restrict__ sup, const int* __restrict__ nbr,
    const float* __restrict__ fc1, const float* __restrict__ fc2, const float* __restrict__ fc3,
    const float* __restrict__ alp, const float* __restrict__ bet, const float* __restrict__ nrp,
    const __hip_bfloat16* __restrict__ y0t, const float* __restrict__ stat,
    __hip_bfloat16* __restrict__ agg)
{
  __shared__ float fc2s[512], fc3s[512];
  __shared__ float sc1s[16], sh1s[16], sc2s[16], sh2s[16];
  __shared__ float sc0s[64], sh0s[64];
  __shared__ float mat3_s[16][16][17];
  __shared__ float feat2_s[2][16][65];
  __shared__ int   idx_s[16][16];

  const int tid = threadIdx.x;
  const int b  = blockIdx.x >> 7;
  const int st = blockIdx.x & 127;
  fc2s[tid]       = fc2[tid];
  fc2s[tid + 256] = fc2[tid + 256];
  fc3s[tid]       = fc3[tid];
  fc3s[tid + 256] = fc3[tid + 256];
  if (tid < 16){
    sc1s[tid] = stat[ST_SC_IN1 + (b << 4) + tid];
    sh1s[tid] = stat[ST_SH_IN1 + (b << 4) + tid];
    sc2s[tid] = stat[ST_SC_IN2 + (b << 4) + tid];
    sh2s[tid] = stat[ST_SH_IN2 + (b << 4) + tid];
  }
  if (tid < 64){
    sc0s[tid] = stat[ST_SC_BN0 + tid];
    sh0s[tid] = stat[ST_SH_BN0 + tid];
  }
  const int sl = tid >> 4, k = tid & 15;
  const int s  = (st << 4) + sl;
  const int n  = nbr[((((size_t)b << 11) + s) << 4) + k];
  idx_s[sl][k] = n;
  __syncthreads();

  float t0 = pos[((size_t)b * 3 + 0) * 8192 + n] - sup[((size_t)b * 3 + 0) * 2048 + s];
  float t1 = pos[((size_t)b * 3 + 1) * 8192 + n] - sup[((size_t)b * 3 + 1) * 2048 + s];
  float t2 = pos[((size_t)b * 3 + 2) * 8192 + n] - sup[((size_t)b * 3 + 2) * 2048 + s];
  float dist = sqrtf(t0 * t0 + t1 * t1 + t2 * t2);
  float dw = 1.0f / (1.0f + expf(alp[0] * dist - bet[0]));
  float ssum = rsum16(dw);
  ssum += (ssum == 0.0f ? 1.0f : 0.0f) + 1e-6f;
  dw = dw / ssum * 16.0f;
  const float inr = 1.0f / nrp[0];
  float p0 = t0 * inr, p1 = t1 * inr, p2 = t2 * inr;
  float m1[16], mp1[16];
#pragma unroll
  for (int q = 0; q < 16; q++){
    float z = fc1[q * 3] * p0 + fc1[q * 3 + 1] * p1 + fc1[q * 3 + 2] * p2;
    m1[q] = fmaxf(z * sc1s[q] + sh1s[q], 0.0f);
  }
#pragma unroll
  for (int q = 0; q < 16; q++) mp1[q] = rmax16(m1[q] * dw);
  float m2[16], mp2[16];
#pragma unroll
  for (int q = 0; q < 16; q++){
    float z = 0.0f;
#pragma unroll
    for (int j = 0; j < 16; j++) z = fmaf(fc2s[q * 32 + j], m1[j], z);
#pragma unroll
    for (int j = 0; j < 16; j++) z = fmaf(fc2s[q * 32 + 16 + j], mp1[j], z);
    m2[q] = fmaxf(z * sc2s[q] + sh2s[q], 0.0f);
  }
#pragma unroll
  for (int q = 0; q < 16; q++) mp2[q] = rmax16(m2[q] * dw);
#pragma unroll
  for (int q = 0; q < 16; q++){
    float z = 0.0f;
#pragma unroll
    for (int j = 0; j < 16; j++) z = fmaf(fc3s[q * 32 + j], m2[j], z);
#pragma unroll
    for (int j = 0; j < 16; j++) z = fmaf(fc3s[q * 32 + 16 + j], mp2[j], z);
    mat3_s[sl][q][k] = fmaxf(z, 0.0f) * dw;
  }
  __syncthreads();

  const int h   = tid >> 7;
  const int r7  = tid & 127;
  const int gk  = r7 >> 3;
  const int gc8 = r7 & 7;
  const int cc  = r7 >> 1;
  const int qh  = r7 & 1;

  for (int it = 0; it < 8; it++){
    const int sl2 = it * 2 + h;
    {
      int nn = idx_s[sl2][gk];
      union { uint4 u; __hip_bfloat16 e[8]; } ld;
      ld.u = *(const uint4*)&y0t[((size_t)(b << 13) + nn) * 64 + gc8 * 8];
#pragma unroll
      for (int j = 0; j < 8; j++){
        int ch = gc8 * 8 + j;
        feat2_s[h][gk][ch] = fmaxf(__bfloat162float(ld.e[j]) * sc0s[ch] + sh0s[ch], 0.0f);
      }
    }
    __syncthreads();
    {
      float fv[16];
#pragma unroll
      for (int kk = 0; kk < 16; kk++) fv[kk] = feat2_s[h][kk][cc];
      union { uint4 u; __hip_bfloat16 e[8]; } pk;
#pragma unroll
      for (int q2 = 0; q2 < 8; q2++){
        int q = qh * 8 + q2;
        float a2 = 0.0f;
#pragma unroll
        for (int kk = 0; kk < 16; kk++) a2 = fmaf(fv[kk], mat3_s[sl2][q][kk], a2);
        pk.e[q2] = __float2bfloat16(a2);
      }
      int ss = (st << 4) + sl2;
      *(uint4*)&agg[((size_t)(b << 11) + ss) * 1024 + cc * 16 + qh * 8] = pk.u;
    }
    __syncthreads();
  }
}

// =================================================================
// K6: MFMA cv GEMM. Partials: p6[blk*4+wv][128]
// =================================================================
__global__ __launch_bounds__(256) void k6_mfma(
    const __hip_bfloat16* __restrict__ agg, const __hip_bfloat16* __restrict__ cvb,
    float* __restrict__ hfka, float* __restrict__ p6)
{
  const int tid = threadIdx.x;
  const int b = blockIdx.x >> 5, stile = blockIdx.x & 31;
  const int wv = tid >> 6, l = tid & 63;
  const int lr = l & 15, lg = l >> 4;
  const int sw = (stile << 6) + (wv << 4);
  float* p6row = p6 + ((size_t)blockIdx.x * 4 + wv) * 128;

  f32x4 acc[4];
#pragma unroll
  for (int i = 0; i < 4; i++) acc[i] = (f32x4){0.f, 0.f, 0.f, 0.f};

  const __hip_bfloat16* brow = agg + ((size_t)(b << 11) + sw + lr) * 1024 + lg * 8;
  const __hip_bfloat16* arow = cvb + (size_t)lr * 1024 + lg * 8;

#pragma unroll 4
  for (int ks = 0; ks < 32; ks++){
    bf16x8 B = *(const bf16x8*)(brow + ks * 32);
    bf16x8 A[4];
#pragma unroll
    for (int mf = 0; mf < 4; mf++) A[mf] = *(const bf16x8*)(arow + mf * 16384 + ks * 32);
#pragma unroll
    for (int mf = 0; mf < 4; mf++)
      acc[mf] = __builtin_amdgcn_mfma_f32_16x16x32_bf16(A[mf], B, acc[mf], 0, 0, 0);
  }

  const int s = sw + lr;
#pragma unroll
  for (int mf = 0; mf < 4; mf++){
    const int m0 = mf * 16 + lg * 4;
    float4 v = make_float4(acc[mf][0], acc[mf][1], acc[mf][2], acc[mf][3]);
    *(float4*)&hfka[((size_t)(b << 11) + s) * 64 + m0] = v;
#pragma unroll
    for (int r = 0; r < 4; r++){
      float ss = acc[mf][r], qq = ss * ss;
#pragma unroll
      for (int off = 8; off >= 1; off >>= 1){
        ss += __shfl_xor(ss, off, 16);
        qq += __shfl_xor(qq, off, 16);
      }
      if (lr == 0){
        p6row[m0 + r]      = ss;
        p6row[64 + m0 + r] = qq;
      }
    }
  }
}

// =================================================================
// K7: MFMA cv2. Partials: p7[blk][512]
// =================================================================
__global__ __launch_bounds__(256) void k7_mfma(
    const float* __restrict__ hfka, const __hip_bfloat16* __restrict__ cv2b,
    const float* __restrict__ bias, const float* __restrict__ stat_ro,
    __hip_bfloat16* __restrict__ h2, float* __restrict__ p7)
{
  const int tid = threadIdx.x;
  const int b = blockIdx.x >> 5, stile = blockIdx.x & 31;
  const int s0 = stile << 6;
  const int wv = tid >> 6, l = tid & 63;
  const int lr = l & 15, lg = l >> 4;
  float* p7row = p7 + (size_t)blockIdx.x * 512;

  float s1r[2][8], h1r[2][8];
#pragma unroll
  for (int ks = 0; ks < 2; ks++)
#pragma unroll
    for (int j = 0; j < 8; j++){
      int ch = ks * 32 + lg * 8 + j;
      s1r[ks][j] = stat_ro[ST_SC_BN1 + ch];
      h1r[ks][j] = stat_ro[ST_SH_BN1 + ch];
    }

  bf16x8 B[2][4];
#pragma unroll
  for (int ks = 0; ks < 2; ks++)
#pragma unroll
    for (int nf = 0; nf < 4; nf++){
      int s = s0 + nf * 16 + lr;
      const float* hp = hfka + ((size_t)(b << 11) + s) * 64 + ks * 32 + lg * 8;
      float4 v0 = *(const float4*)hp;
      float4 v1 = *(const float4*)(hp + 4);
      float vv[8] = {v0.x, v0.y, v0.z, v0.w, v1.x, v1.y, v1.z, v1.w};
      union { bf16x8 f; __hip_bfloat16 e[8]; } pk;
#pragma unroll
      for (int j = 0; j < 8; j++)
        pk.e[j] = __float2bfloat16(fmaxf(vv[j] * s1r[ks][j] + h1r[ks][j], 0.0f));
      B[ks][nf] = pk.f;
    }

  f32x4 acc[4][4];
#pragma unroll
  for (int i = 0; i < 4; i++)
#pragma unroll
    for (int j = 0; j < 4; j++) acc[i][j] = (f32x4){0.f, 0.f, 0.f, 0.f};

  const __hip_bfloat16* arow = cv2b + (size_t)(wv * 64 + lr) * 64 + lg * 8;
#pragma unroll
  for (int ks = 0; ks < 2; ks++){
    bf16x8 A[4];
#pragma unroll
    for (int mf = 0; mf < 4; mf++) A[mf] = *(const bf16x8*)(arow + mf * 1024 + ks * 32);
#pragma unroll
    for (int mf = 0; mf < 4; mf++)
#pragma unroll
      for (int nf = 0; nf < 4; nf++)
        acc[mf][nf] = __builtin_amdgcn_mfma_f32_16x16x32_bf16(A[mf], B[ks][nf], acc[mf][nf], 0, 0, 0);
  }

#pragma unroll
  for (int mf = 0; mf < 4; mf++){
    const int m0 = wv * 64 + mf * 16 + lg * 4;
    float bv[4];
#pragma unroll
    for (int r = 0; r < 4; r++) bv[r] = bias[m0 + r];
#pragma unroll
    for (int nf = 0; nf < 4; nf++){
      int s = s0 + nf * 16 + lr;
      union { uint2 u; __hip_bfloat16 e[4]; } pk;
#pragma unroll
      for (int r = 0; r < 4; r++){
        acc[mf][nf][r] += bv[r];
        pk.e[r] = __float2bfloat16(acc[mf][nf][r]);
      }
      *(uint2*)&h2[((size_t)(b << 11) + s) * 256 + m0] = pk.u;
    }
#pragma unroll
    for (int r = 0; r < 4; r++){
      float ss = 0.f, qq = 0.f;
#pragma unroll
      for (int nf = 0; nf < 4; nf++){ float v = acc[mf][nf][r]; ss += v; qq += v * v; }
#pragma unroll
      for (int off = 8; off >= 1; off >>= 1){
        ss += __shfl_xor(ss, off, 16);
        qq += __shfl_xor(qq, off, 16);
      }
      if (lr == 0){
        p7row[m0 + r]       = ss;
        p7row[256 + m0 + r] = qq;
      }
    }
  }
}

// =================================================================
// K8: final
// =================================================================
__global__ __launch_bounds__(256) void k_final(
    const __hip_bfloat16* __restrict__ sct, const __hip_bfloat16* __restrict__ h2,
    const int* __restrict__ nbr, const float* __restrict__ stat, float* __restrict__ out)
{
  __shared__ int   idx_s[256];
  __shared__ float tile_s[16][257];
  const int tid = threadIdx.x;
  const int b  = blockIdx.x >> 7;
  const int st = blockIdx.x & 127;
  const int s0 = st << 4;
  idx_s[tid] = nbr[((size_t)(b << 11) + s0) * 16 + tid];
  const int sl = tid >> 4, cg = tid & 15, ch0 = cg << 4;

  float ssc[16], hsc[16], s2v[16], h2v[16];
#pragma unroll
  for (int j = 0; j < 16; j++){
    ssc[j] = stat[ST_SC_SC  + ch0 + j];
    hsc[j] = stat[ST_SH_SC  + ch0 + j];
    s2v[j] = stat[ST_SC_BN2 + ch0 + j];
    h2v[j] = stat[ST_SH_BN2 + ch0 + j];
  }
  __syncthreads();

  float mx[16];
#pragma unroll
  for (int j = 0; j < 16; j++) mx[j] = -3.4e38f;
  for (int k = 0; k < 16; k++){
    int nn = idx_s[sl * 16 + k];
    const uint4* p = (const uint4*)&sct[((size_t)(b << 13) + nn) * 256 + ch0];
    union { uint4 u; __hip_bfloat16 e[8]; } a0, a1;
    a0.u = p[0]; a1.u = p[1];
#pragma unroll
    for (int j = 0; j < 8; j++){
      mx[j]     = fmaxf(mx[j],     __bfloat162float(a0.e[j]) * ssc[j]     + hsc[j]);
      mx[j + 8] = fmaxf(mx[j + 8], __bfloat162float(a1.e[j]) * ssc[j + 8] + hsc[j + 8]);
    }
  }
  {
    const uint4* p = (const uint4*)&h2[((size_t)(b << 11) + s0 + sl) * 256 + ch0];
    union { uint4 u; __hip_bfloat16 e[8]; } a0, a1;
    a0.u = p[0]; a1.u = p[1];
#pragma unroll
    for (int j = 0; j < 8; j++){
      tile_s[sl][ch0 + j]     = fmaxf(__bfloat162float(a0.e[j]) * s2v[j]     + h2v[j]     + mx[j], 0.0f);
      tile_s[sl][ch0 + 8 + j] = fmaxf(__bfloat162float(a1.e[j]) * s2v[j + 8] + h2v[j + 8] + mx[j + 8], 0.0f);
    }
  }
  __syncthreads();
  const int o = tid;
#pragma unroll
  for (int p4 = 0; p4 < 4; p4++){
    float4 v = make_float4(tile_s[p4 * 4 + 0][o], tile_s[p4 * 4 + 1][o],
                           tile_s[p4 * 4 + 2][o], tile_s[p4 * 4 + 3][o]);
    *(float4*)&out[((size_t)(b << 8) + o) * 2048 + s0 + p4 * 4] = v;
  }
}

// =================================================================
extern "C" void kernel_launch(void* const* d_in, const int* in_sizes, int n_in,
                              void* d_out, int out_size, void* d_ws, size_t ws_size,
                              hipStream_t stream)
{
  (void)in_sizes; (void)n_in; (void)out_size; (void)ws_size;
  const float* x     = (const float*)d_in[0];
  const float* pos   = (const float*)d_in[1];
  const float* sup   = (const float*)d_in[2];
  const int*   nbr   = (const int*)d_in[3];
  const float* cv0w  = (const float*)d_in[5];
  const float* cv0b  = (const float*)d_in[6];
  const float* bn0g  = (const float*)d_in[7];
  const float* bn0b  = (const float*)d_in[8];
  const float* fc1   = (const float*)d_in[9];
  const float* fc2   = (const float*)d_in[10];
  const float* fc3   = (const float*)d_in[11];
  const float* in1g  = (const float*)d_in[12];
  const float* in1b  = (const float*)d_in[13];
  const float* in2g  = (const float*)d_in[14];
  const float* in2b  = (const float*)d_in[15];
  const float* alp   = (const float*)d_in[16];
  const float* bet   = (const float*)d_in[17];
  const float* nrp   = (const float*)d_in[18];
  const float* cvw   = (const float*)d_in[19];
  const float* bn1g  = (const float*)d_in[20];
  const float* bn1b  = (const float*)d_in[21];
  const float* cv2w  = (const float*)d_in[22];
  const float* cv2bi = (const float*)d_in[23];
  const float* bn2g  = (const float*)d_in[24];
  const float* bn2b  = (const float*)d_in[25];
  const float* scw   = (const float*)d_in[26];
  const float* scb   = (const float*)d_in[27];
  const float* bnscg = (const float*)d_in[28];
  const float* bnscb = (const float*)d_in[29];

  char* w = (char*)d_ws;
  __hip_bfloat16* sct  = (__hip_bfloat16*)(w);                  //  0       (64 MB)
  __hip_bfloat16* y0t  = (__hip_bfloat16*)(w + 67108864);       //  16 MB
  __hip_bfloat16* aggp = (__hip_bfloat16*)(w + 83886080);       //  64 MB (k_fka..k6)
  __hip_bfloat16* xb   = (__hip_bfloat16*)(w + 83886080);       //  32 MB (xpose..k1)
  float*          pin1 = (float*)(w + 83886080);                //   1 MB (in1..red)
  float*          pin2 = (float*)(w + 84934656);                //   1 MB (in2..red)
  float*          p7   = (float*)(w + 83886080);                //   1 MB (k7..red)
  float*          hfka = (float*)(w + 150994944);               //   8 MB (k6..k7)
  float*          p1   = (float*)(w + 150994944);               // 5.2 MB (k1..red)
  __hip_bfloat16* h2   = (__hip_bfloat16*)(w + 159383552);      //  16 MB (k7..final)
  float*          p6   = (float*)(w + 159383552);               //   1 MB (k6..red)
  __hip_bfloat16* wb   = (__hip_bfloat16*)(w + 176160768);
  __hip_bfloat16* cvb  = (__hip_bfloat16*)(w + 176242688);
  __hip_bfloat16* cv2b = (__hip_bfloat16*)(w + 176373760);
  float*          stat = (float*)(w + 192937984UL);

  k_prep_w<<<480, 256, 0, stream>>>(cv0w, scw, cvw, cv2w, wb, cvb, cv2b);
  k_xpose<<<2048, 256, 0, stream>>>(x, xb);
  k1_mfma<<<2048, 256, 0, stream>>>(xb, wb, cv0b, scb, y0t, sct, p1);
  k_redP1<<<20, 256, 0, stream>>>(p1, 2048, bn0g, bn0b, bnscg, bnscb,
                                  1.0f / 131072.0f, stat);
  k_in1_stats<<<2048, 256, 0, stream>>>(pos, sup, nbr, fc1, nrp, pin1);
  k_redB<<<16, 256, 0, stream>>>(pin1, 512, in1g, in1b, 1.0f / 32768.0f,
                                 stat + ST_SC_IN1, stat + ST_SH_IN1);
  k_in2_stats<<<2048, 256, 0, stream>>>(pos, sup, nbr, fc1, fc2, alp, bet, nrp, stat, pin2);
  k_redB<<<16, 256, 0, stream>>>(pin2, 512, in2g, in2b, 1.0f / 32768.0f,
                                 stat + ST_SC_IN2, stat + ST_SH_IN2);
  k_fka<<<2048, 256, 0, stream>>>(pos, sup, nbr, fc1, fc2, fc3, alp, bet, nrp, y0t, stat, aggp);
  k6_mfma<<<512, 256, 0, stream>>>(aggp, cvb, hfka, p6);
  k_redA<<<4, 256, 0, stream>>>(p6, 2048, 128, 0, 64, bn1g, bn1b,
                                1.0f / 32768.0f, 64, stat + ST_SC_BN1, stat + ST_SH_BN1);
  k7_mfma<<<512, 256, 0, stream>>>(hfka, cv2b, cv2bi, stat, h2, p7);
  k_redA<<<16, 256, 0, stream>>>(p7, 512, 512, 0, 256, bn2g, bn2b,
                                 1.0f / 32768.0f, 256, stat + ST_SC_BN2, stat + ST_SH_BN2);
  k_final<<<2048, 256, 0, stream>>>(sct, h2, nbr, stat, (float*)d_out);
}

// Round 7
// 494.744 us; speedup vs baseline: 3.0181x; 1.0279x over previous
//
#include <hip/hip_runtime.h>
#include <hip/hip_bf16.h>

#define DEV static __device__ __forceinline__

typedef __attribute__((ext_vector_type(8))) short bf16x8;
typedef __attribute__((ext_vector_type(4))) float f32x4;

// ---------------- stat layout (floats, inside ws) ----------------
#define ST_SC_BN0  0
#define ST_SH_BN0  64
#define ST_SC_SC   128
#define ST_SH_SC   384
#define ST_SC_IN1  640
#define ST_SH_IN1  896
#define ST_SC_IN2  1152
#define ST_SH_IN2  1408
#define ST_SC_BN1  1664
#define ST_SH_BN1  1728
#define ST_SC_BN2  1792
#define ST_SH_BN2  2048

DEV float rsum16(float v){
#pragma unroll
  for (int off = 8; off >= 1; off >>= 1) v += __shfl_xor(v, off, 16);
  return v;
}
DEV float rmax16(float v){
#pragma unroll
  for (int off = 8; off >= 1; off >>= 1) v = fmaxf(v, __shfl_xor(v, off, 16));
  return v;
}

// =================================================================
// P0: weight conversion f32 -> bf16.
// =================================================================
__global__ __launch_bounds__(256) void k_prep_w(
    const float* __restrict__ cv0w, const float* __restrict__ scw,
    const float* __restrict__ cvw,  const float* __restrict__ cv2w,
    __hip_bfloat16* __restrict__ wb, __hip_bfloat16* __restrict__ cvb,
    __hip_bfloat16* __restrict__ cv2b)
{
  int i = blockIdx.x * 256 + threadIdx.x;   // 0 .. 122879
  if (i < 40960){
    float v = (i < 8192) ? cv0w[i] : scw[i - 8192];
    wb[i] = __float2bfloat16(v);
  } else if (i < 106496){
    cvb[i - 40960] = __float2bfloat16(cvw[i - 40960]);
  } else {
    cv2b[i - 106496] = __float2bfloat16(cv2w[i - 106496]);
  }
}

// =================================================================
// K1: fused transpose + MFMA cv0+shortcut GEMM.
// Stages x (f32, n-contig) -> LDS xt[64n][136c] bf16 (transposed),
// B-frags read from LDS; A (weights) direct from global (L2-hot).
// p1[blk][640]: [ch]=sum, [320+ch]=sumsq, ch in 0..319.
// =================================================================
__global__ __launch_bounds__(256) void k1_mfma(
    const float* __restrict__ x, const __hip_bfloat16* __restrict__ wb,
    const float* __restrict__ cv0b, const float* __restrict__ scb,
    __hip_bfloat16* __restrict__ y0t, __hip_bfloat16* __restrict__ sct,
    float* __restrict__ p1)
{
  __shared__ __hip_bfloat16 xt[64][136];   // row stride 272B -> conflict-free b128
  const int tid = threadIdx.x;
  const int b = blockIdx.x >> 7, nt = blockIdx.x & 127;
  const int n0 = nt << 6;
  const int wv = tid >> 6, l = tid & 63;
  const int lr = l & 15, lg = l >> 4;
  float* p1row = p1 + (size_t)blockIdx.x * 640;

  // stage + transpose + convert: 8 passes, each 16 c-rows x 64 n
#pragma unroll
  for (int p = 0; p < 8; p++){
    int c  = (p << 4) + (tid >> 4);
    int n4 = (tid & 15) << 2;
    float4 v = *(const float4*)&x[(((size_t)b * 128 + c) << 13) + n0 + n4];
    xt[n4 + 0][c] = __float2bfloat16(v.x);
    xt[n4 + 1][c] = __float2bfloat16(v.y);
    xt[n4 + 2][c] = __float2bfloat16(v.z);
    xt[n4 + 3][c] = __float2bfloat16(v.w);
  }
  __syncthreads();

  f32x4 acc[5][4];
#pragma unroll
  for (int i = 0; i < 5; i++)
#pragma unroll
    for (int j = 0; j < 4; j++) acc[i][j] = (f32x4){0.f, 0.f, 0.f, 0.f};

  const __hip_bfloat16* wrow = wb + (size_t)(wv * 80 + lr) * 128 + lg * 8;

#pragma unroll
  for (int ks = 0; ks < 4; ks++){
    bf16x8 B[4], A[5];
#pragma unroll
    for (int nf = 0; nf < 4; nf++)
      B[nf] = *(const bf16x8*)&xt[nf * 16 + lr][ks * 32 + lg * 8];
#pragma unroll
    for (int mf = 0; mf < 5; mf++) A[mf] = *(const bf16x8*)(wrow + mf * 2048 + ks * 32);
#pragma unroll
    for (int mf = 0; mf < 5; mf++)
#pragma unroll
      for (int nf = 0; nf < 4; nf++)
        acc[mf][nf] = __builtin_amdgcn_mfma_f32_16x16x32_bf16(A[mf], B[nf], acc[mf][nf], 0, 0, 0);
  }

#pragma unroll
  for (int mf = 0; mf < 5; mf++){
    const int m0 = wv * 80 + mf * 16 + lg * 4;
    float bv[4];
#pragma unroll
    for (int r = 0; r < 4; r++){
      int m = m0 + r;
      bv[r] = (m < 64) ? cv0b[m] : scb[m - 64];
    }
#pragma unroll
    for (int nf = 0; nf < 4; nf++)
#pragma unroll
      for (int r = 0; r < 4; r++) acc[mf][nf][r] += bv[r];

#pragma unroll
    for (int nf = 0; nf < 4; nf++){
      int n = n0 + nf * 16 + lr;
      union { uint2 u; __hip_bfloat16 e[4]; } pk;
#pragma unroll
      for (int r = 0; r < 4; r++) pk.e[r] = __float2bfloat16(acc[mf][nf][r]);
      if (m0 < 64)
        *(uint2*)&y0t[((size_t)(b << 13) + n) * 64 + m0] = pk.u;
      else
        *(uint2*)&sct[((size_t)(b << 13) + n) * 256 + (m0 - 64)] = pk.u;
    }
#pragma unroll
    for (int r = 0; r < 4; r++){
      float ss = 0.f, qq = 0.f;
#pragma unroll
      for (int nf = 0; nf < 4; nf++){ float v = acc[mf][nf][r]; ss += v; qq += v * v; }
#pragma unroll
      for (int off = 8; off >= 1; off >>= 1){
        ss += __shfl_xor(ss, off, 16);
        qq += __shfl_xor(qq, off, 16);
      }
      if (lr == 0){
        int ch = m0 + r;
        p1row[ch]       = ss;
        p1row[320 + ch] = qq;
      }
    }
  }
}

// =================================================================
// Fast reducers: 256 thr = 64 row-stripes x 4 ch-quads, f32x4 loads,
// LDS tree reduce.
// =================================================================
__global__ __launch_bounds__(256) void k_redP1(
    const float* __restrict__ part, int nrows,
    const float* __restrict__ g0, const float* __restrict__ b0,
    const float* __restrict__ gs, const float* __restrict__ bs,
    float inv_cnt, float* __restrict__ stat)
{
  __shared__ f32x4 sh_s[256], sh_q[256];
  const int tid = threadIdx.x;
  const int ch0 = blockIdx.x << 4;
  const int c4 = (tid & 3) << 2;
  const int stripe = tid >> 2;
  f32x4 s = {0.f,0.f,0.f,0.f}, q = {0.f,0.f,0.f,0.f};
  for (int r = stripe; r < nrows; r += 64){
    const float* row = part + (size_t)r * 640;
    s += *(const f32x4*)&row[ch0 + c4];
    q += *(const f32x4*)&row[320 + ch0 + c4];
  }
  sh_s[tid] = s; sh_q[tid] = q;
  __syncthreads();
  for (int off = 128; off >= 4; off >>= 1){
    if (tid < off){ sh_s[tid] += sh_s[tid + off]; sh_q[tid] += sh_q[tid + off]; }
    __syncthreads();
  }
  if (tid < 4){
    f32x4 S = sh_s[tid], Q = sh_q[tid];
#pragma unroll
    for (int j = 0; j < 4; j++){
      int ch = ch0 + (tid << 2) + j;
      float m  = S[j] * inv_cnt;
      float v  = Q[j] * inv_cnt - m * m;
      if (ch < 64){
        float sc = g0[ch] * rsqrtf(v + 1e-5f);
        stat[ST_SC_BN0 + ch] = sc;
        stat[ST_SH_BN0 + ch] = b0[ch] - m * sc;
      } else {
        int c = ch - 64;
        float sc = gs[c] * rsqrtf(v + 1e-5f);
        stat[ST_SC_SC + c] = sc;
        stat[ST_SH_SC + c] = bs[c] - m * sc;
      }
    }
  }
}

__global__ __launch_bounds__(256) void k_redA(
    const float* __restrict__ part, int nrows, int rowstride,
    int sum_off, int sq_off,
    const float* __restrict__ g, const float* __restrict__ bb,
    float inv_cnt, int gmod,
    float* __restrict__ scale, float* __restrict__ shift)
{
  __shared__ f32x4 sh_s[256], sh_q[256];
  const int tid = threadIdx.x;
  const int ch0 = blockIdx.x << 4;
  const int c4 = (tid & 3) << 2;
  const int stripe = tid >> 2;
  f32x4 s = {0.f,0.f,0.f,0.f}, q = {0.f,0.f,0.f,0.f};
  for (int r = stripe; r < nrows; r += 64){
    const float* row = part + (size_t)r * rowstride;
    s += *(const f32x4*)&row[sum_off + ch0 + c4];
    q += *(const f32x4*)&row[sq_off + ch0 + c4];
  }
  sh_s[tid] = s; sh_q[tid] = q;
  __syncthreads();
  for (int off = 128; off >= 4; off >>= 1){
    if (tid < off){ sh_s[tid] += sh_s[tid + off]; sh_q[tid] += sh_q[tid + off]; }
    __syncthreads();
  }
  if (tid < 4){
    f32x4 S = sh_s[tid], Q = sh_q[tid];
#pragma unroll
    for (int j = 0; j < 4; j++){
      int ch = ch0 + (tid << 2) + j;
      float m  = S[j] * inv_cnt;
      float v  = Q[j] * inv_cnt - m * m;
      float sc = g[ch % gmod] * rsqrtf(v + 1e-5f);
      scale[ch] = sc;
      shift[ch] = bb[ch % gmod] - m * sc;
    }
  }
}

__global__ __launch_bounds__(256) void k_redB(
    const float* __restrict__ part, int rows_per_b,
    const float* __restrict__ g, const float* __restrict__ bb, float inv_cnt,
    float* __restrict__ scale, float* __restrict__ shift)
{
  __shared__ f32x4 sh_s[256], sh_q[256];
  const int tid = threadIdx.x;
  const int b = blockIdx.x;
  const int c4 = (tid & 3) << 2;
  const int stripe = tid >> 2;
  const float* base = part + (size_t)b * rows_per_b * 32;
  f32x4 s = {0.f,0.f,0.f,0.f}, q = {0.f,0.f,0.f,0.f};
  for (int r = stripe; r < rows_per_b; r += 64){
    s += *(const f32x4*)&base[r * 32 + c4];
    q += *(const f32x4*)&base[r * 32 + 16 + c4];
  }
  sh_s[tid] = s; sh_q[tid] = q;
  __syncthreads();
  for (int off = 128; off >= 4; off >>= 1){
    if (tid < off){ sh_s[tid] += sh_s[tid + off]; sh_q[tid] += sh_q[tid + off]; }
    __syncthreads();
  }
  if (tid < 4){
    f32x4 S = sh_s[tid], Q = sh_q[tid];
#pragma unroll
    for (int j = 0; j < 4; j++){
      int c = (tid << 2) + j;
      float m  = S[j] * inv_cnt;
      float v  = Q[j] * inv_cnt - m * m;
      float sc = g[c] * rsqrtf(v + 1e-5f);
      scale[b * 16 + c] = sc;
      shift[b * 16 + c] = bb[c] - m * sc;
    }
  }
}

// =================================================================
// K3: IN1 stats -> pin1[blk*4+wv][32]
// =================================================================
__global__ __launch_bounds__(256) void k_in1_stats(
    const float* __restrict__ pos, const float* __restrict__ sup, const int* __restrict__ nbr,
    const float* __restrict__ fc1, const float* __restrict__ nrp, float* __restrict__ pin1)
{
  const int tid = threadIdx.x;
  const int b  = blockIdx.x >> 7;
  const int st = blockIdx.x & 127;
  const int sl = tid >> 4, k = tid & 15;
  const int s  = (st << 4) + sl;
  const int n  = nbr[((((size_t)b << 11) + s) << 4) + k];
  float* pr = pin1 + ((size_t)blockIdx.x * 4 + (tid >> 6)) * 32;
  const float inr = 1.0f / nrp[0];
  float p0 = (pos[((size_t)b * 3 + 0) * 8192 + n] - sup[((size_t)b * 3 + 0) * 2048 + s]) * inr;
  float p1 = (pos[((size_t)b * 3 + 1) * 8192 + n] - sup[((size_t)b * 3 + 1) * 2048 + s]) * inr;
  float p2 = (pos[((size_t)b * 3 + 2) * 8192 + n] - sup[((size_t)b * 3 + 2) * 2048 + s]) * inr;
#pragma unroll
  for (int q = 0; q < 16; q++){
    float z = fc1[q * 3] * p0 + fc1[q * 3 + 1] * p1 + fc1[q * 3 + 2] * p2;
    float a = z, c = z * z;
#pragma unroll
    for (int off = 32; off >= 1; off >>= 1){
      a += __shfl_xor(a, off, 64);
      c += __shfl_xor(c, off, 64);
    }
    if ((tid & 63) == q){
      pr[q]      = a;
      pr[16 + q] = c;
    }
  }
}

// =================================================================
// K4: IN2 stats -> pin2[blk*4+wv][32]
// =================================================================
__global__ __launch_bounds__(256) void k_in2_stats(
    const float* __restrict__ pos, const float* __restrict__ sup, const int* __restrict__ nbr,
    const float* __restrict__ fc1, const float* __restrict__ fc2,
    const float* __restrict__ alp, const float* __restrict__ bet, const float* __restrict__ nrp,
    const float* __restrict__ stat, float* __restrict__ pin2)
{
  __shared__ float fc2s[512];
  __shared__ float sc1s[16], sh1s[16];
  const int tid = threadIdx.x;
  const int b  = blockIdx.x >> 7;
  const int st = blockIdx.x & 127;
  fc2s[tid]       = fc2[tid];
  fc2s[tid + 256] = fc2[tid + 256];
  if (tid < 16){
    sc1s[tid] = stat[ST_SC_IN1 + (b << 4) + tid];
    sh1s[tid] = stat[ST_SH_IN1 + (b << 4) + tid];
  }
  __syncthreads();
  const int sl = tid >> 4, k = tid & 15;
  const int s  = (st << 4) + sl;
  const int n  = nbr[((((size_t)b << 11) + s) << 4) + k];
  float* pr = pin2 + ((size_t)blockIdx.x * 4 + (tid >> 6)) * 32;
  float t0 = pos[((size_t)b * 3 + 0) * 8192 + n] - sup[((size_t)b * 3 + 0) * 2048 + s];
  float t1 = pos[((size_t)b * 3 + 1) * 8192 + n] - sup[((size_t)b * 3 + 1) * 2048 + s];
  float t2 = pos[((size_t)b * 3 + 2) * 8192 + n] - sup[((size_t)b * 3 + 2) * 2048 + s];
  float dist = sqrtf(t0 * t0 + t1 * t1 + t2 * t2);
  float dw = 1.0f / (1.0f + expf(alp[0] * dist - bet[0]));
  float ssum = rsum16(dw);
  ssum += (ssum == 0.0f ? 1.0f : 0.0f) + 1e-6f;
  dw = dw / ssum * 16.0f;
  const float inr = 1.0f / nrp[0];
  float p0 = t0 * inr, p1 = t1 * inr, p2 = t2 * inr;
  float m1[16], mp1[16];
#pragma unroll
  for (int q = 0; q < 16; q++){
    float z = fc1[q * 3] * p0 + fc1[q * 3 + 1] * p1 + fc1[q * 3 + 2] * p2;
    m1[q] = fmaxf(z * sc1s[q] + sh1s[q], 0.0f);
  }
#pragma unroll
  for (int q = 0; q < 16; q++) mp1[q] = rmax16(m1[q] * dw);
#pragma unroll
  for (int q = 0; q < 16; q++){
    float z = 0.0f;
#pragma unroll
    for (int j = 0; j < 16; j++) z = fmaf(fc2s[q * 32 + j], m1[j], z);
#pragma unroll
    for (int j = 0; j < 16; j++) z = fmaf(fc2s[q * 32 + 16 + j], mp1[j], z);
    float a = z, c = z * z;
#pragma unroll
    for (int off = 32; off >= 1; off >>= 1){
      a += __shfl_xor(a, off, 64);
      c += __shfl_xor(c, off, 64);
    }
    if ((tid & 63) == q){
      pr[q]      = a;
      pr[16 + q] = c;
    }
  }
}

// =================================================================
// K5: FKA main + fused cv GEMM (Phase C).
// Phase A: geometry chain -> mat3 (LDS).
// Phase B: gather feat, agg[s][c*16+q] -> global (bf16).
// Phase C: per-wave MFMA hfka[s][o] = cvb @ agg (own agg rows: L2 hit)
//          + bn1 partials p6[blk][128].
// =================================================================
__global__ __launch_bounds__(256) void k_fka(
    const float* __restrict__ pos, const float* __restrict__ sup, const int* __restrict__ nbr,
    const float* __restrict__ fc1, const float* __restrict__ fc2, const float* __restrict__ fc3,
    const float* __restrict__ alp, const float* __restrict__ bet, const float* __restrict__ nrp,
    const __hip_bfloat16* __restrict__ y0t, const float* __restrict__ stat,
    __hip_bfloat16* __restrict__ agg, const __hip_bfloat16* __restrict__ cvb,
    float* __restrict__ hfka, float* __restrict__ p6)
{
  __shared__ float fc2s[512], fc3s[512];
  __shared__ float sc1s[16], sh1s[16], sc2s[16], sh2s[16];
  __shared__ float sc0s[64], sh0s[64];
  __shared__ float mat3_s[16][16][17];
  __shared__ float feat2_s[2][16][65];
  __shared__ int   idx_s[16][16];

  const int tid = threadIdx.x;
  const int b  = blockIdx.x >> 7;
  const int st = blockIdx.x & 127;
  fc2s[tid]       = fc2[tid];
  fc2s[tid + 256] = fc2[tid + 256];
  fc3s[tid]       = fc3[tid];
  fc3s[tid + 256] = fc3[tid + 256];
  if (tid < 16){
    sc1s[tid] = stat[ST_SC_IN1 + (b << 4) + tid];
    sh1s[tid] = stat[ST_SH_IN1 + (b << 4) + tid];
    sc2s[tid] = stat[ST_SC_IN2 + (b << 4) + tid];
    sh2s[tid] = stat[ST_SH_IN2 + (b << 4) + tid];
  }
  if (tid < 64){
    sc0s[tid] = stat[ST_SC_BN0 + tid];
    sh0s[tid] = stat[ST_SH_BN0 + tid];
  }
  const int sl = tid >> 4, k = tid & 15;
  const int s  = (st << 4) + sl;
  const int n  = nbr[((((size_t)b << 11) + s) << 4) + k];
  idx_s[sl][k] = n;
  __syncthreads();

  // ---- Phase A ----
  float t0 = pos[((size_t)b * 3 + 0) * 8192 + n] - sup[((size_t)b * 3 + 0) * 2048 + s];
  float t1 = pos[((size_t)b * 3 + 1) * 8192 + n] - sup[((size_t)b * 3 + 1) * 2048 + s];
  float t2 = pos[((size_t)b * 3 + 2) * 8192 + n] - sup[((size_t)b * 3 + 2) * 2048 + s];
  float dist = sqrtf(t0 * t0 + t1 * t1 + t2 * t2);
  float dw = 1.0f / (1.0f + expf(alp[0] * dist - bet[0]));
  float ssum = rsum16(dw);
  ssum += (ssum == 0.0f ? 1.0f : 0.0f) + 1e-6f;
  dw = dw / ssum * 16.0f;
  const float inr = 1.0f / nrp[0];
  float p0 = t0 * inr, p1 = t1 * inr, p2 = t2 * inr;
  float m1[16], mp1[16];
#pragma unroll
  for (int q = 0; q < 16; q++){
    float z = fc1[q * 3] * p0 + fc1[q * 3 + 1] * p1 + fc1[q * 3 + 2] * p2;
    m1[q] = fmaxf(z * sc1s[q] + sh1s[q], 0.0f);
  }
#pragma unroll
  for (int q = 0; q < 16; q++) mp1[q] = rmax16(m1[q] * dw);
  float m2[16], mp2[16];
#pragma unroll
  for (int q = 0; q < 16; q++){
    float z = 0.0f;
#pragma unroll
    for (int j = 0; j < 16; j++) z = fmaf(fc2s[q * 32 + j], m1[j], z);
#pragma unroll
    for (int j = 0; j < 16; j++) z = fmaf(fc2s[q * 32 + 16 + j], mp1[j], z);
    m2[q] = fmaxf(z * sc2s[q] + sh2s[q], 0.0f);
  }
#pragma unroll
  for (int q = 0; q < 16; q++) mp2[q] = rmax16(m2[q] * dw);
#pragma unroll
  for (int q = 0; q < 16; q++){
    float z = 0.0f;
#pragma unroll
    for (int j = 0; j < 16; j++) z = fmaf(fc3s[q * 32 + j], m2[j], z);
#pragma unroll
    for (int j = 0; j < 16; j++) z = fmaf(fc3s[q * 32 + 16 + j], mp2[j], z);
    mat3_s[sl][q][k] = fmaxf(z, 0.0f) * dw;
  }
  __syncthreads();

  // ---- Phase B ----
  const int h   = tid >> 7;
  const int r7  = tid & 127;
  const int gk  = r7 >> 3;
  const int gc8 = r7 & 7;
  const int cc  = r7 >> 1;
  const int qh  = r7 & 1;

  for (int it = 0; it < 8; it++){
    const int sl2 = it * 2 + h;
    {
      int nn = idx_s[sl2][gk];
      union { uint4 u; __hip_bfloat16 e[8]; } ld;
      ld.u = *(const uint4*)&y0t[((size_t)(b << 13) + nn) * 64 + gc8 * 8];
#pragma unroll
      for (int j = 0; j < 8; j++){
        int ch = gc8 * 8 + j;
        feat2_s[h][gk][ch] = fmaxf(__bfloat162float(ld.e[j]) * sc0s[ch] + sh0s[ch], 0.0f);
      }
    }
    __syncthreads();
    {
      float fv[16];
#pragma unroll
      for (int kk = 0; kk < 16; kk++) fv[kk] = feat2_s[h][kk][cc];
      union { uint4 u; __hip_bfloat16 e[8]; } pk;
#pragma unroll
      for (int q2 = 0; q2 < 8; q2++){
        int q = qh * 8 + q2;
        float a2 = 0.0f;
#pragma unroll
        for (int kk = 0; kk < 16; kk++) a2 = fmaf(fv[kk], mat3_s[sl2][q][kk], a2);
        pk.e[q2] = __float2bfloat16(a2);
      }
      int ss = (st << 4) + sl2;
      *(uint4*)&agg[((size_t)(b << 11) + ss) * 1024 + cc * 16 + qh * 8] = pk.u;
    }
    __syncthreads();   // drains vmcnt -> agg visible to Phase C
  }

  // ---- Phase C: hfka = cvb(64x1024) @ agg (M=16/wave, N=16 s, K=1024) ----
  {
    const int wv2 = tid >> 6, l2 = tid & 63;
    const int lr2 = l2 & 15, lg2 = l2 >> 4;
    const int s0 = st << 4;
    f32x4 accc = {0.f, 0.f, 0.f, 0.f};
    const __hip_bfloat16* brow = agg + ((size_t)(b << 11) + s0 + lr2) * 1024 + lg2 * 8;
    const __hip_bfloat16* arow = cvb + (size_t)(wv2 * 16 + lr2) * 1024 + lg2 * 8;
#pragma unroll 4
    for (int ks = 0; ks < 32; ks++){
      bf16x8 Bf = *(const bf16x8*)(brow + ks * 32);
      bf16x8 Af = *(const bf16x8*)(arow + ks * 32);
      accc = __builtin_amdgcn_mfma_f32_16x16x32_bf16(Af, Bf, accc, 0, 0, 0);
    }
    // write hfka: s = s0+lr2 (col), o = wv2*16 + lg2*4 + r (row)
    *(float4*)&hfka[((size_t)(b << 11) + s0 + lr2) * 64 + wv2 * 16 + (lg2 << 2)] =
        make_float4(accc[0], accc[1], accc[2], accc[3]);
    // bn1 partials: reduce over s (16 lanes of same lg2)
    float* p6row = p6 + (size_t)blockIdx.x * 128;
#pragma unroll
    for (int r = 0; r < 4; r++){
      float ss = accc[r], qq = ss * ss;
#pragma unroll
      for (int off = 8; off >= 1; off >>= 1){
        ss += __shfl_xor(ss, off, 16);
        qq += __shfl_xor(qq, off, 16);
      }
      if (lr2 == 0){
        int ch = wv2 * 16 + (lg2 << 2) + r;
        p6row[ch]      = ss;
        p6row[64 + ch] = qq;
      }
    }
  }
}

// =================================================================
// K7: MFMA cv2. Partials: p7[blk][512]
// =================================================================
__global__ __launch_bounds__(256) void k7_mfma(
    const float* __restrict__ hfka, const __hip_bfloat16* __restrict__ cv2b,
    const float* __restrict__ bias, const float* __restrict__ stat_ro,
    __hip_bfloat16* __restrict__ h2, float* __restrict__ p7)
{
  const int tid = threadIdx.x;
  const int b = blockIdx.x >> 5, stile = blockIdx.x & 31;
  const int s0 = stile << 6;
  const int wv = tid >> 6, l = tid & 63;
  const int lr = l & 15, lg = l >> 4;
  float* p7row = p7 + (size_t)blockIdx.x * 512;

  float s1r[2][8], h1r[2][8];
#pragma unroll
  for (int ks = 0; ks < 2; ks++)
#pragma unroll
    for (int j = 0; j < 8; j++){
      int ch = ks * 32 + lg * 8 + j;
      s1r[ks][j] = stat_ro[ST_SC_BN1 + ch];
      h1r[ks][j] = stat_ro[ST_SH_BN1 + ch];
    }

  bf16x8 B[2][4];
#pragma unroll
  for (int ks = 0; ks < 2; ks++)
#pragma unroll
    for (int nf = 0; nf < 4; nf++){
      int s = s0 + nf * 16 + lr;
      const float* hp = hfka + ((size_t)(b << 11) + s) * 64 + ks * 32 + lg * 8;
      float4 v0 = *(const float4*)hp;
      float4 v1 = *(const float4*)(hp + 4);
      float vv[8] = {v0.x, v0.y, v0.z, v0.w, v1.x, v1.y, v1.z, v1.w};
      union { bf16x8 f; __hip_bfloat16 e[8]; } pk;
#pragma unroll
      for (int j = 0; j < 8; j++)
        pk.e[j] = __float2bfloat16(fmaxf(vv[j] * s1r[ks][j] + h1r[ks][j], 0.0f));
      B[ks][nf] = pk.f;
    }

  f32x4 acc[4][4];
#pragma unroll
  for (int i = 0; i < 4; i++)
#pragma unroll
    for (int j = 0; j < 4; j++) acc[i][j] = (f32x4){0.f, 0.f, 0.f, 0.f};

  const __hip_bfloat16* arow = cv2b + (size_t)(wv * 64 + lr) * 64 + lg * 8;
#pragma unroll
  for (int ks = 0; ks < 2; ks++){
    bf16x8 A[4];
#pragma unroll
    for (int mf = 0; mf < 4; mf++) A[mf] = *(const bf16x8*)(arow + mf * 1024 + ks * 32);
#pragma unroll
    for (int mf = 0; mf < 4; mf++)
#pragma unroll
      for (int nf = 0; nf < 4; nf++)
        acc[mf][nf] = __builtin_amdgcn_mfma_f32_16x16x32_bf16(A[mf], B[ks][nf], acc[mf][nf], 0, 0, 0);
  }

#pragma unroll
  for (int mf = 0; mf < 4; mf++){
    const int m0 = wv * 64 + mf * 16 + lg * 4;
    float bv[4];
#pragma unroll
    for (int r = 0; r < 4; r++) bv[r] = bias[m0 + r];
#pragma unroll
    for (int nf = 0; nf < 4; nf++){
      int s = s0 + nf * 16 + lr;
      union { uint2 u; __hip_bfloat16 e[4]; } pk;
#pragma unroll
      for (int r = 0; r < 4; r++){
        acc[mf][nf][r] += bv[r];
        pk.e[r] = __float2bfloat16(acc[mf][nf][r]);
      }
      *(uint2*)&h2[((size_t)(b << 11) + s) * 256 + m0] = pk.u;
    }
#pragma unroll
    for (int r = 0; r < 4; r++){
      float ss = 0.f, qq = 0.f;
#pragma unroll
      for (int nf = 0; nf < 4; nf++){ float v = acc[mf][nf][r]; ss += v; qq += v * v; }
#pragma unroll
      for (int off = 8; off >= 1; off >>= 1){
        ss += __shfl_xor(ss, off, 16);
        qq += __shfl_xor(qq, off, 16);
      }
      if (lr == 0){
        p7row[m0 + r]       = ss;
        p7row[256 + m0 + r] = qq;
      }
    }
  }
}

// =================================================================
// K8: final
// =================================================================
__global__ __launch_bounds__(256) void k_final(
    const __hip_bfloat16* __restrict__ sct, const __hip_bfloat16* __restrict__ h2,
    const int* __restrict__ nbr, const float* __restrict__ stat, float* __restrict__ out)
{
  __shared__ int   idx_s[256];
  __shared__ float tile_s[16][257];
  const int tid = threadIdx.x;
  const int b  = blockIdx.x >> 7;
  const int st = blockIdx.x & 127;
  const int s0 = st << 4;
  idx_s[tid] = nbr[((size_t)(b << 11) + s0) * 16 + tid];
  const int sl = tid >> 4, cg = tid & 15, ch0 = cg << 4;

  float ssc[16], hsc[16], s2v[16], h2v[16];
#pragma unroll
  for (int j = 0; j < 16; j++){
    ssc[j] = stat[ST_SC_SC  + ch0 + j];
    hsc[j] = stat[ST_SH_SC  + ch0 + j];
    s2v[j] = stat[ST_SC_BN2 + ch0 + j];
    h2v[j] = stat[ST_SH_BN2 + ch0 + j];
  }
  __syncthreads();

  float mx[16];
#pragma unroll
  for (int j = 0; j < 16; j++) mx[j] = -3.4e38f;
  for (int k = 0; k < 16; k++){
    int nn = idx_s[sl * 16 + k];
    const uint4* p = (const uint4*)&sct[((size_t)(b << 13) + nn) * 256 + ch0];
    union { uint4 u; __hip_bfloat16 e[8]; } a0, a1;
    a0.u = p[0]; a1.u = p[1];
#pragma unroll
    for (int j = 0; j < 8; j++){
      mx[j]     = fmaxf(mx[j],     __bfloat162float(a0.e[j]) * ssc[j]     + hsc[j]);
      mx[j + 8] = fmaxf(mx[j + 8], __bfloat162float(a1.e[j]) * ssc[j + 8] + hsc[j + 8]);
    }
  }
  {
    const uint4* p = (const uint4*)&h2[((size_t)(b << 11) + s0 + sl) * 256 + ch0];
    union { uint4 u; __hip_bfloat16 e[8]; } a0, a1;
    a0.u = p[0]; a1.u = p[1];
#pragma unroll
    for (int j = 0; j < 8; j++){
      tile_s[sl][ch0 + j]     = fmaxf(__bfloat162float(a0.e[j]) * s2v[j]     + h2v[j]     + mx[j], 0.0f);
      tile_s[sl][ch0 + 8 + j] = fmaxf(__bfloat162float(a1.e[j]) * s2v[j + 8] + h2v[j + 8] + mx[j + 8], 0.0f);
    }
  }
  __syncthreads();
  const int o = tid;
#pragma unroll
  for (int p4 = 0; p4 < 4; p4++){
    float4 v = make_float4(tile_s[p4 * 4 + 0][o], tile_s[p4 * 4 + 1][o],
                           tile_s[p4 * 4 + 2][o], tile_s[p4 * 4 + 3][o]);
    *(float4*)&out[((size_t)(b << 8) + o) * 2048 + s0 + p4 * 4] = v;
  }
}

// =================================================================
extern "C" void kernel_launch(void* const* d_in, const int* in_sizes, int n_in,
                              void* d_out, int out_size, void* d_ws, size_t ws_size,
                              hipStream_t stream)
{
  (void)in_sizes; (void)n_in; (void)out_size; (void)ws_size;
  const float* x     = (const float*)d_in[0];
  const float* pos   = (const float*)d_in[1];
  const float* sup   = (const float*)d_in[2];
  const int*   nbr   = (const int*)d_in[3];
  const float* cv0w  = (const float*)d_in[5];
  const float* cv0b  = (const float*)d_in[6];
  const float* bn0g  = (const float*)d_in[7];
  const float* bn0b  = (const float*)d_in[8];
  const float* fc1   = (const float*)d_in[9];
  const float* fc2   = (const float*)d_in[10];
  const float* fc3   = (const float*)d_in[11];
  const float* in1g  = (const float*)d_in[12];
  const float* in1b  = (const float*)d_in[13];
  const float* in2g  = (const float*)d_in[14];
  const float* in2b  = (const float*)d_in[15];
  const float* alp   = (const float*)d_in[16];
  const float* bet   = (const float*)d_in[17];
  const float* nrp   = (const float*)d_in[18];
  const float* cvw   = (const float*)d_in[19];
  const float* bn1g  = (const float*)d_in[20];
  const float* bn1b  = (const float*)d_in[21];
  const float* cv2w  = (const float*)d_in[22];
  const float* cv2bi = (const float*)d_in[23];
  const float* bn2g  = (const float*)d_in[24];
  const float* bn2b  = (const float*)d_in[25];
  const float* scw   = (const float*)d_in[26];
  const float* scb   = (const float*)d_in[27];
  const float* bnscg = (const float*)d_in[28];
  const float* bnscb = (const float*)d_in[29];

  char* w = (char*)d_ws;
  __hip_bfloat16* sct  = (__hip_bfloat16*)(w);                  //  0       (64 MB)
  __hip_bfloat16* y0t  = (__hip_bfloat16*)(w + 67108864);       //  16 MB
  __hip_bfloat16* aggp = (__hip_bfloat16*)(w + 83886080);       //  64 MB (fka B..C)
  float*          pin1 = (float*)(w + 83886080);                //   1 MB (in1..red)
  float*          pin2 = (float*)(w + 84934656);                //   1 MB (in2..red)
  float*          p7   = (float*)(w + 83886080);                //   1 MB (k7..red)
  float*          hfka = (float*)(w + 150994944);               //   8 MB (fka C..k7)
  float*          p1   = (float*)(w + 150994944);               // 5.2 MB (k1..red)
  __hip_bfloat16* h2   = (__hip_bfloat16*)(w + 159383552);      //  16 MB (k7..final)
  float*          p6   = (float*)(w + 159383552);               //   1 MB (fka..red)
  __hip_bfloat16* wb   = (__hip_bfloat16*)(w + 176160768);
  __hip_bfloat16* cvb  = (__hip_bfloat16*)(w + 176242688);
  __hip_bfloat16* cv2b = (__hip_bfloat16*)(w + 176373760);
  float*          stat = (float*)(w + 192937984UL);

  k_prep_w<<<480, 256, 0, stream>>>(cv0w, scw, cvw, cv2w, wb, cvb, cv2b);
  k1_mfma<<<2048, 256, 0, stream>>>(x, wb, cv0b, scb, y0t, sct, p1);
  k_redP1<<<20, 256, 0, stream>>>(p1, 2048, bn0g, bn0b, bnscg, bnscb,
                                  1.0f / 131072.0f, stat);
  k_in1_stats<<<2048, 256, 0, stream>>>(pos, sup, nbr, fc1, nrp, pin1);
  k_redB<<<16, 256, 0, stream>>>(pin1, 512, in1g, in1b, 1.0f / 32768.0f,
                                 stat + ST_SC_IN1, stat + ST_SH_IN1);
  k_in2_stats<<<2048, 256, 0, stream>>>(pos, sup, nbr, fc1, fc2, alp, bet, nrp, stat, pin2);
  k_redB<<<16, 256, 0, stream>>>(pin2, 512, in2g, in2b, 1.0f / 32768.0f,
                                 stat + ST_SC_IN2, stat + ST_SH_IN2);
  k_fka<<<2048, 256, 0, stream>>>(pos, sup, nbr, fc1, fc2, fc3, alp, bet, nrp, y0t, stat,
                                  aggp, cvb, hfka, p6);
  k_redA<<<4, 256, 0, stream>>>(p6, 2048, 128, 0, 64, bn1g, bn1b,
                                1.0f / 32768.0f, 64, stat + ST_SC_BN1, stat + ST_SH_BN1);
  k7_mfma<<<512, 256, 0, stream>>>(hfka, cv2b, cv2bi, stat, h2, p7);
  k_redA<<<16, 256, 0, stream>>>(p7, 512, 512, 0, 256, bn2g, bn2b,
                                 1.0f / 32768.0f, 256, stat + ST_SC_BN2, stat + ST_SH_BN2);
  k_final<<<2048, 256, 0, stream>>>(sct, h2, nbr, stat, (float*)d_out);
}

// Round 9
// 480.618 us; speedup vs baseline: 3.1068x; 1.0294x over previous
//
#include <hip/hip_runtime.h>
#include <hip/hip_bf16.h>

#define DEV static __device__ __forceinline__

typedef __attribute__((ext_vector_type(8))) short bf16x8;
typedef __attribute__((ext_vector_type(4))) float f32x4;

// ---------------- stat layout (floats, inside ws) ----------------
#define ST_SC_BN0  0
#define ST_SH_BN0  64
#define ST_SC_SC   128
#define ST_SH_SC   384
#define ST_SC_IN1  640
#define ST_SH_IN1  896
#define ST_SC_IN2  1152
#define ST_SH_IN2  1408
#define ST_SC_BN1  1664
#define ST_SH_BN1  1728
#define ST_SC_BN2  1792
#define ST_SH_BN2  2048

DEV float rsum16(float v){
#pragma unroll
  for (int off = 8; off >= 1; off >>= 1) v += __shfl_xor(v, off, 16);
  return v;
}
DEV float rmax16(float v){
#pragma unroll
  for (int off = 8; off >= 1; off >>= 1) v = fmaxf(v, __shfl_xor(v, off, 16));
  return v;
}

// =================================================================
// P0: weight conversion f32 -> bf16.
// =================================================================
__global__ __launch_bounds__(256) void k_prep_w(
    const float* __restrict__ cv0w, const float* __restrict__ scw,
    const float* __restrict__ cvw,  const float* __restrict__ cv2w,
    __hip_bfloat16* __restrict__ wb, __hip_bfloat16* __restrict__ cvb,
    __hip_bfloat16* __restrict__ cv2b)
{
  int i = blockIdx.x * 256 + threadIdx.x;   // 0 .. 122879
  if (i < 40960){
    float v = (i < 8192) ? cv0w[i] : scw[i - 8192];
    wb[i] = __float2bfloat16(v);
  } else if (i < 106496){
    cvb[i - 40960] = __float2bfloat16(cvw[i - 40960]);
  } else {
    cv2b[i - 106496] = __float2bfloat16(cv2w[i - 106496]);
  }
}

// =================================================================
// K1: fused transpose + MFMA cv0+shortcut GEMM.
// =================================================================
__global__ __launch_bounds__(256) void k1_mfma(
    const float* __restrict__ x, const __hip_bfloat16* __restrict__ wb,
    const float* __restrict__ cv0b, const float* __restrict__ scb,
    __hip_bfloat16* __restrict__ y0t, __hip_bfloat16* __restrict__ sct,
    float* __restrict__ p1)
{
  __shared__ __hip_bfloat16 xt[64][136];   // row stride 272B -> conflict-free b128
  const int tid = threadIdx.x;
  const int b = blockIdx.x >> 7, nt = blockIdx.x & 127;
  const int n0 = nt << 6;
  const int wv = tid >> 6, l = tid & 63;
  const int lr = l & 15, lg = l >> 4;
  float* p1row = p1 + (size_t)blockIdx.x * 640;

#pragma unroll
  for (int p = 0; p < 8; p++){
    int c  = (p << 4) + (tid >> 4);
    int n4 = (tid & 15) << 2;
    float4 v = *(const float4*)&x[(((size_t)b * 128 + c) << 13) + n0 + n4];
    xt[n4 + 0][c] = __float2bfloat16(v.x);
    xt[n4 + 1][c] = __float2bfloat16(v.y);
    xt[n4 + 2][c] = __float2bfloat16(v.z);
    xt[n4 + 3][c] = __float2bfloat16(v.w);
  }
  __syncthreads();

  f32x4 acc[5][4];
#pragma unroll
  for (int i = 0; i < 5; i++)
#pragma unroll
    for (int j = 0; j < 4; j++) acc[i][j] = (f32x4){0.f, 0.f, 0.f, 0.f};

  const __hip_bfloat16* wrow = wb + (size_t)(wv * 80 + lr) * 128 + lg * 8;

#pragma unroll
  for (int ks = 0; ks < 4; ks++){
    bf16x8 B[4], A[5];
#pragma unroll
    for (int nf = 0; nf < 4; nf++)
      B[nf] = *(const bf16x8*)&xt[nf * 16 + lr][ks * 32 + lg * 8];
#pragma unroll
    for (int mf = 0; mf < 5; mf++) A[mf] = *(const bf16x8*)(wrow + mf * 2048 + ks * 32);
#pragma unroll
    for (int mf = 0; mf < 5; mf++)
#pragma unroll
      for (int nf = 0; nf < 4; nf++)
        acc[mf][nf] = __builtin_amdgcn_mfma_f32_16x16x32_bf16(A[mf], B[nf], acc[mf][nf], 0, 0, 0);
  }

#pragma unroll
  for (int mf = 0; mf < 5; mf++){
    const int m0 = wv * 80 + mf * 16 + lg * 4;
    float bv[4];
#pragma unroll
    for (int r = 0; r < 4; r++){
      int m = m0 + r;
      bv[r] = (m < 64) ? cv0b[m] : scb[m - 64];
    }
#pragma unroll
    for (int nf = 0; nf < 4; nf++)
#pragma unroll
      for (int r = 0; r < 4; r++) acc[mf][nf][r] += bv[r];

#pragma unroll
    for (int nf = 0; nf < 4; nf++){
      int n = n0 + nf * 16 + lr;
      union { uint2 u; __hip_bfloat16 e[4]; } pk;
#pragma unroll
      for (int r = 0; r < 4; r++) pk.e[r] = __float2bfloat16(acc[mf][nf][r]);
      if (m0 < 64)
        *(uint2*)&y0t[((size_t)(b << 13) + n) * 64 + m0] = pk.u;
      else
        *(uint2*)&sct[((size_t)(b << 13) + n) * 256 + (m0 - 64)] = pk.u;
    }
#pragma unroll
    for (int r = 0; r < 4; r++){
      float ss = 0.f, qq = 0.f;
#pragma unroll
      for (int nf = 0; nf < 4; nf++){ float v = acc[mf][nf][r]; ss += v; qq += v * v; }
#pragma unroll
      for (int off = 8; off >= 1; off >>= 1){
        ss += __shfl_xor(ss, off, 16);
        qq += __shfl_xor(qq, off, 16);
      }
      if (lr == 0){
        int ch = m0 + r;
        p1row[ch]       = ss;
        p1row[320 + ch] = qq;
      }
    }
  }
}

// =================================================================
// Fast reducers
// =================================================================
__global__ __launch_bounds__(256) void k_redP1(
    const float* __restrict__ part, int nrows,
    const float* __restrict__ g0, const float* __restrict__ b0,
    const float* __restrict__ gs, const float* __restrict__ bs,
    float inv_cnt, float* __restrict__ stat)
{
  __shared__ f32x4 sh_s[256], sh_q[256];
  const int tid = threadIdx.x;
  const int ch0 = blockIdx.x << 4;
  const int c4 = (tid & 3) << 2;
  const int stripe = tid >> 2;
  f32x4 s = {0.f,0.f,0.f,0.f}, q = {0.f,0.f,0.f,0.f};
  for (int r = stripe; r < nrows; r += 64){
    const float* row = part + (size_t)r * 640;
    s += *(const f32x4*)&row[ch0 + c4];
    q += *(const f32x4*)&row[320 + ch0 + c4];
  }
  sh_s[tid] = s; sh_q[tid] = q;
  __syncthreads();
  for (int off = 128; off >= 4; off >>= 1){
    if (tid < off){ sh_s[tid] += sh_s[tid + off]; sh_q[tid] += sh_q[tid + off]; }
    __syncthreads();
  }
  if (tid < 4){
    f32x4 S = sh_s[tid], Q = sh_q[tid];
#pragma unroll
    for (int j = 0; j < 4; j++){
      int ch = ch0 + (tid << 2) + j;
      float m  = S[j] * inv_cnt;
      float v  = Q[j] * inv_cnt - m * m;
      if (ch < 64){
        float sc = g0[ch] * rsqrtf(v + 1e-5f);
        stat[ST_SC_BN0 + ch] = sc;
        stat[ST_SH_BN0 + ch] = b0[ch] - m * sc;
      } else {
        int c = ch - 64;
        float sc = gs[c] * rsqrtf(v + 1e-5f);
        stat[ST_SC_SC + c] = sc;
        stat[ST_SH_SC + c] = bs[c] - m * sc;
      }
    }
  }
}

__global__ __launch_bounds__(256) void k_redA(
    const float* __restrict__ part, int nrows, int rowstride,
    int sum_off, int sq_off,
    const float* __restrict__ g, const float* __restrict__ bb,
    float inv_cnt, int gmod,
    float* __restrict__ scale, float* __restrict__ shift)
{
  __shared__ f32x4 sh_s[256], sh_q[256];
  const int tid = threadIdx.x;
  const int ch0 = blockIdx.x << 4;
  const int c4 = (tid & 3) << 2;
  const int stripe = tid >> 2;
  f32x4 s = {0.f,0.f,0.f,0.f}, q = {0.f,0.f,0.f,0.f};
  for (int r = stripe; r < nrows; r += 64){
    const float* row = part + (size_t)r * rowstride;
    s += *(const f32x4*)&row[sum_off + ch0 + c4];
    q += *(const f32x4*)&row[sq_off + ch0 + c4];
  }
  sh_s[tid] = s; sh_q[tid] = q;
  __syncthreads();
  for (int off = 128; off >= 4; off >>= 1){
    if (tid < off){ sh_s[tid] += sh_s[tid + off]; sh_q[tid] += sh_q[tid + off]; }
    __syncthreads();
  }
  if (tid < 4){
    f32x4 S = sh_s[tid], Q = sh_q[tid];
#pragma unroll
    for (int j = 0; j < 4; j++){
      int ch = ch0 + (tid << 2) + j;
      float m  = S[j] * inv_cnt;
      float v  = Q[j] * inv_cnt - m * m;
      float sc = g[ch % gmod] * rsqrtf(v + 1e-5f);
      scale[ch] = sc;
      shift[ch] = bb[ch % gmod] - m * sc;
    }
  }
}

__global__ __launch_bounds__(256) void k_redB(
    const float* __restrict__ part, int rows_per_b,
    const float* __restrict__ g, const float* __restrict__ bb, float inv_cnt,
    float* __restrict__ scale, float* __restrict__ shift)
{
  __shared__ f32x4 sh_s[256], sh_q[256];
  const int tid = threadIdx.x;
  const int b = blockIdx.x;
  const int c4 = (tid & 3) << 2;
  const int stripe = tid >> 2;
  const float* base = part + (size_t)b * rows_per_b * 32;
  f32x4 s = {0.f,0.f,0.f,0.f}, q = {0.f,0.f,0.f,0.f};
  for (int r = stripe; r < rows_per_b; r += 64){
    s += *(const f32x4*)&base[r * 32 + c4];
    q += *(const f32x4*)&base[r * 32 + 16 + c4];
  }
  sh_s[tid] = s; sh_q[tid] = q;
  __syncthreads();
  for (int off = 128; off >= 4; off >>= 1){
    if (tid < off){ sh_s[tid] += sh_s[tid + off]; sh_q[tid] += sh_q[tid + off]; }
    __syncthreads();
  }
  if (tid < 4){
    f32x4 S = sh_s[tid], Q = sh_q[tid];
#pragma unroll
    for (int j = 0; j < 4; j++){
      int c = (tid << 2) + j;
      float m  = S[j] * inv_cnt;
      float v  = Q[j] * inv_cnt - m * m;
      float sc = g[c] * rsqrtf(v + 1e-5f);
      scale[b * 16 + c] = sc;
      shift[b * 16 + c] = bb[c] - m * sc;
    }
  }
}

// =================================================================
// K3: IN1 stats -> pin1[blk*4+wv][32]
// =================================================================
__global__ __launch_bounds__(256) void k_in1_stats(
    const float* __restrict__ pos, const float* __restrict__ sup, const int* __restrict__ nbr,
    const float* __restrict__ fc1, const float* __restrict__ nrp, float* __restrict__ pin1)
{
  const int tid = threadIdx.x;
  const int b  = blockIdx.x >> 7;
  const int st = blockIdx.x & 127;
  const int sl = tid >> 4, k = tid & 15;
  const int s  = (st << 4) + sl;
  const int n  = nbr[((((size_t)b << 11) + s) << 4) + k];
  float* pr = pin1 + ((size_t)blockIdx.x * 4 + (tid >> 6)) * 32;
  const float inr = 1.0f / nrp[0];
  float p0 = (pos[((size_t)b * 3 + 0) * 8192 + n] - sup[((size_t)b * 3 + 0) * 2048 + s]) * inr;
  float p1 = (pos[((size_t)b * 3 + 1) * 8192 + n] - sup[((size_t)b * 3 + 1) * 2048 + s]) * inr;
  float p2 = (pos[((size_t)b * 3 + 2) * 8192 + n] - sup[((size_t)b * 3 + 2) * 2048 + s]) * inr;
#pragma unroll
  for (int q = 0; q < 16; q++){
    float z = fc1[q * 3] * p0 + fc1[q * 3 + 1] * p1 + fc1[q * 3 + 2] * p2;
    float a = z, c = z * z;
#pragma unroll
    for (int off = 32; off >= 1; off >>= 1){
      a += __shfl_xor(a, off, 64);
      c += __shfl_xor(c, off, 64);
    }
    if ((tid & 63) == q){
      pr[q]      = a;
      pr[16 + q] = c;
    }
  }
}

// =================================================================
// K4: IN2 stats -> pin2[blk*4+wv][32]
// =================================================================
__global__ __launch_bounds__(256) void k_in2_stats(
    const float* __restrict__ pos, const float* __restrict__ sup, const int* __restrict__ nbr,
    const float* __restrict__ fc1, const float* __restrict__ fc2,
    const float* __restrict__ alp, const float* __restrict__ bet, const float* __restrict__ nrp,
    const float* __restrict__ stat, float* __restrict__ pin2)
{
  __shared__ float fc2s[512];
  __shared__ float sc1s[16], sh1s[16];
  const int tid = threadIdx.x;
  const int b  = blockIdx.x >> 7;
  const int st = blockIdx.x & 127;
  fc2s[tid]       = fc2[tid];
  fc2s[tid + 256] = fc2[tid + 256];
  if (tid < 16){
    sc1s[tid] = stat[ST_SC_IN1 + (b << 4) + tid];
    sh1s[tid] = stat[ST_SH_IN1 + (b << 4) + tid];
  }
  __syncthreads();
  const int sl = tid >> 4, k = tid & 15;
  const int s  = (st << 4) + sl;
  const int n  = nbr[((((size_t)b << 11) + s) << 4) + k];
  float* pr = pin2 + ((size_t)blockIdx.x * 4 + (tid >> 6)) * 32;
  float t0 = pos[((size_t)b * 3 + 0) * 8192 + n] - sup[((size_t)b * 3 + 0) * 2048 + s];
  float t1 = pos[((size_t)b * 3 + 1) * 8192 + n] - sup[((size_t)b * 3 + 1) * 2048 + s];
  float t2 = pos[((size_t)b * 3 + 2) * 8192 + n] - sup[((size_t)b * 3 + 2) * 2048 + s];
  float dist = sqrtf(t0 * t0 + t1 * t1 + t2 * t2);
  float dw = 1.0f / (1.0f + expf(alp[0] * dist - bet[0]));
  float ssum = rsum16(dw);
  ssum += (ssum == 0.0f ? 1.0f : 0.0f) + 1e-6f;
  dw = dw / ssum * 16.0f;
  const float inr = 1.0f / nrp[0];
  float p0 = t0 * inr, p1 = t1 * inr, p2 = t2 * inr;
  float m1[16], mp1[16];
#pragma unroll
  for (int q = 0; q < 16; q++){
    float z = fc1[q * 3] * p0 + fc1[q * 3 + 1] * p1 + fc1[q * 3 + 2] * p2;
    m1[q] = fmaxf(z * sc1s[q] + sh1s[q], 0.0f);
  }
#pragma unroll
  for (int q = 0; q < 16; q++) mp1[q] = rmax16(m1[q] * dw);
#pragma unroll
  for (int q = 0; q < 16; q++){
    float z = 0.0f;
#pragma unroll
    for (int j = 0; j < 16; j++) z = fmaf(fc2s[q * 32 + j], m1[j], z);
#pragma unroll
    for (int j = 0; j < 16; j++) z = fmaf(fc2s[q * 32 + 16 + j], mp1[j], z);
    float a = z, c = z * z;
#pragma unroll
    for (int off = 32; off >= 1; off >>= 1){
      a += __shfl_xor(a, off, 64);
      c += __shfl_xor(c, off, 64);
    }
    if ((tid & 63) == q){
      pr[q]      = a;
      pr[16 + q] = c;
    }
  }
}

// =================================================================
// K5: FKA main + fused cv GEMM. agg lives ONLY in LDS (XOR-swizzled).
// Phase A: geometry chain -> mat3 (LDS).
// Phase B: gather feat -> agg_lds[16 s][1024 k] bf16, byte^((s&7)<<4).
// Phase C: per-wave MFMA hfka = cvb @ agg_lds + bn1 partials p6.
// =================================================================
__global__ __launch_bounds__(256) void k_fka(
    const float* __restrict__ pos, const float* __restrict__ sup, const int* __restrict__ nbr,
    const float* __restrict__ fc1, const float* __restrict__ fc2, const float* __restrict__ fc3,
    const float* __restrict__ alp, const float* __restrict__ bet, const float* __restrict__ nrp,
    const __hip_bfloat16* __restrict__ y0t, const float* __restrict__ stat,
    const __hip_bfloat16* __restrict__ cvb,
    float* __restrict__ hfka, float* __restrict__ p6)
{
  __shared__ float fc2s[512], fc3s[512];
  __shared__ float sc1s[16], sh1s[16], sc2s[16], sh2s[16];
  __shared__ float sc0s[64], sh0s[64];
  __shared__ float mat3_s[16][16][17];
  __shared__ float feat2_s[2][16][65];
  __shared__ int   idx_s[16][16];
  __shared__ __align__(16) char agg_lds[16 * 2048];   // 32 KB, XOR-swizzled rows

  const int tid = threadIdx.x;
  const int b  = blockIdx.x >> 7;
  const int st = blockIdx.x & 127;
  fc2s[tid]       = fc2[tid];
  fc2s[tid + 256] = fc2[tid + 256];
  fc3s[tid]       = fc3[tid];
  fc3s[tid + 256] = fc3[tid + 256];
  if (tid < 16){
    sc1s[tid] = stat[ST_SC_IN1 + (b << 4) + tid];
    sh1s[tid] = stat[ST_SH_IN1 + (b << 4) + tid];
    sc2s[tid] = stat[ST_SC_IN2 + (b << 4) + tid];
    sh2s[tid] = stat[ST_SH_IN2 + (b << 4) + tid];
  }
  if (tid < 64){
    sc0s[tid] = stat[ST_SC_BN0 + tid];
    sh0s[tid] = stat[ST_SH_BN0 + tid];
  }
  const int sl = tid >> 4, k = tid & 15;
  const int s  = (st << 4) + sl;
  const int n  = nbr[((((size_t)b << 11) + s) << 4) + k];
  idx_s[sl][k] = n;
  __syncthreads();

  // ---- Phase A ----
  float t0 = pos[((size_t)b * 3 + 0) * 8192 + n] - sup[((size_t)b * 3 + 0) * 2048 + s];
  float t1 = pos[((size_t)b * 3 + 1) * 8192 + n] - sup[((size_t)b * 3 + 1) * 2048 + s];
  float t2 = pos[((size_t)b * 3 + 2) * 8192 + n] - sup[((size_t)b * 3 + 2) * 2048 + s];
  float dist = sqrtf(t0 * t0 + t1 * t1 + t2 * t2);
  float dw = 1.0f / (1.0f + expf(alp[0] * dist - bet[0]));
  float ssum = rsum16(dw);
  ssum += (ssum == 0.0f ? 1.0f : 0.0f) + 1e-6f;
  dw = dw / ssum * 16.0f;
  const float inr = 1.0f / nrp[0];
  float p0 = t0 * inr, p1 = t1 * inr, p2 = t2 * inr;
  float m1[16], mp1[16];
#pragma unroll
  for (int q = 0; q < 16; q++){
    float z = fc1[q * 3] * p0 + fc1[q * 3 + 1] * p1 + fc1[q * 3 + 2] * p2;
    m1[q] = fmaxf(z * sc1s[q] + sh1s[q], 0.0f);
  }
#pragma unroll
  for (int q = 0; q < 16; q++) mp1[q] = rmax16(m1[q] * dw);
  float m2[16], mp2[16];
#pragma unroll
  for (int q = 0; q < 16; q++){
    float z = 0.0f;
#pragma unroll
    for (int j = 0; j < 16; j++) z = fmaf(fc2s[q * 32 + j], m1[j], z);
#pragma unroll
    for (int j = 0; j < 16; j++) z = fmaf(fc2s[q * 32 + 16 + j], mp1[j], z);
    m2[q] = fmaxf(z * sc2s[q] + sh2s[q], 0.0f);
  }
#pragma unroll
  for (int q = 0; q < 16; q++) mp2[q] = rmax16(m2[q] * dw);
#pragma unroll
  for (int q = 0; q < 16; q++){
    float z = 0.0f;
#pragma unroll
    for (int j = 0; j < 16; j++) z = fmaf(fc3s[q * 32 + j], m2[j], z);
#pragma unroll
    for (int j = 0; j < 16; j++) z = fmaf(fc3s[q * 32 + 16 + j], mp2[j], z);
    mat3_s[sl][q][k] = fmaxf(z, 0.0f) * dw;
  }
  __syncthreads();

  // ---- Phase B: gather + agg -> LDS (swizzled) ----
  const int h   = tid >> 7;
  const int r7  = tid & 127;
  const int gk  = r7 >> 3;
  const int gc8 = r7 & 7;
  const int cc  = r7 >> 1;
  const int qh  = r7 & 1;

  for (int it = 0; it < 8; it++){
    const int sl2 = it * 2 + h;
    {
      int nn = idx_s[sl2][gk];
      union { uint4 u; __hip_bfloat16 e[8]; } ld;
      ld.u = *(const uint4*)&y0t[((size_t)(b << 13) + nn) * 64 + gc8 * 8];
#pragma unroll
      for (int j = 0; j < 8; j++){
        int ch = gc8 * 8 + j;
        feat2_s[h][gk][ch] = fmaxf(__bfloat162float(ld.e[j]) * sc0s[ch] + sh0s[ch], 0.0f);
      }
    }
    __syncthreads();
    {
      float fv[16];
#pragma unroll
      for (int kk = 0; kk < 16; kk++) fv[kk] = feat2_s[h][kk][cc];
      union { uint4 u; __hip_bfloat16 e[8]; } pk;
#pragma unroll
      for (int q2 = 0; q2 < 8; q2++){
        int q = qh * 8 + q2;
        float a2 = 0.0f;
#pragma unroll
        for (int kk = 0; kk < 16; kk++) a2 = fmaf(fv[kk], mat3_s[sl2][q][kk], a2);
        pk.e[q2] = __float2bfloat16(a2);
      }
      int bo = ((cc * 16 + qh * 8) * 2) ^ ((sl2 & 7) << 4);
      *(uint4*)(agg_lds + sl2 * 2048 + bo) = pk.u;
    }
    __syncthreads();
  }

  // ---- Phase C: hfka = cvb(64x1024) @ agg_lds (M=16/wave, N=16 s, K=1024) ----
  {
    const int wv2 = tid >> 6, l2 = tid & 63;
    const int lr2 = l2 & 15, lg2 = l2 >> 4;
    const int s0 = st << 4;
    f32x4 accc = {0.f, 0.f, 0.f, 0.f};
    const __hip_bfloat16* arow = cvb + (size_t)(wv2 * 16 + lr2) * 1024 + lg2 * 8;
    const char* brow_base = agg_lds + lr2 * 2048;
    const int   bxor = (lr2 & 7) << 4;
#pragma unroll 4
    for (int ks = 0; ks < 32; ks++){
      int bo = ((lg2 * 8 + ks * 32) * 2) ^ bxor;
      bf16x8 Bf = *(const bf16x8*)(brow_base + bo);
      bf16x8 Af = *(const bf16x8*)(arow + ks * 32);
      accc = __builtin_amdgcn_mfma_f32_16x16x32_bf16(Af, Bf, accc, 0, 0, 0);
    }
    *(float4*)&hfka[((size_t)(b << 11) + s0 + lr2) * 64 + wv2 * 16 + (lg2 << 2)] =
        make_float4(accc[0], accc[1], accc[2], accc[3]);
    float* p6row = p6 + (size_t)blockIdx.x * 128;
#pragma unroll
    for (int r = 0; r < 4; r++){
      float ss = accc[r], qq = ss * ss;
#pragma unroll
      for (int off = 8; off >= 1; off >>= 1){
        ss += __shfl_xor(ss, off, 16);
        qq += __shfl_xor(qq, off, 16);
      }
      if (lr2 == 0){
        int ch = wv2 * 16 + (lg2 << 2) + r;
        p6row[ch]      = ss;
        p6row[64 + ch] = qq;
      }
    }
  }
}

// =================================================================
// K7: MFMA cv2. Partials: p7[blk][512]
// =================================================================
__global__ __launch_bounds__(256) void k7_mfma(
    const float* __restrict__ hfka, const __hip_bfloat16* __restrict__ cv2b,
    const float* __restrict__ bias, const float* __restrict__ stat_ro,
    __hip_bfloat16* __restrict__ h2, float* __restrict__ p7)
{
  const int tid = threadIdx.x;
  const int b = blockIdx.x >> 5, stile = blockIdx.x & 31;
  const int s0 = stile << 6;
  const int wv = tid >> 6, l = tid & 63;
  const int lr = l & 15, lg = l >> 4;
  float* p7row = p7 + (size_t)blockIdx.x * 512;

  float s1r[2][8], h1r[2][8];
#pragma unroll
  for (int ks = 0; ks < 2; ks++)
#pragma unroll
    for (int j = 0; j < 8; j++){
      int ch = ks * 32 + lg * 8 + j;
      s1r[ks][j] = stat_ro[ST_SC_BN1 + ch];
      h1r[ks][j] = stat_ro[ST_SH_BN1 + ch];
    }

  bf16x8 B[2][4];
#pragma unroll
  for (int ks = 0; ks < 2; ks++)
#pragma unroll
    for (int nf = 0; nf < 4; nf++){
      int s = s0 + nf * 16 + lr;
      const float* hp = hfka + ((size_t)(b << 11) + s) * 64 + ks * 32 + lg * 8;
      float4 v0 = *(const float4*)hp;
      float4 v1 = *(const float4*)(hp + 4);
      float vv[8] = {v0.x, v0.y, v0.z, v0.w, v1.x, v1.y, v1.z, v1.w};
      union { bf16x8 f; __hip_bfloat16 e[8]; } pk;
#pragma unroll
      for (int j = 0; j < 8; j++)
        pk.e[j] = __float2bfloat16(fmaxf(vv[j] * s1r[ks][j] + h1r[ks][j], 0.0f));
      B[ks][nf] = pk.f;
    }

  f32x4 acc[4][4];
#pragma unroll
  for (int i = 0; i < 4; i++)
#pragma unroll
    for (int j = 0; j < 4; j++) acc[i][j] = (f32x4){0.f, 0.f, 0.f, 0.f};

  const __hip_bfloat16* arow = cv2b + (size_t)(wv * 64 + lr) * 64 + lg * 8;
#pragma unroll
  for (int ks = 0; ks < 2; ks++){
    bf16x8 A[4];
#pragma unroll
    for (int mf = 0; mf < 4; mf++) A[mf] = *(const bf16x8*)(arow + mf * 1024 + ks * 32);
#pragma unroll
    for (int mf = 0; mf < 4; mf++)
#pragma unroll
      for (int nf = 0; nf < 4; nf++)
        acc[mf][nf] = __builtin_amdgcn_mfma_f32_16x16x32_bf16(A[mf], B[ks][nf], acc[mf][nf], 0, 0, 0);
  }

#pragma unroll
  for (int mf = 0; mf < 4; mf++){
    const int m0 = wv * 64 + mf * 16 + lg * 4;
    float bv[4];
#pragma unroll
    for (int r = 0; r < 4; r++) bv[r] = bias[m0 + r];
#pragma unroll
    for (int nf = 0; nf < 4; nf++){
      int s = s0 + nf * 16 + lr;
      union { uint2 u; __hip_bfloat16 e[4]; } pk;
#pragma unroll
      for (int r = 0; r < 4; r++){
        acc[mf][nf][r] += bv[r];
        pk.e[r] = __float2bfloat16(acc[mf][nf][r]);
      }
      *(uint2*)&h2[((size_t)(b << 11) + s) * 256 + m0] = pk.u;
    }
#pragma unroll
    for (int r = 0; r < 4; r++){
      float ss = 0.f, qq = 0.f;
#pragma unroll
      for (int nf = 0; nf < 4; nf++){ float v = acc[mf][nf][r]; ss += v; qq += v * v; }
#pragma unroll
      for (int off = 8; off >= 1; off >>= 1){
        ss += __shfl_xor(ss, off, 16);
        qq += __shfl_xor(qq, off, 16);
      }
      if (lr == 0){
        p7row[m0 + r]       = ss;
        p7row[256 + m0 + r] = qq;
      }
    }
  }
}

// =================================================================
// K8: final
// =================================================================
__global__ __launch_bounds__(256) void k_final(
    const __hip_bfloat16* __restrict__ sct, const __hip_bfloat16* __restrict__ h2,
    const int* __restrict__ nbr, const float* __restrict__ stat, float* __restrict__ out)
{
  __shared__ int   idx_s[256];
  __shared__ float tile_s[16][257];
  const int tid = threadIdx.x;
  const int b  = blockIdx.x >> 7;
  const int st = blockIdx.x & 127;
  const int s0 = st << 4;
  idx_s[tid] = nbr[((size_t)(b << 11) + s0) * 16 + tid];
  const int sl = tid >> 4, cg = tid & 15, ch0 = cg << 4;

  float ssc[16], hsc[16], s2v[16], h2v[16];
#pragma unroll
  for (int j = 0; j < 16; j++){
    ssc[j] = stat[ST_SC_SC  + ch0 + j];
    hsc[j] = stat[ST_SH_SC  + ch0 + j];
    s2v[j] = stat[ST_SC_BN2 + ch0 + j];
    h2v[j] = stat[ST_SH_BN2 + ch0 + j];
  }
  __syncthreads();

  float mx[16];
#pragma unroll
  for (int j = 0; j < 16; j++) mx[j] = -3.4e38f;
  for (int k = 0; k < 16; k++){
    int nn = idx_s[sl * 16 + k];
    const uint4* p = (const uint4*)&sct[((size_t)(b << 13) + nn) * 256 + ch0];
    union { uint4 u; __hip_bfloat16 e[8]; } a0, a1;
    a0.u = p[0]; a1.u = p[1];
#pragma unroll
    for (int j = 0; j < 8; j++){
      mx[j]     = fmaxf(mx[j],     __bfloat162float(a0.e[j]) * ssc[j]     + hsc[j]);
      mx[j + 8] = fmaxf(mx[j + 8], __bfloat162float(a1.e[j]) * ssc[j + 8] + hsc[j + 8]);
    }
  }
  {
    const uint4* p = (const uint4*)&h2[((size_t)(b << 11) + s0 + sl) * 256 + ch0];
    union { uint4 u; __hip_bfloat16 e[8]; } a0, a1;
    a0.u = p[0]; a1.u = p[1];
#pragma unroll
    for (int j = 0; j < 8; j++){
      tile_s[sl][ch0 + j]     = fmaxf(__bfloat162float(a0.e[j]) * s2v[j]     + h2v[j]     + mx[j], 0.0f);
      tile_s[sl][ch0 + 8 + j] = fmaxf(__bfloat162float(a1.e[j]) * s2v[j + 8] + h2v[j + 8] + mx[j + 8], 0.0f);
    }
  }
  __syncthreads();
  const int o = tid;
#pragma unroll
  for (int p4 = 0; p4 < 4; p4++){
    float4 v = make_float4(tile_s[p4 * 4 + 0][o], tile_s[p4 * 4 + 1][o],
                           tile_s[p4 * 4 + 2][o], tile_s[p4 * 4 + 3][o]);
    *(float4*)&out[((size_t)(b << 8) + o) * 2048 + s0 + p4 * 4] = v;
  }
}

// =================================================================
extern "C" void kernel_launch(void* const* d_in, const int* in_sizes, int n_in,
                              void* d_out, int out_size, void* d_ws, size_t ws_size,
                              hipStream_t stream)
{
  (void)in_sizes; (void)n_in; (void)out_size; (void)ws_size;
  const float* x     = (const float*)d_in[0];
  const float* pos   = (const float*)d_in[1];
  const float* sup   = (const float*)d_in[2];
  const int*   nbr   = (const int*)d_in[3];
  const float* cv0w  = (const float*)d_in[5];
  const float* cv0b  = (const float*)d_in[6];
  const float* bn0g  = (const float*)d_in[7];
  const float* bn0b  = (const float*)d_in[8];
  const float* fc1   = (const float*)d_in[9];
  const float* fc2   = (const float*)d_in[10];
  const float* fc3   = (const float*)d_in[11];
  const float* in1g  = (const float*)d_in[12];
  const float* in1b  = (const float*)d_in[13];
  const float* in2g  = (const float*)d_in[14];
  const float* in2b  = (const float*)d_in[15];
  const float* alp   = (const float*)d_in[16];
  const float* bet   = (const float*)d_in[17];
  const float* nrp   = (const float*)d_in[18];
  const float* cvw   = (const float*)d_in[19];
  const float* bn1g  = (const float*)d_in[20];
  const float* bn1b  = (const float*)d_in[21];
  const float* cv2w  = (const float*)d_in[22];
  const float* cv2bi = (const float*)d_in[23];
  const float* bn2g  = (const float*)d_in[24];
  const float* bn2b  = (const float*)d_in[25];
  const float* scw   = (const float*)d_in[26];
  const float* scb   = (const float*)d_in[27];
  const float* bnscg = (const float*)d_in[28];
  const float* bnscb = (const float*)d_in[29];

  char* w = (char*)d_ws;
  __hip_bfloat16* sct  = (__hip_bfloat16*)(w);                  //  0       (64 MB)
  __hip_bfloat16* y0t  = (__hip_bfloat16*)(w + 67108864);       //  16 MB
  float*          pin1 = (float*)(w + 83886080);                //   1 MB (in1..red)
  float*          pin2 = (float*)(w + 84934656);                //   1 MB (in2..red)
  float*          p7   = (float*)(w + 85983232);                //   1 MB (k7..red)
  float*          hfka = (float*)(w + 150994944);               //   8 MB (fka..k7)
  float*          p1   = (float*)(w + 160432128);               // 5.2 MB (k1..red)
  __hip_bfloat16* h2   = (__hip_bfloat16*)(w + 100663296);      //  16 MB (k7..final)
  float*          p6   = (float*)(w + 125829120);               //   1 MB (fka..red)
  __hip_bfloat16* wb   = (__hip_bfloat16*)(w + 176160768);
  __hip_bfloat16* cvb  = (__hip_bfloat16*)(w + 176242688);
  __hip_bfloat16* cv2b = (__hip_bfloat16*)(w + 176373760);
  float*          stat = (float*)(w + 192937984UL);

  k_prep_w<<<480, 256, 0, stream>>>(cv0w, scw, cvw, cv2w, wb, cvb, cv2b);
  k1_mfma<<<2048, 256, 0, stream>>>(x, wb, cv0b, scb, y0t, sct, p1);
  k_redP1<<<20, 256, 0, stream>>>(p1, 2048, bn0g, bn0b, bnscg, bnscb,
                                  1.0f / 131072.0f, stat);
  k_in1_stats<<<2048, 256, 0, stream>>>(pos, sup, nbr, fc1, nrp, pin1);
  k_redB<<<16, 256, 0, stream>>>(pin1, 512, in1g, in1b, 1.0f / 32768.0f,
                                 stat + ST_SC_IN1, stat + ST_SH_IN1);
  k_in2_stats<<<2048, 256, 0, stream>>>(pos, sup, nbr, fc1, fc2, alp, bet, nrp, stat, pin2);
  k_redB<<<16, 256, 0, stream>>>(pin2, 512, in2g, in2b, 1.0f / 32768.0f,
                                 stat + ST_SC_IN2, stat + ST_SH_IN2);
  k_fka<<<2048, 256, 0, stream>>>(pos, sup, nbr, fc1, fc2, fc3, alp, bet, nrp, y0t, stat,
                                  cvb, hfka, p6);
  k_redA<<<4, 256, 0, stream>>>(p6, 2048, 128, 0, 64, bn1g, bn1b,
                                1.0f / 32768.0f, 64, stat + ST_SC_BN1, stat + ST_SH_BN1);
  k7_mfma<<<512, 256, 0, stream>>>(hfka, cv2b, cv2bi, stat, h2, p7);
  k_redA<<<16, 256, 0, stream>>>(p7, 512, 512, 0, 256, bn2g, bn2b,
                                 1.0f / 32768.0f, 256, stat + ST_SC_BN2, stat + ST_SH_BN2);
  k_final<<<2048, 256, 0, stream>>>(sct, h2, nbr, stat, (float*)d_out);
}

// Round 10
// 479.546 us; speedup vs baseline: 3.1138x; 1.0022x over previous
//
#include <hip/hip_runtime.h>
#include <hip/hip_bf16.h>

#define DEV static __device__ __forceinline__

typedef __attribute__((ext_vector_type(8))) short bf16x8;
typedef __attribute__((ext_vector_type(4))) float f32x4;

// ---------------- stat layout (floats, inside ws) ----------------
#define ST_SC_BN0  0
#define ST_SH_BN0  64
#define ST_SC_SC   128
#define ST_SH_SC   384
#define ST_SC_IN1  640
#define ST_SH_IN1  896
#define ST_SC_IN2  1152
#define ST_SH_IN2  1408
#define ST_SC_BN1  1664
#define ST_SH_BN1  1728
#define ST_SC_BN2  1792
#define ST_SH_BN2  2048

DEV float rsum16(float v){
#pragma unroll
  for (int off = 8; off >= 1; off >>= 1) v += __shfl_xor(v, off, 16);
  return v;
}
DEV float rmax16(float v){
#pragma unroll
  for (int off = 8; off >= 1; off >>= 1) v = fmaxf(v, __shfl_xor(v, off, 16));
  return v;
}

// =================================================================
// P0: weight conversion f32 -> bf16.
// =================================================================
__global__ __launch_bounds__(256) void k_prep_w(
    const float* __restrict__ cv0w, const float* __restrict__ scw,
    const float* __restrict__ cvw,  const float* __restrict__ cv2w,
    __hip_bfloat16* __restrict__ wb, __hip_bfloat16* __restrict__ cvb,
    __hip_bfloat16* __restrict__ cv2b)
{
  int i = blockIdx.x * 256 + threadIdx.x;   // 0 .. 122879
  if (i < 40960){
    float v = (i < 8192) ? cv0w[i] : scw[i - 8192];
    wb[i] = __float2bfloat16(v);
  } else if (i < 106496){
    cvb[i - 40960] = __float2bfloat16(cvw[i - 40960]);
  } else {
    cv2b[i - 106496] = __float2bfloat16(cv2w[i - 106496]);
  }
}

// =================================================================
// K1: fused transpose + MFMA cv0+shortcut GEMM.
// =================================================================
__global__ __launch_bounds__(256) void k1_mfma(
    const float* __restrict__ x, const __hip_bfloat16* __restrict__ wb,
    const float* __restrict__ cv0b, const float* __restrict__ scb,
    __hip_bfloat16* __restrict__ y0t, __hip_bfloat16* __restrict__ sct,
    float* __restrict__ p1)
{
  __shared__ __hip_bfloat16 xt[64][136];   // row stride 272B -> conflict-free b128
  const int tid = threadIdx.x;
  const int b = blockIdx.x >> 7, nt = blockIdx.x & 127;
  const int n0 = nt << 6;
  const int wv = tid >> 6, l = tid & 63;
  const int lr = l & 15, lg = l >> 4;
  float* p1row = p1 + (size_t)blockIdx.x * 640;

#pragma unroll
  for (int p = 0; p < 8; p++){
    int c  = (p << 4) + (tid >> 4);
    int n4 = (tid & 15) << 2;
    float4 v = *(const float4*)&x[(((size_t)b * 128 + c) << 13) + n0 + n4];
    xt[n4 + 0][c] = __float2bfloat16(v.x);
    xt[n4 + 1][c] = __float2bfloat16(v.y);
    xt[n4 + 2][c] = __float2bfloat16(v.z);
    xt[n4 + 3][c] = __float2bfloat16(v.w);
  }
  __syncthreads();

  f32x4 acc[5][4];
#pragma unroll
  for (int i = 0; i < 5; i++)
#pragma unroll
    for (int j = 0; j < 4; j++) acc[i][j] = (f32x4){0.f, 0.f, 0.f, 0.f};

  const __hip_bfloat16* wrow = wb + (size_t)(wv * 80 + lr) * 128 + lg * 8;

#pragma unroll
  for (int ks = 0; ks < 4; ks++){
    bf16x8 B[4], A[5];
#pragma unroll
    for (int nf = 0; nf < 4; nf++)
      B[nf] = *(const bf16x8*)&xt[nf * 16 + lr][ks * 32 + lg * 8];
#pragma unroll
    for (int mf = 0; mf < 5; mf++) A[mf] = *(const bf16x8*)(wrow + mf * 2048 + ks * 32);
#pragma unroll
    for (int mf = 0; mf < 5; mf++)
#pragma unroll
      for (int nf = 0; nf < 4; nf++)
        acc[mf][nf] = __builtin_amdgcn_mfma_f32_16x16x32_bf16(A[mf], B[nf], acc[mf][nf], 0, 0, 0);
  }

#pragma unroll
  for (int mf = 0; mf < 5; mf++){
    const int m0 = wv * 80 + mf * 16 + lg * 4;
    float bv[4];
#pragma unroll
    for (int r = 0; r < 4; r++){
      int m = m0 + r;
      bv[r] = (m < 64) ? cv0b[m] : scb[m - 64];
    }
#pragma unroll
    for (int nf = 0; nf < 4; nf++)
#pragma unroll
      for (int r = 0; r < 4; r++) acc[mf][nf][r] += bv[r];

#pragma unroll
    for (int nf = 0; nf < 4; nf++){
      int n = n0 + nf * 16 + lr;
      union { uint2 u; __hip_bfloat16 e[4]; } pk;
#pragma unroll
      for (int r = 0; r < 4; r++) pk.e[r] = __float2bfloat16(acc[mf][nf][r]);
      if (m0 < 64)
        *(uint2*)&y0t[((size_t)(b << 13) + n) * 64 + m0] = pk.u;
      else
        *(uint2*)&sct[((size_t)(b << 13) + n) * 256 + (m0 - 64)] = pk.u;
    }
#pragma unroll
    for (int r = 0; r < 4; r++){
      float ss = 0.f, qq = 0.f;
#pragma unroll
      for (int nf = 0; nf < 4; nf++){ float v = acc[mf][nf][r]; ss += v; qq += v * v; }
#pragma unroll
      for (int off = 8; off >= 1; off >>= 1){
        ss += __shfl_xor(ss, off, 16);
        qq += __shfl_xor(qq, off, 16);
      }
      if (lr == 0){
        int ch = m0 + r;
        p1row[ch]       = ss;
        p1row[320 + ch] = qq;
      }
    }
  }
}

// =================================================================
// Fast reducers
// =================================================================
__global__ __launch_bounds__(256) void k_redP1(
    const float* __restrict__ part, int nrows,
    const float* __restrict__ g0, const float* __restrict__ b0,
    const float* __restrict__ gs, const float* __restrict__ bs,
    float inv_cnt, float* __restrict__ stat)
{
  __shared__ f32x4 sh_s[256], sh_q[256];
  const int tid = threadIdx.x;
  const int ch0 = blockIdx.x << 4;
  const int c4 = (tid & 3) << 2;
  const int stripe = tid >> 2;
  f32x4 s = {0.f,0.f,0.f,0.f}, q = {0.f,0.f,0.f,0.f};
  for (int r = stripe; r < nrows; r += 64){
    const float* row = part + (size_t)r * 640;
    s += *(const f32x4*)&row[ch0 + c4];
    q += *(const f32x4*)&row[320 + ch0 + c4];
  }
  sh_s[tid] = s; sh_q[tid] = q;
  __syncthreads();
  for (int off = 128; off >= 4; off >>= 1){
    if (tid < off){ sh_s[tid] += sh_s[tid + off]; sh_q[tid] += sh_q[tid + off]; }
    __syncthreads();
  }
  if (tid < 4){
    f32x4 S = sh_s[tid], Q = sh_q[tid];
#pragma unroll
    for (int j = 0; j < 4; j++){
      int ch = ch0 + (tid << 2) + j;
      float m  = S[j] * inv_cnt;
      float v  = Q[j] * inv_cnt - m * m;
      if (ch < 64){
        float sc = g0[ch] * rsqrtf(v + 1e-5f);
        stat[ST_SC_BN0 + ch] = sc;
        stat[ST_SH_BN0 + ch] = b0[ch] - m * sc;
      } else {
        int c = ch - 64;
        float sc = gs[c] * rsqrtf(v + 1e-5f);
        stat[ST_SC_SC + c] = sc;
        stat[ST_SH_SC + c] = bs[c] - m * sc;
      }
    }
  }
}

__global__ __launch_bounds__(256) void k_redA(
    const float* __restrict__ part, int nrows, int rowstride,
    int sum_off, int sq_off,
    const float* __restrict__ g, const float* __restrict__ bb,
    float inv_cnt, int gmod,
    float* __restrict__ scale, float* __restrict__ shift)
{
  __shared__ f32x4 sh_s[256], sh_q[256];
  const int tid = threadIdx.x;
  const int ch0 = blockIdx.x << 4;
  const int c4 = (tid & 3) << 2;
  const int stripe = tid >> 2;
  f32x4 s = {0.f,0.f,0.f,0.f}, q = {0.f,0.f,0.f,0.f};
  for (int r = stripe; r < nrows; r += 64){
    const float* row = part + (size_t)r * rowstride;
    s += *(const f32x4*)&row[sum_off + ch0 + c4];
    q += *(const f32x4*)&row[sq_off + ch0 + c4];
  }
  sh_s[tid] = s; sh_q[tid] = q;
  __syncthreads();
  for (int off = 128; off >= 4; off >>= 1){
    if (tid < off){ sh_s[tid] += sh_s[tid + off]; sh_q[tid] += sh_q[tid + off]; }
    __syncthreads();
  }
  if (tid < 4){
    f32x4 S = sh_s[tid], Q = sh_q[tid];
#pragma unroll
    for (int j = 0; j < 4; j++){
      int ch = ch0 + (tid << 2) + j;
      float m  = S[j] * inv_cnt;
      float v  = Q[j] * inv_cnt - m * m;
      float sc = g[ch % gmod] * rsqrtf(v + 1e-5f);
      scale[ch] = sc;
      shift[ch] = bb[ch % gmod] - m * sc;
    }
  }
}

__global__ __launch_bounds__(256) void k_redB(
    const float* __restrict__ part, int rows_per_b,
    const float* __restrict__ g, const float* __restrict__ bb, float inv_cnt,
    float* __restrict__ scale, float* __restrict__ shift)
{
  __shared__ f32x4 sh_s[256], sh_q[256];
  const int tid = threadIdx.x;
  const int b = blockIdx.x;
  const int c4 = (tid & 3) << 2;
  const int stripe = tid >> 2;
  const float* base = part + (size_t)b * rows_per_b * 32;
  f32x4 s = {0.f,0.f,0.f,0.f}, q = {0.f,0.f,0.f,0.f};
  for (int r = stripe; r < rows_per_b; r += 64){
    s += *(const f32x4*)&base[r * 32 + c4];
    q += *(const f32x4*)&base[r * 32 + 16 + c4];
  }
  sh_s[tid] = s; sh_q[tid] = q;
  __syncthreads();
  for (int off = 128; off >= 4; off >>= 1){
    if (tid < off){ sh_s[tid] += sh_s[tid + off]; sh_q[tid] += sh_q[tid + off]; }
    __syncthreads();
  }
  if (tid < 4){
    f32x4 S = sh_s[tid], Q = sh_q[tid];
#pragma unroll
    for (int j = 0; j < 4; j++){
      int c = (tid << 2) + j;
      float m  = S[j] * inv_cnt;
      float v  = Q[j] * inv_cnt - m * m;
      float sc = g[c] * rsqrtf(v + 1e-5f);
      scale[b * 16 + c] = sc;
      shift[b * 16 + c] = bb[c] - m * sc;
    }
  }
}

// =================================================================
// K3: IN1 stats -> pin1[blk*4+wv][32]
// =================================================================
__global__ __launch_bounds__(256) void k_in1_stats(
    const float* __restrict__ pos, const float* __restrict__ sup, const int* __restrict__ nbr,
    const float* __restrict__ fc1, const float* __restrict__ nrp, float* __restrict__ pin1)
{
  const int tid = threadIdx.x;
  const int b  = blockIdx.x >> 7;
  const int st = blockIdx.x & 127;
  const int sl = tid >> 4, k = tid & 15;
  const int s  = (st << 4) + sl;
  const int n  = nbr[((((size_t)b << 11) + s) << 4) + k];
  float* pr = pin1 + ((size_t)blockIdx.x * 4 + (tid >> 6)) * 32;
  const float inr = 1.0f / nrp[0];
  float p0 = (pos[((size_t)b * 3 + 0) * 8192 + n] - sup[((size_t)b * 3 + 0) * 2048 + s]) * inr;
  float p1 = (pos[((size_t)b * 3 + 1) * 8192 + n] - sup[((size_t)b * 3 + 1) * 2048 + s]) * inr;
  float p2 = (pos[((size_t)b * 3 + 2) * 8192 + n] - sup[((size_t)b * 3 + 2) * 2048 + s]) * inr;
#pragma unroll
  for (int q = 0; q < 16; q++){
    float z = fc1[q * 3] * p0 + fc1[q * 3 + 1] * p1 + fc1[q * 3 + 2] * p2;
    float a = z, c = z * z;
#pragma unroll
    for (int off = 32; off >= 1; off >>= 1){
      a += __shfl_xor(a, off, 64);
      c += __shfl_xor(c, off, 64);
    }
    if ((tid & 63) == q){
      pr[q]      = a;
      pr[16 + q] = c;
    }
  }
}

// =================================================================
// K4: IN2 stats -> pin2[blk*4+wv][32]
// =================================================================
__global__ __launch_bounds__(256) void k_in2_stats(
    const float* __restrict__ pos, const float* __restrict__ sup, const int* __restrict__ nbr,
    const float* __restrict__ fc1, const float* __restrict__ fc2,
    const float* __restrict__ alp, const float* __restrict__ bet, const float* __restrict__ nrp,
    const float* __restrict__ stat, float* __restrict__ pin2)
{
  __shared__ float fc2s[512];
  __shared__ float sc1s[16], sh1s[16];
  const int tid = threadIdx.x;
  const int b  = blockIdx.x >> 7;
  const int st = blockIdx.x & 127;
  fc2s[tid]       = fc2[tid];
  fc2s[tid + 256] = fc2[tid + 256];
  if (tid < 16){
    sc1s[tid] = stat[ST_SC_IN1 + (b << 4) + tid];
    sh1s[tid] = stat[ST_SH_IN1 + (b << 4) + tid];
  }
  __syncthreads();
  const int sl = tid >> 4, k = tid & 15;
  const int s  = (st << 4) + sl;
  const int n  = nbr[((((size_t)b << 11) + s) << 4) + k];
  float* pr = pin2 + ((size_t)blockIdx.x * 4 + (tid >> 6)) * 32;
  float t0 = pos[((size_t)b * 3 + 0) * 8192 + n] - sup[((size_t)b * 3 + 0) * 2048 + s];
  float t1 = pos[((size_t)b * 3 + 1) * 8192 + n] - sup[((size_t)b * 3 + 1) * 2048 + s];
  float t2 = pos[((size_t)b * 3 + 2) * 8192 + n] - sup[((size_t)b * 3 + 2) * 2048 + s];
  float dist = sqrtf(t0 * t0 + t1 * t1 + t2 * t2);
  float dw = 1.0f / (1.0f + expf(alp[0] * dist - bet[0]));
  float ssum = rsum16(dw);
  ssum += (ssum == 0.0f ? 1.0f : 0.0f) + 1e-6f;
  dw = dw / ssum * 16.0f;
  const float inr = 1.0f / nrp[0];
  float p0 = t0 * inr, p1 = t1 * inr, p2 = t2 * inr;
  float m1[16], mp1[16];
#pragma unroll
  for (int q = 0; q < 16; q++){
    float z = fc1[q * 3] * p0 + fc1[q * 3 + 1] * p1 + fc1[q * 3 + 2] * p2;
    m1[q] = fmaxf(z * sc1s[q] + sh1s[q], 0.0f);
  }
#pragma unroll
  for (int q = 0; q < 16; q++) mp1[q] = rmax16(m1[q] * dw);
#pragma unroll
  for (int q = 0; q < 16; q++){
    float z = 0.0f;
#pragma unroll
    for (int j = 0; j < 16; j++) z = fmaf(fc2s[q * 32 + j], m1[j], z);
#pragma unroll
    for (int j = 0; j < 16; j++) z = fmaf(fc2s[q * 32 + 16 + j], mp1[j], z);
    float a = z, c = z * z;
#pragma unroll
    for (int off = 32; off >= 1; off >>= 1){
      a += __shfl_xor(a, off, 64);
      c += __shfl_xor(c, off, 64);
    }
    if ((tid & 63) == q){
      pr[q]      = a;
      pr[16 + q] = c;
    }
  }
}

// =================================================================
// K5: FKA main + fused cv GEMM. agg in LDS only, TWO 8-row passes
// to halve the LDS footprint (16 KB agg -> 3 blocks/CU).
// Phase A: geometry chain -> mat3 (LDS).
// Per half: Phase B fills agg_lds[8][1024] (XOR-swizzled rows);
//           Phase C MFMAs those 8 s-rows (lanes lr2>=8 duplicate,
//           don't store; p6 lane-reduce double-counts -> x0.5).
// =================================================================
__global__ __launch_bounds__(256) void k_fka(
    const float* __restrict__ pos, const float* __restrict__ sup, const int* __restrict__ nbr,
    const float* __restrict__ fc1, const float* __restrict__ fc2, const float* __restrict__ fc3,
    const float* __restrict__ alp, const float* __restrict__ bet, const float* __restrict__ nrp,
    const __hip_bfloat16* __restrict__ y0t, const float* __restrict__ stat,
    const __hip_bfloat16* __restrict__ cvb,
    float* __restrict__ hfka, float* __restrict__ p6)
{
  __shared__ float fc2s[512], fc3s[512];
  __shared__ float sc1s[16], sh1s[16], sc2s[16], sh2s[16];
  __shared__ float sc0s[64], sh0s[64];
  __shared__ float mat3_s[16][16][17];
  __shared__ float feat2_s[2][16][65];
  __shared__ int   idx_s[16][16];
  __shared__ __align__(16) char agg_lds[8 * 2048];   // 16 KB, XOR-swizzled rows

  const int tid = threadIdx.x;
  const int b  = blockIdx.x >> 7;
  const int st = blockIdx.x & 127;
  fc2s[tid]       = fc2[tid];
  fc2s[tid + 256] = fc2[tid + 256];
  fc3s[tid]       = fc3[tid];
  fc3s[tid + 256] = fc3[tid + 256];
  if (tid < 16){
    sc1s[tid] = stat[ST_SC_IN1 + (b << 4) + tid];
    sh1s[tid] = stat[ST_SH_IN1 + (b << 4) + tid];
    sc2s[tid] = stat[ST_SC_IN2 + (b << 4) + tid];
    sh2s[tid] = stat[ST_SH_IN2 + (b << 4) + tid];
  }
  if (tid < 64){
    sc0s[tid] = stat[ST_SC_BN0 + tid];
    sh0s[tid] = stat[ST_SH_BN0 + tid];
  }
  const int sl = tid >> 4, k = tid & 15;
  const int s  = (st << 4) + sl;
  const int n  = nbr[((((size_t)b << 11) + s) << 4) + k];
  idx_s[sl][k] = n;
  __syncthreads();

  // ---- Phase A ----
  float t0 = pos[((size_t)b * 3 + 0) * 8192 + n] - sup[((size_t)b * 3 + 0) * 2048 + s];
  float t1 = pos[((size_t)b * 3 + 1) * 8192 + n] - sup[((size_t)b * 3 + 1) * 2048 + s];
  float t2 = pos[((size_t)b * 3 + 2) * 8192 + n] - sup[((size_t)b * 3 + 2) * 2048 + s];
  float dist = sqrtf(t0 * t0 + t1 * t1 + t2 * t2);
  float dw = 1.0f / (1.0f + expf(alp[0] * dist - bet[0]));
  float ssum = rsum16(dw);
  ssum += (ssum == 0.0f ? 1.0f : 0.0f) + 1e-6f;
  dw = dw / ssum * 16.0f;
  const float inr = 1.0f / nrp[0];
  float p0 = t0 * inr, p1 = t1 * inr, p2 = t2 * inr;
  float m1[16], mp1[16];
#pragma unroll
  for (int q = 0; q < 16; q++){
    float z = fc1[q * 3] * p0 + fc1[q * 3 + 1] * p1 + fc1[q * 3 + 2] * p2;
    m1[q] = fmaxf(z * sc1s[q] + sh1s[q], 0.0f);
  }
#pragma unroll
  for (int q = 0; q < 16; q++) mp1[q] = rmax16(m1[q] * dw);
  float m2[16], mp2[16];
#pragma unroll
  for (int q = 0; q < 16; q++){
    float z = 0.0f;
#pragma unroll
    for (int j = 0; j < 16; j++) z = fmaf(fc2s[q * 32 + j], m1[j], z);
#pragma unroll
    for (int j = 0; j < 16; j++) z = fmaf(fc2s[q * 32 + 16 + j], mp1[j], z);
    m2[q] = fmaxf(z * sc2s[q] + sh2s[q], 0.0f);
  }
#pragma unroll
  for (int q = 0; q < 16; q++) mp2[q] = rmax16(m2[q] * dw);
#pragma unroll
  for (int q = 0; q < 16; q++){
    float z = 0.0f;
#pragma unroll
    for (int j = 0; j < 16; j++) z = fmaf(fc3s[q * 32 + j], m2[j], z);
#pragma unroll
    for (int j = 0; j < 16; j++) z = fmaf(fc3s[q * 32 + 16 + j], mp2[j], z);
    mat3_s[sl][q][k] = fmaxf(z, 0.0f) * dw;
  }
  __syncthreads();

  // ---- two half-passes over s ----
  const int h   = tid >> 7;
  const int r7  = tid & 127;
  const int gk  = r7 >> 3;
  const int gc8 = r7 & 7;
  const int cc  = r7 >> 1;
  const int qh  = r7 & 1;

  const int wv2 = tid >> 6, l2 = tid & 63;
  const int lr2 = l2 & 15, lg2 = l2 >> 4;
  const int s0 = st << 4;
  const char* brow_base = agg_lds + (lr2 & 7) * 2048;
  const int   bxor = (lr2 & 7) << 4;
  const __hip_bfloat16* arow = cvb + (size_t)(wv2 * 16 + lr2) * 1024 + lg2 * 8;

  float psum[4] = {0.f, 0.f, 0.f, 0.f};
  float psq[4]  = {0.f, 0.f, 0.f, 0.f};

  for (int half = 0; half < 2; half++){
    // Phase B: 4 iterations, 2 s-rows each -> agg_lds rows 0..7
    for (int it = 0; it < 4; it++){
      const int sl2 = half * 8 + it * 2 + h;
      {
        int nn = idx_s[sl2][gk];
        union { uint4 u; __hip_bfloat16 e[8]; } ld;
        ld.u = *(const uint4*)&y0t[((size_t)(b << 13) + nn) * 64 + gc8 * 8];
#pragma unroll
        for (int j = 0; j < 8; j++){
          int ch = gc8 * 8 + j;
          feat2_s[h][gk][ch] = fmaxf(__bfloat162float(ld.e[j]) * sc0s[ch] + sh0s[ch], 0.0f);
        }
      }
      __syncthreads();
      {
        float fv[16];
#pragma unroll
        for (int kk = 0; kk < 16; kk++) fv[kk] = feat2_s[h][kk][cc];
        union { uint4 u; __hip_bfloat16 e[8]; } pk;
#pragma unroll
        for (int q2 = 0; q2 < 8; q2++){
          int q = qh * 8 + q2;
          float a2 = 0.0f;
#pragma unroll
          for (int kk = 0; kk < 16; kk++) a2 = fmaf(fv[kk], mat3_s[sl2][q][kk], a2);
          pk.e[q2] = __float2bfloat16(a2);
        }
        int bo = ((cc * 16 + qh * 8) * 2) ^ ((sl2 & 7) << 4);
        *(uint4*)(agg_lds + (sl2 & 7) * 2048 + bo) = pk.u;
      }
      __syncthreads();
    }

    // Phase C half: 8 s-rows; lanes lr2>=8 read duplicates, don't store.
    {
      f32x4 accc = {0.f, 0.f, 0.f, 0.f};
#pragma unroll 4
      for (int ks = 0; ks < 32; ks++){
        int bo = ((lg2 * 8 + ks * 32) * 2) ^ bxor;
        bf16x8 Bf = *(const bf16x8*)(brow_base + bo);
        bf16x8 Af = *(const bf16x8*)(arow + ks * 32);
        accc = __builtin_amdgcn_mfma_f32_16x16x32_bf16(Af, Bf, accc, 0, 0, 0);
      }
      if (lr2 < 8){
        *(float4*)&hfka[((size_t)(b << 11) + s0 + half * 8 + lr2) * 64 + wv2 * 16 + (lg2 << 2)] =
            make_float4(accc[0], accc[1], accc[2], accc[3]);
      }
#pragma unroll
      for (int r = 0; r < 4; r++){
        float ss = accc[r], qq = ss * ss;
#pragma unroll
        for (int off = 8; off >= 1; off >>= 1){
          ss += __shfl_xor(ss, off, 16);
          qq += __shfl_xor(qq, off, 16);
        }
        psum[r] += ss;   // 2x the 8-row sum (duplicate lanes)
        psq[r]  += qq;
      }
      __syncthreads();   // agg_lds reusable by next half
    }
  }

  // bn1 partials (x0.5 corrects the duplicate-lane double count)
  {
    float* p6row = p6 + (size_t)blockIdx.x * 128;
    if (lr2 == 0){
#pragma unroll
      for (int r = 0; r < 4; r++){
        int ch = wv2 * 16 + (lg2 << 2) + r;
        p6row[ch]      = 0.5f * psum[r];
        p6row[64 + ch] = 0.5f * psq[r];
      }
    }
  }
}

// =================================================================
// K7: MFMA cv2. Partials: p7[blk][512]
// =================================================================
__global__ __launch_bounds__(256) void k7_mfma(
    const float* __restrict__ hfka, const __hip_bfloat16* __restrict__ cv2b,
    const float* __restrict__ bias, const float* __restrict__ stat_ro,
    __hip_bfloat16* __restrict__ h2, float* __restrict__ p7)
{
  const int tid = threadIdx.x;
  const int b = blockIdx.x >> 5, stile = blockIdx.x & 31;
  const int s0 = stile << 6;
  const int wv = tid >> 6, l = tid & 63;
  const int lr = l & 15, lg = l >> 4;
  float* p7row = p7 + (size_t)blockIdx.x * 512;

  float s1r[2][8], h1r[2][8];
#pragma unroll
  for (int ks = 0; ks < 2; ks++)
#pragma unroll
    for (int j = 0; j < 8; j++){
      int ch = ks * 32 + lg * 8 + j;
      s1r[ks][j] = stat_ro[ST_SC_BN1 + ch];
      h1r[ks][j] = stat_ro[ST_SH_BN1 + ch];
    }

  bf16x8 B[2][4];
#pragma unroll
  for (int ks = 0; ks < 2; ks++)
#pragma unroll
    for (int nf = 0; nf < 4; nf++){
      int s = s0 + nf * 16 + lr;
      const float* hp = hfka + ((size_t)(b << 11) + s) * 64 + ks * 32 + lg * 8;
      float4 v0 = *(const float4*)hp;
      float4 v1 = *(const float4*)(hp + 4);
      float vv[8] = {v0.x, v0.y, v0.z, v0.w, v1.x, v1.y, v1.z, v1.w};
      union { bf16x8 f; __hip_bfloat16 e[8]; } pk;
#pragma unroll
      for (int j = 0; j < 8; j++)
        pk.e[j] = __float2bfloat16(fmaxf(vv[j] * s1r[ks][j] + h1r[ks][j], 0.0f));
      B[ks][nf] = pk.f;
    }

  f32x4 acc[4][4];
#pragma unroll
  for (int i = 0; i < 4; i++)
#pragma unroll
    for (int j = 0; j < 4; j++) acc[i][j] = (f32x4){0.f, 0.f, 0.f, 0.f};

  const __hip_bfloat16* arow = cv2b + (size_t)(wv * 64 + lr) * 64 + lg * 8;
#pragma unroll
  for (int ks = 0; ks < 2; ks++){
    bf16x8 A[4];
#pragma unroll
    for (int mf = 0; mf < 4; mf++) A[mf] = *(const bf16x8*)(arow + mf * 1024 + ks * 32);
#pragma unroll
    for (int mf = 0; mf < 4; mf++)
#pragma unroll
      for (int nf = 0; nf < 4; nf++)
        acc[mf][nf] = __builtin_amdgcn_mfma_f32_16x16x32_bf16(A[mf], B[ks][nf], acc[mf][nf], 0, 0, 0);
  }

#pragma unroll
  for (int mf = 0; mf < 4; mf++){
    const int m0 = wv * 64 + mf * 16 + lg * 4;
    float bv[4];
#pragma unroll
    for (int r = 0; r < 4; r++) bv[r] = bias[m0 + r];
#pragma unroll
    for (int nf = 0; nf < 4; nf++){
      int s = s0 + nf * 16 + lr;
      union { uint2 u; __hip_bfloat16 e[4]; } pk;
#pragma unroll
      for (int r = 0; r < 4; r++){
        acc[mf][nf][r] += bv[r];
        pk.e[r] = __float2bfloat16(acc[mf][nf][r]);
      }
      *(uint2*)&h2[((size_t)(b << 11) + s) * 256 + m0] = pk.u;
    }
#pragma unroll
    for (int r = 0; r < 4; r++){
      float ss = 0.f, qq = 0.f;
#pragma unroll
      for (int nf = 0; nf < 4; nf++){ float v = acc[mf][nf][r]; ss += v; qq += v * v; }
#pragma unroll
      for (int off = 8; off >= 1; off >>= 1){
        ss += __shfl_xor(ss, off, 16);
        qq += __shfl_xor(qq, off, 16);
      }
      if (lr == 0){
        p7row[m0 + r]       = ss;
        p7row[256 + m0 + r] = qq;
      }
    }
  }
}

// =================================================================
// K8: final
// =================================================================
__global__ __launch_bounds__(256) void k_final(
    const __hip_bfloat16* __restrict__ sct, const __hip_bfloat16* __restrict__ h2,
    const int* __restrict__ nbr, const float* __restrict__ stat, float* __restrict__ out)
{
  __shared__ int   idx_s[256];
  __shared__ float tile_s[16][257];
  const int tid = threadIdx.x;
  const int b  = blockIdx.x >> 7;
  const int st = blockIdx.x & 127;
  const int s0 = st << 4;
  idx_s[tid] = nbr[((size_t)(b << 11) + s0) * 16 + tid];
  const int sl = tid >> 4, cg = tid & 15, ch0 = cg << 4;

  float ssc[16], hsc[16], s2v[16], h2v[16];
#pragma unroll
  for (int j = 0; j < 16; j++){
    ssc[j] = stat[ST_SC_SC  + ch0 + j];
    hsc[j] = stat[ST_SH_SC  + ch0 + j];
    s2v[j] = stat[ST_SC_BN2 + ch0 + j];
    h2v[j] = stat[ST_SH_BN2 + ch0 + j];
  }
  __syncthreads();

  float mx[16];
#pragma unroll
  for (int j = 0; j < 16; j++) mx[j] = -3.4e38f;
  for (int k = 0; k < 16; k++){
    int nn = idx_s[sl * 16 + k];
    const uint4* p = (const uint4*)&sct[((size_t)(b << 13) + nn) * 256 + ch0];
    union { uint4 u; __hip_bfloat16 e[8]; } a0, a1;
    a0.u = p[0]; a1.u = p[1];
#pragma unroll
    for (int j = 0; j < 8; j++){
      mx[j]     = fmaxf(mx[j],     __bfloat162float(a0.e[j]) * ssc[j]     + hsc[j]);
      mx[j + 8] = fmaxf(mx[j + 8], __bfloat162float(a1.e[j]) * ssc[j + 8] + hsc[j + 8]);
    }
  }
  {
    const uint4* p = (const uint4*)&h2[((size_t)(b << 11) + s0 + sl) * 256 + ch0];
    union { uint4 u; __hip_bfloat16 e[8]; } a0, a1;
    a0.u = p[0]; a1.u = p[1];
#pragma unroll
    for (int j = 0; j < 8; j++){
      tile_s[sl][ch0 + j]     = fmaxf(__bfloat162float(a0.e[j]) * s2v[j]     + h2v[j]     + mx[j], 0.0f);
      tile_s[sl][ch0 + 8 + j] = fmaxf(__bfloat162float(a1.e[j]) * s2v[j + 8] + h2v[j + 8] + mx[j + 8], 0.0f);
    }
  }
  __syncthreads();
  const int o = tid;
#pragma unroll
  for (int p4 = 0; p4 < 4; p4++){
    float4 v = make_float4(tile_s[p4 * 4 + 0][o], tile_s[p4 * 4 + 1][o],
                           tile_s[p4 * 4 + 2][o], tile_s[p4 * 4 + 3][o]);
    *(float4*)&out[((size_t)(b << 8) + o) * 2048 + s0 + p4 * 4] = v;
  }
}

// =================================================================
extern "C" void kernel_launch(void* const* d_in, const int* in_sizes, int n_in,
                              void* d_out, int out_size, void* d_ws, size_t ws_size,
                              hipStream_t stream)
{
  (void)in_sizes; (void)n_in; (void)out_size; (void)ws_size;
  const float* x     = (const float*)d_in[0];
  const float* pos   = (const float*)d_in[1];
  const float* sup   = (const float*)d_in[2];
  const int*   nbr   = (const int*)d_in[3];
  const float* cv0w  = (const float*)d_in[5];
  const float* cv0b  = (const float*)d_in[6];
  const float* bn0g  = (const float*)d_in[7];
  const float* bn0b  = (const float*)d_in[8];
  const float* fc1   = (const float*)d_in[9];
  const float* fc2   = (const float*)d_in[10];
  const float* fc3   = (const float*)d_in[11];
  const float* in1g  = (const float*)d_in[12];
  const float* in1b  = (const float*)d_in[13];
  const float* in2g  = (const float*)d_in[14];
  const float* in2b  = (const float*)d_in[15];
  const float* alp   = (const float*)d_in[16];
  const float* bet   = (const float*)d_in[17];
  const float* nrp   = (const float*)d_in[18];
  const float* cvw   = (const float*)d_in[19];
  const float* bn1g  = (const float*)d_in[20];
  const float* bn1b  = (const float*)d_in[21];
  const float* cv2w  = (const float*)d_in[22];
  const float* cv2bi = (const float*)d_in[23];
  const float* bn2g  = (const float*)d_in[24];
  const float* bn2b  = (const float*)d_in[25];
  const float* scw   = (const float*)d_in[26];
  const float* scb   = (const float*)d_in[27];
  const float* bnscg = (const float*)d_in[28];
  const float* bnscb = (const float*)d_in[29];

  char* w = (char*)d_ws;
  __hip_bfloat16* sct  = (__hip_bfloat16*)(w);                  //  0       (64 MB)
  __hip_bfloat16* y0t  = (__hip_bfloat16*)(w + 67108864);       //  16 MB
  float*          pin1 = (float*)(w + 83886080);                //   1 MB (in1..red)
  float*          pin2 = (float*)(w + 84934656);                //   1 MB (in2..red)
  float*          p7   = (float*)(w + 85983232);                //   1 MB (k7..red)
  float*          hfka = (float*)(w + 150994944);               //   8 MB (fka..k7)
  float*          p1   = (float*)(w + 160432128);               // 5.2 MB (k1..red)
  __hip_bfloat16* h2   = (__hip_bfloat16*)(w + 100663296);      //  16 MB (k7..final)
  float*          p6   = (float*)(w + 125829120);               //   1 MB (fka..red)
  __hip_bfloat16* wb   = (__hip_bfloat16*)(w + 176160768);
  __hip_bfloat16* cvb  = (__hip_bfloat16*)(w + 176242688);
  __hip_bfloat16* cv2b = (__hip_bfloat16*)(w + 176373760);
  float*          stat = (float*)(w + 192937984UL);

  k_prep_w<<<480, 256, 0, stream>>>(cv0w, scw, cvw, cv2w, wb, cvb, cv2b);
  k1_mfma<<<2048, 256, 0, stream>>>(x, wb, cv0b, scb, y0t, sct, p1);
  k_redP1<<<20, 256, 0, stream>>>(p1, 2048, bn0g, bn0b, bnscg, bnscb,
                                  1.0f / 131072.0f, stat);
  k_in1_stats<<<2048, 256, 0, stream>>>(pos, sup, nbr, fc1, nrp, pin1);
  k_redB<<<16, 256, 0, stream>>>(pin1, 512, in1g, in1b, 1.0f / 32768.0f,
                                 stat + ST_SC_IN1, stat + ST_SH_IN1);
  k_in2_stats<<<2048, 256, 0, stream>>>(pos, sup, nbr, fc1, fc2, alp, bet, nrp, stat, pin2);
  k_redB<<<16, 256, 0, stream>>>(pin2, 512, in2g, in2b, 1.0f / 32768.0f,
                                 stat + ST_SC_IN2, stat + ST_SH_IN2);
  k_fka<<<2048, 256, 0, stream>>>(pos, sup, nbr, fc1, fc2, fc3, alp, bet, nrp, y0t, stat,
                                  cvb, hfka, p6);
  k_redA<<<4, 256, 0, stream>>>(p6, 2048, 128, 0, 64, bn1g, bn1b,
                                1.0f / 32768.0f, 64, stat + ST_SC_BN1, stat + ST_SH_BN1);
  k7_mfma<<<512, 256, 0, stream>>>(hfka, cv2b, cv2bi, stat, h2, p7);
  k_redA<<<16, 256, 0, stream>>>(p7, 512, 512, 0, 256, bn2g, bn2b,
                                 1.0f / 32768.0f, 256, stat + ST_SC_BN2, stat + ST_SH_BN2);
  k_final<<<2048, 256, 0, stream>>>(sct, h2, nbr, stat, (float*)d_out);
}

// Round 11
// 449.276 us; speedup vs baseline: 3.3235x; 1.0674x over previous
//
#include <hip/hip_runtime.h>
#include <hip/hip_bf16.h>

#define DEV static __device__ __forceinline__

typedef __attribute__((ext_vector_type(8))) short bf16x8;
typedef __attribute__((ext_vector_type(4))) float f32x4;

// ---------------- stat layout (floats, inside ws) ----------------
#define ST_SC_BN0  0
#define ST_SH_BN0  64
#define ST_SC_SC   128
#define ST_SH_SC   384
#define ST_SC_IN1  640
#define ST_SH_IN1  896
#define ST_SC_IN2  1152
#define ST_SH_IN2  1408
#define ST_SC_BN1  1664
#define ST_SH_BN1  1728
#define ST_SC_BN2  1792
#define ST_SH_BN2  2048

DEV float rsum16(float v){
#pragma unroll
  for (int off = 8; off >= 1; off >>= 1) v += __shfl_xor(v, off, 16);
  return v;
}
DEV float rmax16(float v){
#pragma unroll
  for (int off = 8; off >= 1; off >>= 1) v = fmaxf(v, __shfl_xor(v, off, 16));
  return v;
}

// =================================================================
// P0: weight conversion f32 -> bf16. cvb is K-PERMUTED: dst k' = q*64+c
// for src k = c*16+q, so fka's Phase B can write agg q-major coalesced.
// =================================================================
__global__ __launch_bounds__(256) void k_prep_w(
    const float* __restrict__ cv0w, const float* __restrict__ scw,
    const float* __restrict__ cvw,  const float* __restrict__ cv2w,
    __hip_bfloat16* __restrict__ wb, __hip_bfloat16* __restrict__ cvb,
    __hip_bfloat16* __restrict__ cv2b)
{
  int i = blockIdx.x * 256 + threadIdx.x;   // 0 .. 122879
  if (i < 40960){
    float v = (i < 8192) ? cv0w[i] : scw[i - 8192];
    wb[i] = __float2bfloat16(v);
  } else if (i < 106496){
    int j = i - 40960;                  // [64][1024] flat, k = c*16+q
    int o = j >> 10, kk = j & 1023;
    int c = kk >> 4, q = kk & 15;
    cvb[(o << 10) + (q << 6) + c] = __float2bfloat16(cvw[j]);
  } else {
    cv2b[i - 106496] = __float2bfloat16(cv2w[i - 106496]);
  }
}

// =================================================================
// K1: fused transpose + MFMA cv0+shortcut GEMM.
// =================================================================
__global__ __launch_bounds__(256) void k1_mfma(
    const float* __restrict__ x, const __hip_bfloat16* __restrict__ wb,
    const float* __restrict__ cv0b, const float* __restrict__ scb,
    __hip_bfloat16* __restrict__ y0t, __hip_bfloat16* __restrict__ sct,
    float* __restrict__ p1)
{
  __shared__ __hip_bfloat16 xt[64][136];   // row stride 272B -> conflict-free b128
  const int tid = threadIdx.x;
  const int b = blockIdx.x >> 7, nt = blockIdx.x & 127;
  const int n0 = nt << 6;
  const int wv = tid >> 6, l = tid & 63;
  const int lr = l & 15, lg = l >> 4;
  float* p1row = p1 + (size_t)blockIdx.x * 640;

#pragma unroll
  for (int p = 0; p < 8; p++){
    int c  = (p << 4) + (tid >> 4);
    int n4 = (tid & 15) << 2;
    float4 v = *(const float4*)&x[(((size_t)b * 128 + c) << 13) + n0 + n4];
    xt[n4 + 0][c] = __float2bfloat16(v.x);
    xt[n4 + 1][c] = __float2bfloat16(v.y);
    xt[n4 + 2][c] = __float2bfloat16(v.z);
    xt[n4 + 3][c] = __float2bfloat16(v.w);
  }
  __syncthreads();

  f32x4 acc[5][4];
#pragma unroll
  for (int i = 0; i < 5; i++)
#pragma unroll
    for (int j = 0; j < 4; j++) acc[i][j] = (f32x4){0.f, 0.f, 0.f, 0.f};

  const __hip_bfloat16* wrow = wb + (size_t)(wv * 80 + lr) * 128 + lg * 8;

#pragma unroll
  for (int ks = 0; ks < 4; ks++){
    bf16x8 B[4], A[5];
#pragma unroll
    for (int nf = 0; nf < 4; nf++)
      B[nf] = *(const bf16x8*)&xt[nf * 16 + lr][ks * 32 + lg * 8];
#pragma unroll
    for (int mf = 0; mf < 5; mf++) A[mf] = *(const bf16x8*)(wrow + mf * 2048 + ks * 32);
#pragma unroll
    for (int mf = 0; mf < 5; mf++)
#pragma unroll
      for (int nf = 0; nf < 4; nf++)
        acc[mf][nf] = __builtin_amdgcn_mfma_f32_16x16x32_bf16(A[mf], B[nf], acc[mf][nf], 0, 0, 0);
  }

#pragma unroll
  for (int mf = 0; mf < 5; mf++){
    const int m0 = wv * 80 + mf * 16 + lg * 4;
    float bv[4];
#pragma unroll
    for (int r = 0; r < 4; r++){
      int m = m0 + r;
      bv[r] = (m < 64) ? cv0b[m] : scb[m - 64];
    }
#pragma unroll
    for (int nf = 0; nf < 4; nf++)
#pragma unroll
      for (int r = 0; r < 4; r++) acc[mf][nf][r] += bv[r];

#pragma unroll
    for (int nf = 0; nf < 4; nf++){
      int n = n0 + nf * 16 + lr;
      union { uint2 u; __hip_bfloat16 e[4]; } pk;
#pragma unroll
      for (int r = 0; r < 4; r++) pk.e[r] = __float2bfloat16(acc[mf][nf][r]);
      if (m0 < 64)
        *(uint2*)&y0t[((size_t)(b << 13) + n) * 64 + m0] = pk.u;
      else
        *(uint2*)&sct[((size_t)(b << 13) + n) * 256 + (m0 - 64)] = pk.u;
    }
#pragma unroll
    for (int r = 0; r < 4; r++){
      float ss = 0.f, qq = 0.f;
#pragma unroll
      for (int nf = 0; nf < 4; nf++){ float v = acc[mf][nf][r]; ss += v; qq += v * v; }
#pragma unroll
      for (int off = 8; off >= 1; off >>= 1){
        ss += __shfl_xor(ss, off, 16);
        qq += __shfl_xor(qq, off, 16);
      }
      if (lr == 0){
        int ch = m0 + r;
        p1row[ch]       = ss;
        p1row[320 + ch] = qq;
      }
    }
  }
}

// =================================================================
// Fast reducers
// =================================================================
__global__ __launch_bounds__(256) void k_redP1(
    const float* __restrict__ part, int nrows,
    const float* __restrict__ g0, const float* __restrict__ b0,
    const float* __restrict__ gs, const float* __restrict__ bs,
    float inv_cnt, float* __restrict__ stat)
{
  __shared__ f32x4 sh_s[256], sh_q[256];
  const int tid = threadIdx.x;
  const int ch0 = blockIdx.x << 4;
  const int c4 = (tid & 3) << 2;
  const int stripe = tid >> 2;
  f32x4 s = {0.f,0.f,0.f,0.f}, q = {0.f,0.f,0.f,0.f};
  for (int r = stripe; r < nrows; r += 64){
    const float* row = part + (size_t)r * 640;
    s += *(const f32x4*)&row[ch0 + c4];
    q += *(const f32x4*)&row[320 + ch0 + c4];
  }
  sh_s[tid] = s; sh_q[tid] = q;
  __syncthreads();
  for (int off = 128; off >= 4; off >>= 1){
    if (tid < off){ sh_s[tid] += sh_s[tid + off]; sh_q[tid] += sh_q[tid + off]; }
    __syncthreads();
  }
  if (tid < 4){
    f32x4 S = sh_s[tid], Q = sh_q[tid];
#pragma unroll
    for (int j = 0; j < 4; j++){
      int ch = ch0 + (tid << 2) + j;
      float m  = S[j] * inv_cnt;
      float v  = Q[j] * inv_cnt - m * m;
      if (ch < 64){
        float sc = g0[ch] * rsqrtf(v + 1e-5f);
        stat[ST_SC_BN0 + ch] = sc;
        stat[ST_SH_BN0 + ch] = b0[ch] - m * sc;
      } else {
        int c = ch - 64;
        float sc = gs[c] * rsqrtf(v + 1e-5f);
        stat[ST_SC_SC + c] = sc;
        stat[ST_SH_SC + c] = bs[c] - m * sc;
      }
    }
  }
}

__global__ __launch_bounds__(256) void k_redA(
    const float* __restrict__ part, int nrows, int rowstride,
    int sum_off, int sq_off,
    const float* __restrict__ g, const float* __restrict__ bb,
    float inv_cnt, int gmod,
    float* __restrict__ scale, float* __restrict__ shift)
{
  __shared__ f32x4 sh_s[256], sh_q[256];
  const int tid = threadIdx.x;
  const int ch0 = blockIdx.x << 4;
  const int c4 = (tid & 3) << 2;
  const int stripe = tid >> 2;
  f32x4 s = {0.f,0.f,0.f,0.f}, q = {0.f,0.f,0.f,0.f};
  for (int r = stripe; r < nrows; r += 64){
    const float* row = part + (size_t)r * rowstride;
    s += *(const f32x4*)&row[sum_off + ch0 + c4];
    q += *(const f32x4*)&row[sq_off + ch0 + c4];
  }
  sh_s[tid] = s; sh_q[tid] = q;
  __syncthreads();
  for (int off = 128; off >= 4; off >>= 1){
    if (tid < off){ sh_s[tid] += sh_s[tid + off]; sh_q[tid] += sh_q[tid + off]; }
    __syncthreads();
  }
  if (tid < 4){
    f32x4 S = sh_s[tid], Q = sh_q[tid];
#pragma unroll
    for (int j = 0; j < 4; j++){
      int ch = ch0 + (tid << 2) + j;
      float m  = S[j] * inv_cnt;
      float v  = Q[j] * inv_cnt - m * m;
      float sc = g[ch % gmod] * rsqrtf(v + 1e-5f);
      scale[ch] = sc;
      shift[ch] = bb[ch % gmod] - m * sc;
    }
  }
}

__global__ __launch_bounds__(256) void k_redB(
    const float* __restrict__ part, int rows_per_b,
    const float* __restrict__ g, const float* __restrict__ bb, float inv_cnt,
    float* __restrict__ scale, float* __restrict__ shift)
{
  __shared__ f32x4 sh_s[256], sh_q[256];
  const int tid = threadIdx.x;
  const int b = blockIdx.x;
  const int c4 = (tid & 3) << 2;
  const int stripe = tid >> 2;
  const float* base = part + (size_t)b * rows_per_b * 32;
  f32x4 s = {0.f,0.f,0.f,0.f}, q = {0.f,0.f,0.f,0.f};
  for (int r = stripe; r < rows_per_b; r += 64){
    s += *(const f32x4*)&base[r * 32 + c4];
    q += *(const f32x4*)&base[r * 32 + 16 + c4];
  }
  sh_s[tid] = s; sh_q[tid] = q;
  __syncthreads();
  for (int off = 128; off >= 4; off >>= 1){
    if (tid < off){ sh_s[tid] += sh_s[tid + off]; sh_q[tid] += sh_q[tid + off]; }
    __syncthreads();
  }
  if (tid < 4){
    f32x4 S = sh_s[tid], Q = sh_q[tid];
#pragma unroll
    for (int j = 0; j < 4; j++){
      int c = (tid << 2) + j;
      float m  = S[j] * inv_cnt;
      float v  = Q[j] * inv_cnt - m * m;
      float sc = g[c] * rsqrtf(v + 1e-5f);
      scale[b * 16 + c] = sc;
      shift[b * 16 + c] = bb[c] - m * sc;
    }
  }
}

// =================================================================
// K3: IN1 stats -> pin1[blk*4+wv][32]
// =================================================================
__global__ __launch_bounds__(256) void k_in1_stats(
    const float* __restrict__ pos, const float* __restrict__ sup, const int* __restrict__ nbr,
    const float* __restrict__ fc1, const float* __restrict__ nrp, float* __restrict__ pin1)
{
  const int tid = threadIdx.x;
  const int b  = blockIdx.x >> 7;
  const int st = blockIdx.x & 127;
  const int sl = tid >> 4, k = tid & 15;
  const int s  = (st << 4) + sl;
  const int n  = nbr[((((size_t)b << 11) + s) << 4) + k];
  float* pr = pin1 + ((size_t)blockIdx.x * 4 + (tid >> 6)) * 32;
  const float inr = 1.0f / nrp[0];
  float p0 = (pos[((size_t)b * 3 + 0) * 8192 + n] - sup[((size_t)b * 3 + 0) * 2048 + s]) * inr;
  float p1 = (pos[((size_t)b * 3 + 1) * 8192 + n] - sup[((size_t)b * 3 + 1) * 2048 + s]) * inr;
  float p2 = (pos[((size_t)b * 3 + 2) * 8192 + n] - sup[((size_t)b * 3 + 2) * 2048 + s]) * inr;
#pragma unroll
  for (int q = 0; q < 16; q++){
    float z = fc1[q * 3] * p0 + fc1[q * 3 + 1] * p1 + fc1[q * 3 + 2] * p2;
    float a = z, c = z * z;
#pragma unroll
    for (int off = 32; off >= 1; off >>= 1){
      a += __shfl_xor(a, off, 64);
      c += __shfl_xor(c, off, 64);
    }
    if ((tid & 63) == q){
      pr[q]      = a;
      pr[16 + q] = c;
    }
  }
}

// =================================================================
// K4: IN2 stats -> pin2[blk*4+wv][32]
// =================================================================
__global__ __launch_bounds__(256) void k_in2_stats(
    const float* __restrict__ pos, const float* __restrict__ sup, const int* __restrict__ nbr,
    const float* __restrict__ fc1, const float* __restrict__ fc2,
    const float* __restrict__ alp, const float* __restrict__ bet, const float* __restrict__ nrp,
    const float* __restrict__ stat, float* __restrict__ pin2)
{
  __shared__ float fc2s[512];
  __shared__ float sc1s[16], sh1s[16];
  const int tid = threadIdx.x;
  const int b  = blockIdx.x >> 7;
  const int st = blockIdx.x & 127;
  fc2s[tid]       = fc2[tid];
  fc2s[tid + 256] = fc2[tid + 256];
  if (tid < 16){
    sc1s[tid] = stat[ST_SC_IN1 + (b << 4) + tid];
    sh1s[tid] = stat[ST_SH_IN1 + (b << 4) + tid];
  }
  __syncthreads();
  const int sl = tid >> 4, k = tid & 15;
  const int s  = (st << 4) + sl;
  const int n  = nbr[((((size_t)b << 11) + s) << 4) + k];
  float* pr = pin2 + ((size_t)blockIdx.x * 4 + (tid >> 6)) * 32;
  float t0 = pos[((size_t)b * 3 + 0) * 8192 + n] - sup[((size_t)b * 3 + 0) * 2048 + s];
  float t1 = pos[((size_t)b * 3 + 1) * 8192 + n] - sup[((size_t)b * 3 + 1) * 2048 + s];
  float t2 = pos[((size_t)b * 3 + 2) * 8192 + n] - sup[((size_t)b * 3 + 2) * 2048 + s];
  float dist = sqrtf(t0 * t0 + t1 * t1 + t2 * t2);
  float dw = 1.0f / (1.0f + expf(alp[0] * dist - bet[0]));
  float ssum = rsum16(dw);
  ssum += (ssum == 0.0f ? 1.0f : 0.0f) + 1e-6f;
  dw = dw / ssum * 16.0f;
  const float inr = 1.0f / nrp[0];
  float p0 = t0 * inr, p1 = t1 * inr, p2 = t2 * inr;
  float m1[16], mp1[16];
#pragma unroll
  for (int q = 0; q < 16; q++){
    float z = fc1[q * 3] * p0 + fc1[q * 3 + 1] * p1 + fc1[q * 3 + 2] * p2;
    m1[q] = fmaxf(z * sc1s[q] + sh1s[q], 0.0f);
  }
#pragma unroll
  for (int q = 0; q < 16; q++) mp1[q] = rmax16(m1[q] * dw);
#pragma unroll
  for (int q = 0; q < 16; q++){
    float z = 0.0f;
#pragma unroll
    for (int j = 0; j < 16; j++) z = fmaf(fc2s[q * 32 + j], m1[j], z);
#pragma unroll
    for (int j = 0; j < 16; j++) z = fmaf(fc2s[q * 32 + 16 + j], mp1[j], z);
    float a = z, c = z * z;
#pragma unroll
    for (int off = 32; off >= 1; off >>= 1){
      a += __shfl_xor(a, off, 64);
      c += __shfl_xor(c, off, 64);
    }
    if ((tid & 63) == q){
      pr[q]      = a;
      pr[16 + q] = c;
    }
  }
}

// =================================================================
// K5: FKA main, barrier-free Phase B.
// Phase A: geometry chain -> mat3_s[16][17][20] (q-rows 80B aligned).
// Phase B: thread (sB, tB) owns s-row sB, 4 channels c4=tB*4.
//   Gathers its own 16 k feats directly from y0t (L2-resident),
//   computes agg[q][c4..c4+3], writes agg GLOBAL q-major coalesced.
//   No LDS staging, no barriers.
// agg layout: [b][s][k'=q*64+c] bf16 (cvb is pre-permuted to match).
// =================================================================
__global__ __launch_bounds__(256) void k_fka(
    const float* __restrict__ pos, const float* __restrict__ sup, const int* __restrict__ nbr,
    const float* __restrict__ fc1, const float* __restrict__ fc2, const float* __restrict__ fc3,
    const float* __restrict__ alp, const float* __restrict__ bet, const float* __restrict__ nrp,
    const __hip_bfloat16* __restrict__ y0t, const float* __restrict__ stat,
    __hip_bfloat16* __restrict__ agg)
{
  __shared__ float fc2s[512], fc3s[512];
  __shared__ float sc1s[16], sh1s[16], sc2s[16], sh2s[16];
  __shared__ float sc0s[64], sh0s[64];
  __shared__ float mat3_s[16][17][20];   // [sl][q][k], q-stride 80B (b128-aligned)
  __shared__ int   idx_s[16][16];

  const int tid = threadIdx.x;
  const int b  = blockIdx.x >> 7;
  const int st = blockIdx.x & 127;
  fc2s[tid]       = fc2[tid];
  fc2s[tid + 256] = fc2[tid + 256];
  fc3s[tid]       = fc3[tid];
  fc3s[tid + 256] = fc3[tid + 256];
  if (tid < 16){
    sc1s[tid] = stat[ST_SC_IN1 + (b << 4) + tid];
    sh1s[tid] = stat[ST_SH_IN1 + (b << 4) + tid];
    sc2s[tid] = stat[ST_SC_IN2 + (b << 4) + tid];
    sh2s[tid] = stat[ST_SH_IN2 + (b << 4) + tid];
  }
  if (tid < 64){
    sc0s[tid] = stat[ST_SC_BN0 + tid];
    sh0s[tid] = stat[ST_SH_BN0 + tid];
  }
  const int sl = tid >> 4, k = tid & 15;
  const int s  = (st << 4) + sl;
  const int n  = nbr[((((size_t)b << 11) + s) << 4) + k];
  idx_s[sl][k] = n;
  __syncthreads();

  // ---- Phase A ----
  float t0 = pos[((size_t)b * 3 + 0) * 8192 + n] - sup[((size_t)b * 3 + 0) * 2048 + s];
  float t1 = pos[((size_t)b * 3 + 1) * 8192 + n] - sup[((size_t)b * 3 + 1) * 2048 + s];
  float t2 = pos[((size_t)b * 3 + 2) * 8192 + n] - sup[((size_t)b * 3 + 2) * 2048 + s];
  float dist = sqrtf(t0 * t0 + t1 * t1 + t2 * t2);
  float dw = 1.0f / (1.0f + expf(alp[0] * dist - bet[0]));
  float ssum = rsum16(dw);
  ssum += (ssum == 0.0f ? 1.0f : 0.0f) + 1e-6f;
  dw = dw / ssum * 16.0f;
  const float inr = 1.0f / nrp[0];
  float p0 = t0 * inr, p1 = t1 * inr, p2 = t2 * inr;
  float m1[16], mp1[16];
#pragma unroll
  for (int q = 0; q < 16; q++){
    float z = fc1[q * 3] * p0 + fc1[q * 3 + 1] * p1 + fc1[q * 3 + 2] * p2;
    m1[q] = fmaxf(z * sc1s[q] + sh1s[q], 0.0f);
  }
#pragma unroll
  for (int q = 0; q < 16; q++) mp1[q] = rmax16(m1[q] * dw);
  float m2[16], mp2[16];
#pragma unroll
  for (int q = 0; q < 16; q++){
    float z = 0.0f;
#pragma unroll
    for (int j = 0; j < 16; j++) z = fmaf(fc2s[q * 32 + j], m1[j], z);
#pragma unroll
    for (int j = 0; j < 16; j++) z = fmaf(fc2s[q * 32 + 16 + j], mp1[j], z);
    m2[q] = fmaxf(z * sc2s[q] + sh2s[q], 0.0f);
  }
#pragma unroll
  for (int q = 0; q < 16; q++) mp2[q] = rmax16(m2[q] * dw);
#pragma unroll
  for (int q = 0; q < 16; q++){
    float z = 0.0f;
#pragma unroll
    for (int j = 0; j < 16; j++) z = fmaf(fc3s[q * 32 + j], m2[j], z);
#pragma unroll
    for (int j = 0; j < 16; j++) z = fmaf(fc3s[q * 32 + 16 + j], mp2[j], z);
    mat3_s[sl][q][k] = fmaxf(z, 0.0f) * dw;
  }
  __syncthreads();

  // ---- Phase B: barrier-free ----
  const int sB = tid >> 4;          // s-row 0..15
  const int c4 = (tid & 15) << 2;   // 4 channels
  const float s0a = sc0s[c4],     s0b = sc0s[c4 + 1],
              s0c = sc0s[c4 + 2], s0d = sc0s[c4 + 3];
  const float h0a = sh0s[c4],     h0b = sh0s[c4 + 1],
              h0c = sh0s[c4 + 2], h0d = sh0s[c4 + 3];

  float f0[16], f1[16], f2[16], f3[16];
#pragma unroll
  for (int kk = 0; kk < 16; kk++){
    int nn = idx_s[sB][kk];
    union { uint2 u; __hip_bfloat16 e[4]; } ld;
    ld.u = *(const uint2*)&y0t[((size_t)(b << 13) + nn) * 64 + c4];
    f0[kk] = fmaxf(__bfloat162float(ld.e[0]) * s0a + h0a, 0.0f);
    f1[kk] = fmaxf(__bfloat162float(ld.e[1]) * s0b + h0b, 0.0f);
    f2[kk] = fmaxf(__bfloat162float(ld.e[2]) * s0c + h0c, 0.0f);
    f3[kk] = fmaxf(__bfloat162float(ld.e[3]) * s0d + h0d, 0.0f);
  }

  __hip_bfloat16* arow = agg + ((size_t)(b << 11) + (st << 4) + sB) * 1024 + c4;
#pragma unroll
  for (int q = 0; q < 16; q++){
    float a0 = 0.f, a1 = 0.f, a2 = 0.f, a3 = 0.f;
#pragma unroll
    for (int kk = 0; kk < 16; kk++){
      float mv = mat3_s[sB][q][kk];
      a0 = fmaf(f0[kk], mv, a0);
      a1 = fmaf(f1[kk], mv, a1);
      a2 = fmaf(f2[kk], mv, a2);
      a3 = fmaf(f3[kk], mv, a3);
    }
    union { uint2 u; __hip_bfloat16 e[4]; } pk;
    pk.e[0] = __float2bfloat16(a0);
    pk.e[1] = __float2bfloat16(a1);
    pk.e[2] = __float2bfloat16(a2);
    pk.e[3] = __float2bfloat16(a3);
    *(uint2*)(arow + (q << 6)) = pk.u;
  }
}

// =================================================================
// K6: MFMA cv GEMM (standalone, R4-measured form).
// hfka[b][s][o] = cvb_perm(64x1024) @ agg[b][s][:]. p6 partials.
// =================================================================
__global__ __launch_bounds__(256) void k6_mfma(
    const __hip_bfloat16* __restrict__ agg, const __hip_bfloat16* __restrict__ cvb,
    float* __restrict__ hfka, float* __restrict__ p6)
{
  const int tid = threadIdx.x;
  const int b = blockIdx.x >> 5, stile = blockIdx.x & 31;
  const int wv = tid >> 6, l = tid & 63;
  const int lr = l & 15, lg = l >> 4;
  const int sw = (stile << 6) + (wv << 4);
  float* p6row = p6 + ((size_t)blockIdx.x * 4 + wv) * 128;

  f32x4 acc[4];
#pragma unroll
  for (int i = 0; i < 4; i++) acc[i] = (f32x4){0.f, 0.f, 0.f, 0.f};

  const __hip_bfloat16* brow = agg + ((size_t)(b << 11) + sw + lr) * 1024 + lg * 8;
  const __hip_bfloat16* arow = cvb + (size_t)lr * 1024 + lg * 8;

#pragma unroll 4
  for (int ks = 0; ks < 32; ks++){
    bf16x8 B = *(const bf16x8*)(brow + ks * 32);
    bf16x8 A[4];
#pragma unroll
    for (int mf = 0; mf < 4; mf++) A[mf] = *(const bf16x8*)(arow + mf * 16384 + ks * 32);
#pragma unroll
    for (int mf = 0; mf < 4; mf++)
      acc[mf] = __builtin_amdgcn_mfma_f32_16x16x32_bf16(A[mf], B, acc[mf], 0, 0, 0);
  }

  const int s = sw + lr;
#pragma unroll
  for (int mf = 0; mf < 4; mf++){
    const int m0 = mf * 16 + lg * 4;
    float4 v = make_float4(acc[mf][0], acc[mf][1], acc[mf][2], acc[mf][3]);
    *(float4*)&hfka[((size_t)(b << 11) + s) * 64 + m0] = v;
#pragma unroll
    for (int r = 0; r < 4; r++){
      float ss = acc[mf][r], qq = ss * ss;
#pragma unroll
      for (int off = 8; off >= 1; off >>= 1){
        ss += __shfl_xor(ss, off, 16);
        qq += __shfl_xor(qq, off, 16);
      }
      if (lr == 0){
        p6row[m0 + r]      = ss;
        p6row[64 + m0 + r] = qq;
      }
    }
  }
}

// =================================================================
// K7: MFMA cv2. Partials: p7[blk][512]
// =================================================================
__global__ __launch_bounds__(256) void k7_mfma(
    const float* __restrict__ hfka, const __hip_bfloat16* __restrict__ cv2b,
    const float* __restrict__ bias, const float* __restrict__ stat_ro,
    __hip_bfloat16* __restrict__ h2, float* __restrict__ p7)
{
  const int tid = threadIdx.x;
  const int b = blockIdx.x >> 5, stile = blockIdx.x & 31;
  const int s0 = stile << 6;
  const int wv = tid >> 6, l = tid & 63;
  const int lr = l & 15, lg = l >> 4;
  float* p7row = p7 + (size_t)blockIdx.x * 512;

  float s1r[2][8], h1r[2][8];
#pragma unroll
  for (int ks = 0; ks < 2; ks++)
#pragma unroll
    for (int j = 0; j < 8; j++){
      int ch = ks * 32 + lg * 8 + j;
      s1r[ks][j] = stat_ro[ST_SC_BN1 + ch];
      h1r[ks][j] = stat_ro[ST_SH_BN1 + ch];
    }

  bf16x8 B[2][4];
#pragma unroll
  for (int ks = 0; ks < 2; ks++)
#pragma unroll
    for (int nf = 0; nf < 4; nf++){
      int s = s0 + nf * 16 + lr;
      const float* hp = hfka + ((size_t)(b << 11) + s) * 64 + ks * 32 + lg * 8;
      float4 v0 = *(const float4*)hp;
      float4 v1 = *(const float4*)(hp + 4);
      float vv[8] = {v0.x, v0.y, v0.z, v0.w, v1.x, v1.y, v1.z, v1.w};
      union { bf16x8 f; __hip_bfloat16 e[8]; } pk;
#pragma unroll
      for (int j = 0; j < 8; j++)
        pk.e[j] = __float2bfloat16(fmaxf(vv[j] * s1r[ks][j] + h1r[ks][j], 0.0f));
      B[ks][nf] = pk.f;
    }

  f32x4 acc[4][4];
#pragma unroll
  for (int i = 0; i < 4; i++)
#pragma unroll
    for (int j = 0; j < 4; j++) acc[i][j] = (f32x4){0.f, 0.f, 0.f, 0.f};

  const __hip_bfloat16* arow = cv2b + (size_t)(wv * 64 + lr) * 64 + lg * 8;
#pragma unroll
  for (int ks = 0; ks < 2; ks++){
    bf16x8 A[4];
#pragma unroll
    for (int mf = 0; mf < 4; mf++) A[mf] = *(const bf16x8*)(arow + mf * 1024 + ks * 32);
#pragma unroll
    for (int mf = 0; mf < 4; mf++)
#pragma unroll
      for (int nf = 0; nf < 4; nf++)
        acc[mf][nf] = __builtin_amdgcn_mfma_f32_16x16x32_bf16(A[mf], B[ks][nf], acc[mf][nf], 0, 0, 0);
  }

#pragma unroll
  for (int mf = 0; mf < 4; mf++){
    const int m0 = wv * 64 + mf * 16 + lg * 4;
    float bv[4];
#pragma unroll
    for (int r = 0; r < 4; r++) bv[r] = bias[m0 + r];
#pragma unroll
    for (int nf = 0; nf < 4; nf++){
      int s = s0 + nf * 16 + lr;
      union { uint2 u; __hip_bfloat16 e[4]; } pk;
#pragma unroll
      for (int r = 0; r < 4; r++){
        acc[mf][nf][r] += bv[r];
        pk.e[r] = __float2bfloat16(acc[mf][nf][r]);
      }
      *(uint2*)&h2[((size_t)(b << 11) + s) * 256 + m0] = pk.u;
    }
#pragma unroll
    for (int r = 0; r < 4; r++){
      float ss = 0.f, qq = 0.f;
#pragma unroll
      for (int nf = 0; nf < 4; nf++){ float v = acc[mf][nf][r]; ss += v; qq += v * v; }
#pragma unroll
      for (int off = 8; off >= 1; off >>= 1){
        ss += __shfl_xor(ss, off, 16);
        qq += __shfl_xor(qq, off, 16);
      }
      if (lr == 0){
        p7row[m0 + r]       = ss;
        p7row[256 + m0 + r] = qq;
      }
    }
  }
}

// =================================================================
// K8: final
// =================================================================
__global__ __launch_bounds__(256) void k_final(
    const __hip_bfloat16* __restrict__ sct, const __hip_bfloat16* __restrict__ h2,
    const int* __restrict__ nbr, const float* __restrict__ stat, float* __restrict__ out)
{
  __shared__ int   idx_s[256];
  __shared__ float tile_s[16][257];
  const int tid = threadIdx.x;
  const int b  = blockIdx.x >> 7;
  const int st = blockIdx.x & 127;
  const int s0 = st << 4;
  idx_s[tid] = nbr[((size_t)(b << 11) + s0) * 16 + tid];
  const int sl = tid >> 4, cg = tid & 15, ch0 = cg << 4;

  float ssc[16], hsc[16], s2v[16], h2v[16];
#pragma unroll
  for (int j = 0; j < 16; j++){
    ssc[j] = stat[ST_SC_SC  + ch0 + j];
    hsc[j] = stat[ST_SH_SC  + ch0 + j];
    s2v[j] = stat[ST_SC_BN2 + ch0 + j];
    h2v[j] = stat[ST_SH_BN2 + ch0 + j];
  }
  __syncthreads();

  float mx[16];
#pragma unroll
  for (int j = 0; j < 16; j++) mx[j] = -3.4e38f;
  for (int k = 0; k < 16; k++){
    int nn = idx_s[sl * 16 + k];
    const uint4* p = (const uint4*)&sct[((size_t)(b << 13) + nn) * 256 + ch0];
    union { uint4 u; __hip_bfloat16 e[8]; } a0, a1;
    a0.u = p[0]; a1.u = p[1];
#pragma unroll
    for (int j = 0; j < 8; j++){
      mx[j]     = fmaxf(mx[j],     __bfloat162float(a0.e[j]) * ssc[j]     + hsc[j]);
      mx[j + 8] = fmaxf(mx[j + 8], __bfloat162float(a1.e[j]) * ssc[j + 8] + hsc[j + 8]);
    }
  }
  {
    const uint4* p = (const uint4*)&h2[((size_t)(b << 11) + s0 + sl) * 256 + ch0];
    union { uint4 u; __hip_bfloat16 e[8]; } a0, a1;
    a0.u = p[0]; a1.u = p[1];
#pragma unroll
    for (int j = 0; j < 8; j++){
      tile_s[sl][ch0 + j]     = fmaxf(__bfloat162float(a0.e[j]) * s2v[j]     + h2v[j]     + mx[j], 0.0f);
      tile_s[sl][ch0 + 8 + j] = fmaxf(__bfloat162float(a1.e[j]) * s2v[j + 8] + h2v[j + 8] + mx[j + 8], 0.0f);
    }
  }
  __syncthreads();
  const int o = tid;
#pragma unroll
  for (int p4 = 0; p4 < 4; p4++){
    float4 v = make_float4(tile_s[p4 * 4 + 0][o], tile_s[p4 * 4 + 1][o],
                           tile_s[p4 * 4 + 2][o], tile_s[p4 * 4 + 3][o]);
    *(float4*)&out[((size_t)(b << 8) + o) * 2048 + s0 + p4 * 4] = v;
  }
}

// =================================================================
extern "C" void kernel_launch(void* const* d_in, const int* in_sizes, int n_in,
                              void* d_out, int out_size, void* d_ws, size_t ws_size,
                              hipStream_t stream)
{
  (void)in_sizes; (void)n_in; (void)out_size; (void)ws_size;
  const float* x     = (const float*)d_in[0];
  const float* pos   = (const float*)d_in[1];
  const float* sup   = (const float*)d_in[2];
  const int*   nbr   = (const int*)d_in[3];
  const float* cv0w  = (const float*)d_in[5];
  const float* cv0b  = (const float*)d_in[6];
  const float* bn0g  = (const float*)d_in[7];
  const float* bn0b  = (const float*)d_in[8];
  const float* fc1   = (const float*)d_in[9];
  const float* fc2   = (const float*)d_in[10];
  const float* fc3   = (const float*)d_in[11];
  const float* in1g  = (const float*)d_in[12];
  const float* in1b  = (const float*)d_in[13];
  const float* in2g  = (const float*)d_in[14];
  const float* in2b  = (const float*)d_in[15];
  const float* alp   = (const float*)d_in[16];
  const float* bet   = (const float*)d_in[17];
  const float* nrp   = (const float*)d_in[18];
  const float* cvw   = (const float*)d_in[19];
  const float* bn1g  = (const float*)d_in[20];
  const float* bn1b  = (const float*)d_in[21];
  const float* cv2w  = (const float*)d_in[22];
  const float* cv2bi = (const float*)d_in[23];
  const float* bn2g  = (const float*)d_in[24];
  const float* bn2b  = (const float*)d_in[25];
  const float* scw   = (const float*)d_in[26];
  const float* scb   = (const float*)d_in[27];
  const float* bnscg = (const float*)d_in[28];
  const float* bnscb = (const float*)d_in[29];

  char* w = (char*)d_ws;
  __hip_bfloat16* sct  = (__hip_bfloat16*)(w);                  //  0        (64 MB)
  __hip_bfloat16* y0t  = (__hip_bfloat16*)(w + 67108864);       //  16 MB
  float*          pin1 = (float*)(w + 83886080);                //   1 MB (in1..red, dead pre-fka)
  float*          pin2 = (float*)(w + 84934656);                //   1 MB (in2..red, dead pre-fka)
  float*          p7   = (float*)(w + 85983232);                //   1 MB (k7..red, agg dead)
  __hip_bfloat16* aggp = (__hip_bfloat16*)(w + 83886080);       //  64 MB (fka..k6)
  __hip_bfloat16* h2   = (__hip_bfloat16*)(w + 100663296);      //  16 MB (k7..final, agg dead)
  float*          hfka = (float*)(w + 150994944);               //   8 MB (k6..k7, after agg end)
  float*          p1   = (float*)(w + 160432128);               // 5.2 MB (k1..red)
  float*          p6   = (float*)(w + 167772160);               //   1 MB (k6..red, outside agg)
  __hip_bfloat16* wb   = (__hip_bfloat16*)(w + 176160768);
  __hip_bfloat16* cvb  = (__hip_bfloat16*)(w + 176242688);
  __hip_bfloat16* cv2b = (__hip_bfloat16*)(w + 176373760);
  float*          stat = (float*)(w + 192937984UL);

  k_prep_w<<<480, 256, 0, stream>>>(cv0w, scw, cvw, cv2w, wb, cvb, cv2b);
  k1_mfma<<<2048, 256, 0, stream>>>(x, wb, cv0b, scb, y0t, sct, p1);
  k_redP1<<<20, 256, 0, stream>>>(p1, 2048, bn0g, bn0b, bnscg, bnscb,
                                  1.0f / 131072.0f, stat);
  k_in1_stats<<<2048, 256, 0, stream>>>(pos, sup, nbr, fc1, nrp, pin1);
  k_redB<<<16, 256, 0, stream>>>(pin1, 512, in1g, in1b, 1.0f / 32768.0f,
                                 stat + ST_SC_IN1, stat + ST_SH_IN1);
  k_in2_stats<<<2048, 256, 0, stream>>>(pos, sup, nbr, fc1, fc2, alp, bet, nrp, stat, pin2);
  k_redB<<<16, 256, 0, stream>>>(pin2, 512, in2g, in2b, 1.0f / 32768.0f,
                                 stat + ST_SC_IN2, stat + ST_SH_IN2);
  k_fka<<<2048, 256, 0, stream>>>(pos, sup, nbr, fc1, fc2, fc3, alp, bet, nrp, y0t, stat, aggp);
  k6_mfma<<<512, 256, 0, stream>>>(aggp, cvb, hfka, p6);
  k_redA<<<4, 256, 0, stream>>>(p6, 2048, 128, 0, 64, bn1g, bn1b,
                                1.0f / 32768.0f, 64, stat + ST_SC_BN1, stat + ST_SH_BN1);
  k7_mfma<<<512, 256, 0, stream>>>(hfka, cv2b, cv2bi, stat, h2, p7);
  k_redA<<<16, 256, 0, stream>>>(p7, 512, 512, 0, 256, bn2g, bn2b,
                                 1.0f / 32768.0f, 256, stat + ST_SC_BN2, stat + ST_SH_BN2);
  k_final<<<2048, 256, 0, stream>>>(sct, h2, nbr, stat, (float*)d_out);
}

// Round 13
// 448.061 us; speedup vs baseline: 3.3326x; 1.0027x over previous
//
#include <hip/hip_runtime.h>
#include <hip/hip_bf16.h>

#define DEV static __device__ __forceinline__

typedef __attribute__((ext_vector_type(8))) short bf16x8;
typedef __attribute__((ext_vector_type(4))) float f32x4;

// ---------------- stat layout (floats, inside ws) ----------------
#define ST_SC_BN0  0
#define ST_SH_BN0  64
#define ST_SC_SC   128
#define ST_SH_SC   384
#define ST_SC_IN1  640
#define ST_SH_IN1  896
#define ST_SC_IN2  1152
#define ST_SH_IN2  1408
#define ST_SC_BN1  1664
#define ST_SH_BN1  1728
#define ST_SC_BN2  1792
#define ST_SH_BN2  2048

DEV float rsum16(float v){
#pragma unroll
  for (int off = 8; off >= 1; off >>= 1) v += __shfl_xor(v, off, 16);
  return v;
}
DEV float rmax16(float v){
#pragma unroll
  for (int off = 8; off >= 1; off >>= 1) v = fmaxf(v, __shfl_xor(v, off, 16));
  return v;
}

// =================================================================
// P0: weight conversion f32 -> bf16. cvb is K-PERMUTED: dst k' = q*64+c
// for src k = c*16+q, so fka's Phase B can write agg q-major coalesced.
// =================================================================
__global__ __launch_bounds__(256) void k_prep_w(
    const float* __restrict__ cv0w, const float* __restrict__ scw,
    const float* __restrict__ cvw,  const float* __restrict__ cv2w,
    __hip_bfloat16* __restrict__ wb, __hip_bfloat16* __restrict__ cvb,
    __hip_bfloat16* __restrict__ cv2b)
{
  int i = blockIdx.x * 256 + threadIdx.x;   // 0 .. 122879
  if (i < 40960){
    float v = (i < 8192) ? cv0w[i] : scw[i - 8192];
    wb[i] = __float2bfloat16(v);
  } else if (i < 106496){
    int j = i - 40960;                  // [64][1024] flat, k = c*16+q
    int o = j >> 10, kk = j & 1023;
    int c = kk >> 4, q = kk & 15;
    cvb[(o << 10) + (q << 6) + c] = __float2bfloat16(cvw[j]);
  } else {
    cv2b[i - 106496] = __float2bfloat16(cv2w[i - 106496]);
  }
}

// =================================================================
// K1: fused transpose + MFMA cv0+shortcut GEMM, LDS-staged output
// for full-line coalesced stores. smem union: xt (17 KB) during
// compute, outs[64][328] (42 KB) for the output tile.
// =================================================================
__global__ __launch_bounds__(256) void k1_mfma(
    const float* __restrict__ x, const __hip_bfloat16* __restrict__ wb,
    const float* __restrict__ cv0b, const float* __restrict__ scb,
    __hip_bfloat16* __restrict__ y0t, __hip_bfloat16* __restrict__ sct,
    float* __restrict__ p1)
{
  __shared__ __align__(16) char smem[64 * 328 * 2];   // 41984 B
  __hip_bfloat16 (*xt)[136]   = (__hip_bfloat16 (*)[136])smem;
  __hip_bfloat16 (*outs)[328] = (__hip_bfloat16 (*)[328])smem;

  const int tid = threadIdx.x;
  const int b = blockIdx.x >> 7, nt = blockIdx.x & 127;
  const int n0 = nt << 6;
  const int wv = tid >> 6, l = tid & 63;
  const int lr = l & 15, lg = l >> 4;
  float* p1row = p1 + (size_t)blockIdx.x * 640;

#pragma unroll
  for (int p = 0; p < 8; p++){
    int c  = (p << 4) + (tid >> 4);
    int n4 = (tid & 15) << 2;
    float4 v = *(const float4*)&x[(((size_t)b * 128 + c) << 13) + n0 + n4];
    xt[n4 + 0][c] = __float2bfloat16(v.x);
    xt[n4 + 1][c] = __float2bfloat16(v.y);
    xt[n4 + 2][c] = __float2bfloat16(v.z);
    xt[n4 + 3][c] = __float2bfloat16(v.w);
  }
  __syncthreads();

  f32x4 acc[5][4];
#pragma unroll
  for (int i = 0; i < 5; i++)
#pragma unroll
    for (int j = 0; j < 4; j++) acc[i][j] = (f32x4){0.f, 0.f, 0.f, 0.f};

  const __hip_bfloat16* wrow = wb + (size_t)(wv * 80 + lr) * 128 + lg * 8;

#pragma unroll
  for (int ks = 0; ks < 4; ks++){
    bf16x8 B[4], A[5];
#pragma unroll
    for (int nf = 0; nf < 4; nf++)
      B[nf] = *(const bf16x8*)&xt[nf * 16 + lr][ks * 32 + lg * 8];
#pragma unroll
    for (int mf = 0; mf < 5; mf++) A[mf] = *(const bf16x8*)(wrow + mf * 2048 + ks * 32);
#pragma unroll
    for (int mf = 0; mf < 5; mf++)
#pragma unroll
      for (int nf = 0; nf < 4; nf++)
        acc[mf][nf] = __builtin_amdgcn_mfma_f32_16x16x32_bf16(A[mf], B[nf], acc[mf][nf], 0, 0, 0);
  }
  __syncthreads();   // xt dead; smem becomes outs

  // bias + stats + stage into outs
#pragma unroll
  for (int mf = 0; mf < 5; mf++){
    const int m0 = wv * 80 + mf * 16 + lg * 4;
    float bv[4];
#pragma unroll
    for (int r = 0; r < 4; r++){
      int m = m0 + r;
      bv[r] = (m < 64) ? cv0b[m] : scb[m - 64];
    }
#pragma unroll
    for (int nf = 0; nf < 4; nf++)
#pragma unroll
      for (int r = 0; r < 4; r++) acc[mf][nf][r] += bv[r];

#pragma unroll
    for (int nf = 0; nf < 4; nf++){
      int n = nf * 16 + lr;
      union { uint2 u; __hip_bfloat16 e[4]; } pk;
#pragma unroll
      for (int r = 0; r < 4; r++) pk.e[r] = __float2bfloat16(acc[mf][nf][r]);
      *(uint2*)&outs[n][m0] = pk.u;
    }
#pragma unroll
    for (int r = 0; r < 4; r++){
      float ss = 0.f, qq = 0.f;
#pragma unroll
      for (int nf = 0; nf < 4; nf++){ float v = acc[mf][nf][r]; ss += v; qq += v * v; }
#pragma unroll
      for (int off = 8; off >= 1; off >>= 1){
        ss += __shfl_xor(ss, off, 16);
        qq += __shfl_xor(qq, off, 16);
      }
      if (lr == 0){
        int ch = m0 + r;
        p1row[ch]       = ss;
        p1row[320 + ch] = qq;
      }
    }
  }
  __syncthreads();

  // coalesced copy-out: y0t slab (64n x 64ch = 512 uint4), linear
#pragma unroll
  for (int i = tid; i < 512; i += 256){
    int n = i >> 3, c8 = (i & 7) << 3;
    *(uint4*)&y0t[((size_t)(b << 13) + n0 + n) * 64 + c8] = *(const uint4*)&outs[n][c8];
  }
  // sct slab (64n x 256ch = 2048 uint4): n = i>>5 (32 uint4/row)
#pragma unroll
  for (int i = tid; i < 2048; i += 256){
    int n = i >> 5, c8 = (i & 31) << 3;
    *(uint4*)&sct[((size_t)(b << 13) + n0 + n) * 256 + c8] = *(const uint4*)&outs[n][64 + c8];
  }
}

// =================================================================
// Fast reducers
// =================================================================
__global__ __launch_bounds__(256) void k_redP1(
    const float* __restrict__ part, int nrows,
    const float* __restrict__ g0, const float* __restrict__ b0,
    const float* __restrict__ gs, const float* __restrict__ bs,
    float inv_cnt, float* __restrict__ stat)
{
  __shared__ f32x4 sh_s[256], sh_q[256];
  const int tid = threadIdx.x;
  const int ch0 = blockIdx.x << 4;
  const int c4 = (tid & 3) << 2;
  const int stripe = tid >> 2;
  f32x4 s = {0.f,0.f,0.f,0.f}, q = {0.f,0.f,0.f,0.f};
  for (int r = stripe; r < nrows; r += 64){
    const float* row = part + (size_t)r * 640;
    s += *(const f32x4*)&row[ch0 + c4];
    q += *(const f32x4*)&row[320 + ch0 + c4];
  }
  sh_s[tid] = s; sh_q[tid] = q;
  __syncthreads();
  for (int off = 128; off >= 4; off >>= 1){
    if (tid < off){ sh_s[tid] += sh_s[tid + off]; sh_q[tid] += sh_q[tid + off]; }
    __syncthreads();
  }
  if (tid < 4){
    f32x4 S = sh_s[tid], Q = sh_q[tid];
#pragma unroll
    for (int j = 0; j < 4; j++){
      int ch = ch0 + (tid << 2) + j;
      float m  = S[j] * inv_cnt;
      float v  = Q[j] * inv_cnt - m * m;
      if (ch < 64){
        float sc = g0[ch] * rsqrtf(v + 1e-5f);
        stat[ST_SC_BN0 + ch] = sc;
        stat[ST_SH_BN0 + ch] = b0[ch] - m * sc;
      } else {
        int c = ch - 64;
        float sc = gs[c] * rsqrtf(v + 1e-5f);
        stat[ST_SC_SC + c] = sc;
        stat[ST_SH_SC + c] = bs[c] - m * sc;
      }
    }
  }
}

__global__ __launch_bounds__(256) void k_redA(
    const float* __restrict__ part, int nrows, int rowstride,
    int sum_off, int sq_off,
    const float* __restrict__ g, const float* __restrict__ bb,
    float inv_cnt, int gmod,
    float* __restrict__ scale, float* __restrict__ shift)
{
  __shared__ f32x4 sh_s[256], sh_q[256];
  const int tid = threadIdx.x;
  const int ch0 = blockIdx.x << 4;
  const int c4 = (tid & 3) << 2;
  const int stripe = tid >> 2;
  f32x4 s = {0.f,0.f,0.f,0.f}, q = {0.f,0.f,0.f,0.f};
  for (int r = stripe; r < nrows; r += 64){
    const float* row = part + (size_t)r * rowstride;
    s += *(const f32x4*)&row[sum_off + ch0 + c4];
    q += *(const f32x4*)&row[sq_off + ch0 + c4];
  }
  sh_s[tid] = s; sh_q[tid] = q;
  __syncthreads();
  for (int off = 128; off >= 4; off >>= 1){
    if (tid < off){ sh_s[tid] += sh_s[tid + off]; sh_q[tid] += sh_q[tid + off]; }
    __syncthreads();
  }
  if (tid < 4){
    f32x4 S = sh_s[tid], Q = sh_q[tid];
#pragma unroll
    for (int j = 0; j < 4; j++){
      int ch = ch0 + (tid << 2) + j;
      float m  = S[j] * inv_cnt;
      float v  = Q[j] * inv_cnt - m * m;
      float sc = g[ch % gmod] * rsqrtf(v + 1e-5f);
      scale[ch] = sc;
      shift[ch] = bb[ch % gmod] - m * sc;
    }
  }
}

__global__ __launch_bounds__(256) void k_redB(
    const float* __restrict__ part, int rows_per_b,
    const float* __restrict__ g, const float* __restrict__ bb, float inv_cnt,
    float* __restrict__ scale, float* __restrict__ shift)
{
  __shared__ f32x4 sh_s[256], sh_q[256];
  const int tid = threadIdx.x;
  const int b = blockIdx.x;
  const int c4 = (tid & 3) << 2;
  const int stripe = tid >> 2;
  const float* base = part + (size_t)b * rows_per_b * 32;
  f32x4 s = {0.f,0.f,0.f,0.f}, q = {0.f,0.f,0.f,0.f};
  for (int r = stripe; r < rows_per_b; r += 64){
    s += *(const f32x4*)&base[r * 32 + c4];
    q += *(const f32x4*)&base[r * 32 + 16 + c4];
  }
  sh_s[tid] = s; sh_q[tid] = q;
  __syncthreads();
  for (int off = 128; off >= 4; off >>= 1){
    if (tid < off){ sh_s[tid] += sh_s[tid + off]; sh_q[tid] += sh_q[tid + off]; }
    __syncthreads();
  }
  if (tid < 4){
    f32x4 S = sh_s[tid], Q = sh_q[tid];
#pragma unroll
    for (int j = 0; j < 4; j++){
      int c = (tid << 2) + j;
      float m  = S[j] * inv_cnt;
      float v  = Q[j] * inv_cnt - m * m;
      float sc = g[c] * rsqrtf(v + 1e-5f);
      scale[b * 16 + c] = sc;
      shift[b * 16 + c] = bb[c] - m * sc;
    }
  }
}

// =================================================================
// K3: IN1 stats -> pin1[blk*4+wv][32]
// =================================================================
__global__ __launch_bounds__(256) void k_in1_stats(
    const float* __restrict__ pos, const float* __restrict__ sup, const int* __restrict__ nbr,
    const float* __restrict__ fc1, const float* __restrict__ nrp, float* __restrict__ pin1)
{
  const int tid = threadIdx.x;
  const int b  = blockIdx.x >> 7;
  const int st = blockIdx.x & 127;
  const int sl = tid >> 4, k = tid & 15;
  const int s  = (st << 4) + sl;
  const int n  = nbr[((((size_t)b << 11) + s) << 4) + k];
  float* pr = pin1 + ((size_t)blockIdx.x * 4 + (tid >> 6)) * 32;
  const float inr = 1.0f / nrp[0];
  float p0 = (pos[((size_t)b * 3 + 0) * 8192 + n] - sup[((size_t)b * 3 + 0) * 2048 + s]) * inr;
  float p1 = (pos[((size_t)b * 3 + 1) * 8192 + n] - sup[((size_t)b * 3 + 1) * 2048 + s]) * inr;
  float p2 = (pos[((size_t)b * 3 + 2) * 8192 + n] - sup[((size_t)b * 3 + 2) * 2048 + s]) * inr;
#pragma unroll
  for (int q = 0; q < 16; q++){
    float z = fc1[q * 3] * p0 + fc1[q * 3 + 1] * p1 + fc1[q * 3 + 2] * p2;
    float a = z, c = z * z;
#pragma unroll
    for (int off = 32; off >= 1; off >>= 1){
      a += __shfl_xor(a, off, 64);
      c += __shfl_xor(c, off, 64);
    }
    if ((tid & 63) == q){
      pr[q]      = a;
      pr[16 + q] = c;
    }
  }
}

// =================================================================
// K4: IN2 stats -> pin2[blk*4+wv][32]
// =================================================================
__global__ __launch_bounds__(256) void k_in2_stats(
    const float* __restrict__ pos, const float* __restrict__ sup, const int* __restrict__ nbr,
    const float* __restrict__ fc1, const float* __restrict__ fc2,
    const float* __restrict__ alp, const float* __restrict__ bet, const float* __restrict__ nrp,
    const float* __restrict__ stat, float* __restrict__ pin2)
{
  __shared__ float fc2s[512];
  __shared__ float sc1s[16], sh1s[16];
  const int tid = threadIdx.x;
  const int b  = blockIdx.x >> 7;
  const int st = blockIdx.x & 127;
  fc2s[tid]       = fc2[tid];
  fc2s[tid + 256] = fc2[tid + 256];
  if (tid < 16){
    sc1s[tid] = stat[ST_SC_IN1 + (b << 4) + tid];
    sh1s[tid] = stat[ST_SH_IN1 + (b << 4) + tid];
  }
  __syncthreads();
  const int sl = tid >> 4, k = tid & 15;
  const int s  = (st << 4) + sl;
  const int n  = nbr[((((size_t)b << 11) + s) << 4) + k];
  float* pr = pin2 + ((size_t)blockIdx.x * 4 + (tid >> 6)) * 32;
  float t0 = pos[((size_t)b * 3 + 0) * 8192 + n] - sup[((size_t)b * 3 + 0) * 2048 + s];
  float t1 = pos[((size_t)b * 3 + 1) * 8192 + n] - sup[((size_t)b * 3 + 1) * 2048 + s];
  float t2 = pos[((size_t)b * 3 + 2) * 8192 + n] - sup[((size_t)b * 3 + 2) * 2048 + s];
  float dist = sqrtf(t0 * t0 + t1 * t1 + t2 * t2);
  float dw = 1.0f / (1.0f + expf(alp[0] * dist - bet[0]));
  float ssum = rsum16(dw);
  ssum += (ssum == 0.0f ? 1.0f : 0.0f) + 1e-6f;
  dw = dw / ssum * 16.0f;
  const float inr = 1.0f / nrp[0];
  float p0 = t0 * inr, p1 = t1 * inr, p2 = t2 * inr;
  float m1[16], mp1[16];
#pragma unroll
  for (int q = 0; q < 16; q++){
    float z = fc1[q * 3] * p0 + fc1[q * 3 + 1] * p1 + fc1[q * 3 + 2] * p2;
    m1[q] = fmaxf(z * sc1s[q] + sh1s[q], 0.0f);
  }
#pragma unroll
  for (int q = 0; q < 16; q++) mp1[q] = rmax16(m1[q] * dw);
#pragma unroll
  for (int q = 0; q < 16; q++){
    float z = 0.0f;
#pragma unroll
    for (int j = 0; j < 16; j++) z = fmaf(fc2s[q * 32 + j], m1[j], z);
#pragma unroll
    for (int j = 0; j < 16; j++) z = fmaf(fc2s[q * 32 + 16 + j], mp1[j], z);
    float a = z, c = z * z;
#pragma unroll
    for (int off = 32; off >= 1; off >>= 1){
      a += __shfl_xor(a, off, 64);
      c += __shfl_xor(c, off, 64);
    }
    if ((tid & 63) == q){
      pr[q]      = a;
      pr[16 + q] = c;
    }
  }
}

// =================================================================
// K5: FKA main, barrier-free Phase B.
// =================================================================
__global__ __launch_bounds__(256) void k_fka(
    const float* __restrict__ pos, const float* __restrict__ sup, const int* __restrict__ nbr,
    const float* __restrict__ fc1, const float* __restrict__ fc2, const float* __restrict__ fc3,
    const float* __restrict__ alp, const float* __restrict__ bet, const float* __restrict__ nrp,
    const __hip_bfloat16* __restrict__ y0t, const float* __restrict__ stat,
    __hip_bfloat16* __restrict__ agg)
{
  __shared__ float fc2s[512], fc3s[512];
  __shared__ float sc1s[16], sh1s[16], sc2s[16], sh2s[16];
  __shared__ float sc0s[64], sh0s[64];
  __shared__ float mat3_s[16][17][20];   // [sl][q][k], q-stride 80B (b128-aligned)
  __shared__ int   idx_s[16][16];

  const int tid = threadIdx.x;
  const int b  = blockIdx.x >> 7;
  const int st = blockIdx.x & 127;
  fc2s[tid]       = fc2[tid];
  fc2s[tid + 256] = fc2[tid + 256];
  fc3s[tid]       = fc3[tid];
  fc3s[tid + 256] = fc3[tid + 256];
  if (tid < 16){
    sc1s[tid] = stat[ST_SC_IN1 + (b << 4) + tid];
    sh1s[tid] = stat[ST_SH_IN1 + (b << 4) + tid];
    sc2s[tid] = stat[ST_SC_IN2 + (b << 4) + tid];
    sh2s[tid] = stat[ST_SH_IN2 + (b << 4) + tid];
  }
  if (tid < 64){
    sc0s[tid] = stat[ST_SC_BN0 + tid];
    sh0s[tid] = stat[ST_SH_BN0 + tid];
  }
  const int sl = tid >> 4, k = tid & 15;
  const int s  = (st << 4) + sl;
  const int n  = nbr[((((size_t)b << 11) + s) << 4) + k];
  idx_s[sl][k] = n;
  __syncthreads();

  // ---- Phase A ----
  float t0 = pos[((size_t)b * 3 + 0) * 8192 + n] - sup[((size_t)b * 3 + 0) * 2048 + s];
  float t1 = pos[((size_t)b * 3 + 1) * 8192 + n] - sup[((size_t)b * 3 + 1) * 2048 + s];
  float t2 = pos[((size_t)b * 3 + 2) * 8192 + n] - sup[((size_t)b * 3 + 2) * 2048 + s];
  float dist = sqrtf(t0 * t0 + t1 * t1 + t2 * t2);
  float dw = 1.0f / (1.0f + expf(alp[0] * dist - bet[0]));
  float ssum = rsum16(dw);
  ssum += (ssum == 0.0f ? 1.0f : 0.0f) + 1e-6f;
  dw = dw / ssum * 16.0f;
  const float inr = 1.0f / nrp[0];
  float p0 = t0 * inr, p1 = t1 * inr, p2 = t2 * inr;
  float m1[16], mp1[16];
#pragma unroll
  for (int q = 0; q < 16; q++){
    float z = fc1[q * 3] * p0 + fc1[q * 3 + 1] * p1 + fc1[q * 3 + 2] * p2;
    m1[q] = fmaxf(z * sc1s[q] + sh1s[q], 0.0f);
  }
#pragma unroll
  for (int q = 0; q < 16; q++) mp1[q] = rmax16(m1[q] * dw);
  float m2[16], mp2[16];
#pragma unroll
  for (int q = 0; q < 16; q++){
    float z = 0.0f;
#pragma unroll
    for (int j = 0; j < 16; j++) z = fmaf(fc2s[q * 32 + j], m1[j], z);
#pragma unroll
    for (int j = 0; j < 16; j++) z = fmaf(fc2s[q * 32 + 16 + j], mp1[j], z);
    m2[q] = fmaxf(z * sc2s[q] + sh2s[q], 0.0f);
  }
#pragma unroll
  for (int q = 0; q < 16; q++) mp2[q] = rmax16(m2[q] * dw);
#pragma unroll
  for (int q = 0; q < 16; q++){
    float z = 0.0f;
#pragma unroll
    for (int j = 0; j < 16; j++) z = fmaf(fc3s[q * 32 + j], m2[j], z);
#pragma unroll
    for (int j = 0; j < 16; j++) z = fmaf(fc3s[q * 32 + 16 + j], mp2[j], z);
    mat3_s[sl][q][k] = fmaxf(z, 0.0f) * dw;
  }
  __syncthreads();

  // ---- Phase B: barrier-free ----
  const int sB = tid >> 4;
  const int c4 = (tid & 15) << 2;
  const float s0a = sc0s[c4],     s0b = sc0s[c4 + 1],
              s0c = sc0s[c4 + 2], s0d = sc0s[c4 + 3];
  const float h0a = sh0s[c4],     h0b = sh0s[c4 + 1],
              h0c = sh0s[c4 + 2], h0d = sh0s[c4 + 3];

  float f0[16], f1[16], f2[16], f3[16];
#pragma unroll
  for (int kk = 0; kk < 16; kk++){
    int nn = idx_s[sB][kk];
    union { uint2 u; __hip_bfloat16 e[4]; } ld;
    ld.u = *(const uint2*)&y0t[((size_t)(b << 13) + nn) * 64 + c4];
    f0[kk] = fmaxf(__bfloat162float(ld.e[0]) * s0a + h0a, 0.0f);
    f1[kk] = fmaxf(__bfloat162float(ld.e[1]) * s0b + h0b, 0.0f);
    f2[kk] = fmaxf(__bfloat162float(ld.e[2]) * s0c + h0c, 0.0f);
    f3[kk] = fmaxf(__bfloat162float(ld.e[3]) * s0d + h0d, 0.0f);
  }

  __hip_bfloat16* arow = agg + ((size_t)(b << 11) + (st << 4) + sB) * 1024 + c4;
#pragma unroll
  for (int q = 0; q < 16; q++){
    float a0 = 0.f, a1 = 0.f, a2 = 0.f, a3 = 0.f;
#pragma unroll
    for (int kk = 0; kk < 16; kk++){
      float mv = mat3_s[sB][q][kk];
      a0 = fmaf(f0[kk], mv, a0);
      a1 = fmaf(f1[kk], mv, a1);
      a2 = fmaf(f2[kk], mv, a2);
      a3 = fmaf(f3[kk], mv, a3);
    }
    union { uint2 u; __hip_bfloat16 e[4]; } pk;
    pk.e[0] = __float2bfloat16(a0);
    pk.e[1] = __float2bfloat16(a1);
    pk.e[2] = __float2bfloat16(a2);
    pk.e[3] = __float2bfloat16(a3);
    *(uint2*)(arow + (q << 6)) = pk.u;
  }
}

// =================================================================
// K6: MFMA cv GEMM (standalone).
// =================================================================
__global__ __launch_bounds__(256) void k6_mfma(
    const __hip_bfloat16* __restrict__ agg, const __hip_bfloat16* __restrict__ cvb,
    float* __restrict__ hfka, float* __restrict__ p6)
{
  const int tid = threadIdx.x;
  const int b = blockIdx.x >> 5, stile = blockIdx.x & 31;
  const int wv = tid >> 6, l = tid & 63;
  const int lr = l & 15, lg = l >> 4;
  const int sw = (stile << 6) + (wv << 4);
  float* p6row = p6 + ((size_t)blockIdx.x * 4 + wv) * 128;

  f32x4 acc[4];
#pragma unroll
  for (int i = 0; i < 4; i++) acc[i] = (f32x4){0.f, 0.f, 0.f, 0.f};

  const __hip_bfloat16* brow = agg + ((size_t)(b << 11) + sw + lr) * 1024 + lg * 8;
  const __hip_bfloat16* arow = cvb + (size_t)lr * 1024 + lg * 8;

#pragma unroll 4
  for (int ks = 0; ks < 32; ks++){
    bf16x8 B = *(const bf16x8*)(brow + ks * 32);
    bf16x8 A[4];
#pragma unroll
    for (int mf = 0; mf < 4; mf++) A[mf] = *(const bf16x8*)(arow + mf * 16384 + ks * 32);
#pragma unroll
    for (int mf = 0; mf < 4; mf++)
      acc[mf] = __builtin_amdgcn_mfma_f32_16x16x32_bf16(A[mf], B, acc[mf], 0, 0, 0);
  }

  const int s = sw + lr;
#pragma unroll
  for (int mf = 0; mf < 4; mf++){
    const int m0 = mf * 16 + lg * 4;
    float4 v = make_float4(acc[mf][0], acc[mf][1], acc[mf][2], acc[mf][3]);
    *(float4*)&hfka[((size_t)(b << 11) + s) * 64 + m0] = v;
#pragma unroll
    for (int r = 0; r < 4; r++){
      float ss = acc[mf][r], qq = ss * ss;
#pragma unroll
      for (int off = 8; off >= 1; off >>= 1){
        ss += __shfl_xor(ss, off, 16);
        qq += __shfl_xor(qq, off, 16);
      }
      if (lr == 0){
        p6row[m0 + r]      = ss;
        p6row[64 + m0 + r] = qq;
      }
    }
  }
}

// =================================================================
// K7: MFMA cv2. Partials: p7[blk][512]
// =================================================================
__global__ __launch_bounds__(256) void k7_mfma(
    const float* __restrict__ hfka, const __hip_bfloat16* __restrict__ cv2b,
    const float* __restrict__ bias, const float* __restrict__ stat_ro,
    __hip_bfloat16* __restrict__ h2, float* __restrict__ p7)
{
  const int tid = threadIdx.x;
  const int b = blockIdx.x >> 5, stile = blockIdx.x & 31;
  const int s0 = stile << 6;
  const int wv = tid >> 6, l = tid & 63;
  const int lr = l & 15, lg = l >> 4;
  float* p7row = p7 + (size_t)blockIdx.x * 512;

  float s1r[2][8], h1r[2][8];
#pragma unroll
  for (int ks = 0; ks < 2; ks++)
#pragma unroll
    for (int j = 0; j < 8; j++){
      int ch = ks * 32 + lg * 8 + j;
      s1r[ks][j] = stat_ro[ST_SC_BN1 + ch];
      h1r[ks][j] = stat_ro[ST_SH_BN1 + ch];
    }

  bf16x8 B[2][4];
#pragma unroll
  for (int ks = 0; ks < 2; ks++)
#pragma unroll
    for (int nf = 0; nf < 4; nf++){
      int s = s0 + nf * 16 + lr;
      const float* hp = hfka + ((size_t)(b << 11) + s) * 64 + ks * 32 + lg * 8;
      float4 v0 = *(const float4*)hp;
      float4 v1 = *(const float4*)(hp + 4);
      float vv[8] = {v0.x, v0.y, v0.z, v0.w, v1.x, v1.y, v1.z, v1.w};
      union { bf16x8 f; __hip_bfloat16 e[8]; } pk;
#pragma unroll
      for (int j = 0; j < 8; j++)
        pk.e[j] = __float2bfloat16(fmaxf(vv[j] * s1r[ks][j] + h1r[ks][j], 0.0f));
      B[ks][nf] = pk.f;
    }

  f32x4 acc[4][4];
#pragma unroll
  for (int i = 0; i < 4; i++)
#pragma unroll
    for (int j = 0; j < 4; j++) acc[i][j] = (f32x4){0.f, 0.f, 0.f, 0.f};

  const __hip_bfloat16* arow = cv2b + (size_t)(wv * 64 + lr) * 64 + lg * 8;
#pragma unroll
  for (int ks = 0; ks < 2; ks++){
    bf16x8 A[4];
#pragma unroll
    for (int mf = 0; mf < 4; mf++) A[mf] = *(const bf16x8*)(arow + mf * 1024 + ks * 32);
#pragma unroll
    for (int mf = 0; mf < 4; mf++)
#pragma unroll
      for (int nf = 0; nf < 4; nf++)
        acc[mf][nf] = __builtin_amdgcn_mfma_f32_16x16x32_bf16(A[mf], B[ks][nf], acc[mf][nf], 0, 0, 0);
  }

#pragma unroll
  for (int mf = 0; mf < 4; mf++){
    const int m0 = wv * 64 + mf * 16 + lg * 4;
    float bv[4];
#pragma unroll
    for (int r = 0; r < 4; r++) bv[r] = bias[m0 + r];
#pragma unroll
    for (int nf = 0; nf < 4; nf++){
      int s = s0 + nf * 16 + lr;
      union { uint2 u; __hip_bfloat16 e[4]; } pk;
#pragma unroll
      for (int r = 0; r < 4; r++){
        acc[mf][nf][r] += bv[r];
        pk.e[r] = __float2bfloat16(acc[mf][nf][r]);
      }
      *(uint2*)&h2[((size_t)(b << 11) + s) * 256 + m0] = pk.u;
    }
#pragma unroll
    for (int r = 0; r < 4; r++){
      float ss = 0.f, qq = 0.f;
#pragma unroll
      for (int nf = 0; nf < 4; nf++){ float v = acc[mf][nf][r]; ss += v; qq += v * v; }
#pragma unroll
      for (int off = 8; off >= 1; off >>= 1){
        ss += __shfl_xor(ss, off, 16);
        qq += __shfl_xor(qq, off, 16);
      }
      if (lr == 0){
        p7row[m0 + r]       = ss;
        p7row[256 + m0 + r] = qq;
      }
    }
  }
}

// =================================================================
// K8: final
// =================================================================
__global__ __launch_bounds__(256) void k_final(
    const __hip_bfloat16* __restrict__ sct, const __hip_bfloat16* __restrict__ h2,
    const int* __restrict__ nbr, const float* __restrict__ stat, float* __restrict__ out)
{
  __shared__ int   idx_s[256];
  __shared__ float tile_s[16][257];
  const int tid = threadIdx.x;
  const int b  = blockIdx.x >> 7;
  const int st = blockIdx.x & 127;
  const int s0 = st << 4;
  idx_s[tid] = nbr[((size_t)(b << 11) + s0) * 16 + tid];
  const int sl = tid >> 4, cg = tid & 15, ch0 = cg << 4;

  float ssc[16], hsc[16], s2v[16], h2v[16];
#pragma unroll
  for (int j = 0; j < 16; j++){
    ssc[j] = stat[ST_SC_SC  + ch0 + j];
    hsc[j] = stat[ST_SH_SC  + ch0 + j];
    s2v[j] = stat[ST_SC_BN2 + ch0 + j];
    h2v[j] = stat[ST_SH_BN2 + ch0 + j];
  }
  __syncthreads();

  float mx[16];
#pragma unroll
  for (int j = 0; j < 16; j++) mx[j] = -3.4e38f;
  for (int k = 0; k < 16; k++){
    int nn = idx_s[sl * 16 + k];
    const uint4* p = (const uint4*)&sct[((size_t)(b << 13) + nn) * 256 + ch0];
    union { uint4 u; __hip_bfloat16 e[8]; } a0, a1;
    a0.u = p[0]; a1.u = p[1];
#pragma unroll
    for (int j = 0; j < 8; j++){
      mx[j]     = fmaxf(mx[j],     __bfloat162float(a0.e[j]) * ssc[j]     + hsc[j]);
      mx[j + 8] = fmaxf(mx[j + 8], __bfloat162float(a1.e[j]) * ssc[j + 8] + hsc[j + 8]);
    }
  }
  {
    const uint4* p = (const uint4*)&h2[((size_t)(b << 11) + s0 + sl) * 256 + ch0];
    union { uint4 u; __hip_bfloat16 e[8]; } a0, a1;
    a0.u = p[0]; a1.u = p[1];
#pragma unroll
    for (int j = 0; j < 8; j++){
      tile_s[sl][ch0 + j]     = fmaxf(__bfloat162float(a0.e[j]) * s2v[j]     + h2v[j]     + mx[j], 0.0f);
      tile_s[sl][ch0 + 8 + j] = fmaxf(__bfloat162float(a1.e[j]) * s2v[j + 8] + h2v[j + 8] + mx[j + 8], 0.0f);
    }
  }
  __syncthreads();
  const int o = tid;
#pragma unroll
  for (int p4 = 0; p4 < 4; p4++){
    float4 v = make_float4(tile_s[p4 * 4 + 0][o], tile_s[p4 * 4 + 1][o],
                           tile_s[p4 * 4 + 2][o], tile_s[p4 * 4 + 3][o]);
    *(float4*)&out[((size_t)(b << 8) + o) * 2048 + s0 + p4 * 4] = v;
  }
}

// =================================================================
extern "C" void kernel_launch(void* const* d_in, const int* in_sizes, int n_in,
                              void* d_out, int out_size, void* d_ws, size_t ws_size,
                              hipStream_t stream)
{
  (void)in_sizes; (void)n_in; (void)out_size; (void)ws_size;
  const float* x     = (const float*)d_in[0];
  const float* pos   = (const float*)d_in[1];
  const float* sup   = (const float*)d_in[2];
  const int*   nbr   = (const int*)d_in[3];
  const float* cv0w  = (const float*)d_in[5];
  const float* cv0b  = (const float*)d_in[6];
  const float* bn0g  = (const float*)d_in[7];
  const float* bn0b  = (const float*)d_in[8];
  const float* fc1   = (const float*)d_in[9];
  const float* fc2   = (const float*)d_in[10];
  const float* fc3   = (const float*)d_in[11];
  const float* in1g  = (const float*)d_in[12];
  const float* in1b  = (const float*)d_in[13];
  const float* in2g  = (const float*)d_in[14];
  const float* in2b  = (const float*)d_in[15];
  const float* alp   = (const float*)d_in[16];
  const float* bet   = (const float*)d_in[17];
  const float* nrp   = (const float*)d_in[18];
  const float* cvw   = (const float*)d_in[19];
  const float* bn1g  = (const float*)d_in[20];
  const float* bn1b  = (const float*)d_in[21];
  const float* cv2w  = (const float*)d_in[22];
  const float* cv2bi = (const float*)d_in[23];
  const float* bn2g  = (const float*)d_in[24];
  const float* bn2b  = (const float*)d_in[25];
  const float* scw   = (const float*)d_in[26];
  const float* scb   = (const float*)d_in[27];
  const float* bnscg = (const float*)d_in[28];
  const float* bnscb = (const float*)d_in[29];

  char* w = (char*)d_ws;
  __hip_bfloat16* sct  = (__hip_bfloat16*)(w);                  //  0        (64 MB)
  __hip_bfloat16* y0t  = (__hip_bfloat16*)(w + 67108864);       //  16 MB
  float*          pin1 = (float*)(w + 83886080);                //   1 MB (in1..red, dead pre-fka)
  float*          pin2 = (float*)(w + 84934656);                //   1 MB (in2..red, dead pre-fka)
  float*          p7   = (float*)(w + 85983232);                //   1 MB (k7..red, agg dead)
  __hip_bfloat16* aggp = (__hip_bfloat16*)(w + 83886080);       //  64 MB (fka..k6)
  __hip_bfloat16* h2   = (__hip_bfloat16*)(w + 100663296);      //  16 MB (k7..final, agg dead)
  float*          hfka = (float*)(w + 150994944);               //   8 MB (k6..k7, after agg end)
  float*          p1   = (float*)(w + 160432128);               // 5.2 MB (k1..red)
  float*          p6   = (float*)(w + 167772160);               //   1 MB (k6..red, outside agg)
  __hip_bfloat16* wb   = (__hip_bfloat16*)(w + 176160768);
  __hip_bfloat16* cvb  = (__hip_bfloat16*)(w + 176242688);
  __hip_bfloat16* cv2b = (__hip_bfloat16*)(w + 176373760);
  float*          stat = (float*)(w + 192937984UL);

  k_prep_w<<<480, 256, 0, stream>>>(cv0w, scw, cvw, cv2w, wb, cvb, cv2b);
  k1_mfma<<<2048, 256, 0, stream>>>(x, wb, cv0b, scb, y0t, sct, p1);
  k_redP1<<<20, 256, 0, stream>>>(p1, 2048, bn0g, bn0b, bnscg, bnscb,
                                  1.0f / 131072.0f, stat);
  k_in1_stats<<<2048, 256, 0, stream>>>(pos, sup, nbr, fc1, nrp, pin1);
  k_redB<<<16, 256, 0, stream>>>(pin1, 512, in1g, in1b, 1.0f / 32768.0f,
                                 stat + ST_SC_IN1, stat + ST_SH_IN1);
  k_in2_stats<<<2048, 256, 0, stream>>>(pos, sup, nbr, fc1, fc2, alp, bet, nrp, stat, pin2);
  k_redB<<<16, 256, 0, stream>>>(pin2, 512, in2g, in2b, 1.0f / 32768.0f,
                                 stat + ST_SC_IN2, stat + ST_SH_IN2);
  k_fka<<<2048, 256, 0, stream>>>(pos, sup, nbr, fc1, fc2, fc3, alp, bet, nrp, y0t, stat, aggp);
  k6_mfma<<<512, 256, 0, stream>>>(aggp, cvb, hfka, p6);
  k_redA<<<4, 256, 0, stream>>>(p6, 2048, 128, 0, 64, bn1g, bn1b,
                                1.0f / 32768.0f, 64, stat + ST_SC_BN1, stat + ST_SH_BN1);
  k7_mfma<<<512, 256, 0, stream>>>(hfka, cv2b, cv2bi, stat, h2, p7);
  k_redA<<<16, 256, 0, stream>>>(p7, 512, 512, 0, 256, bn2g, bn2b,
                                 1.0f / 32768.0f, 256, stat + ST_SC_BN2, stat + ST_SH_BN2);
  k_final<<<2048, 256, 0, stream>>>(sct, h2, nbr, stat, (float*)d_out);
}